// Round 1
// 1294.923 us; speedup vs baseline: 1.0820x; 1.0820x over previous
//
#include <hip/hip_runtime.h>
#include <hip/hip_bf16.h>

typedef __hip_bfloat16 bf16;
typedef __attribute__((ext_vector_type(8))) short bf16x8;
typedef __attribute__((ext_vector_type(4))) float f32x4;

#define BB 16
#define EE 2048
#define FF 8192
#define QQ 20
#define DD 256
#define WDIM 300
#define NWORD 50000
#define VERY_NEG_F (-1.0e11f)

static __device__ __forceinline__ float b2f(bf16 x){ return __bfloat162float(x); }
static __device__ __forceinline__ bf16 f2b(float x){ return __float2bfloat16(x); }
static __device__ __forceinline__ float sigm(float x){ return 1.f/(1.f+expf(-x)); }
static __device__ __forceinline__ void ld4bf(const bf16* p, float v[4]){
  short4 s = *(const short4*)p;
  v[0]=b2f(*(const bf16*)&s.x); v[1]=b2f(*(const bf16*)&s.y);
  v[2]=b2f(*(const bf16*)&s.z); v[3]=b2f(*(const bf16*)&s.w);
}
static __device__ __forceinline__ void st4bf(bf16* p, float a,float b,float c,float d){
  unsigned short u[4]; bf16 t;
  t=f2b(a);u[0]=*(unsigned short*)&t; t=f2b(b);u[1]=*(unsigned short*)&t;
  t=f2b(c);u[2]=*(unsigned short*)&t; t=f2b(d);u[3]=*(unsigned short*)&t;
  *(short4*)p=*(short4*)u;
}

// ---------------- workspace offsets (bytes) ----------------
#define O_GX       0UL
#define O_QH       1310720UL
#define O_QNODE    1638400UL
#define O_RELLIN   1654784UL
#define O_WR       2270208UL
#define O_WMAX     2308864UL
#define O_WT       2309120UL
#define O_E2FS     2833408UL
#define O_PR       2964480UL
#define O_PRAGG    3095552UL
#define O_Q2EV     3226624UL
#define O_Q2EVB    3243008UL
#define O_RELSELF  3251200UL
#define O_NORM     3866624UL
#define O_WNXT     4390912UL
#define O_PRSUM    4440064UL
#define O_CNT      4440320UL
#define O_CUR      4571392UL
#define O_BSTART   4702464UL
#define O_BIDX     4834048UL
#define O_ELWPAD   5358336UL
#define O_FLAG     5522176UL
#define O_CVT      5522432UL   // 5393152 B
#define O_AGG      10915584UL  // bf16 16.7MB; A0 (21MB) aliases AGG+start of ENTSELF
#define O_ENTSELF  27692800UL
#define O_LEA      44470016UL
#define O_LEB      61247232UL
#define O_HEAD     78024448UL
#define O_F2EEMB   94801664UL  // end ~111.6MB

// canonical element offsets within O_CVT (all mult of 8)
#define C_ELB   0
#define C_RLW   256
#define C_RLB   153856
#define C_WIH   154112
#define C_WHH   461312   // frag-linear w_hh (262144 elems)
#define C_BIH   723456
#define C_BHH   724480
#define C_Q2EW  725504
#define C_Q2EB  922112
#define C_E2QW  922880
#define C_E2QB  1512704
#define C_E2EW  1513472
#define C_E2EB  2103296
#define C_KHW   2104064
#define C_KHB   2300672
#define C_KTW   2301440
#define C_KTB   2498048
#define C_KSW   2498816
#define C_KSB   2695424
#define C_SCW   2696192
#define C_SCB   2696448

// ---------------- dtype sniffer (verified r2) ----------------
__global__ __launch_bounds__(256) void k_sniff(const unsigned short* ee, int* flag){
  __shared__ int red[256];
  int c=0;
  for(int i=threadIdx.x;i<4096;i+=256){
    int ex=(ee[2*i]>>7)&0xFF;
    c += (ex>=192);
  }
  red[threadIdx.x]=c; __syncthreads();
  for(int o=128;o;o>>=1){ if(threadIdx.x<o) red[threadIdx.x]+=red[threadIdx.x+o]; __syncthreads(); }
  if(!threadIdx.x) flag[0] = (red[0]>64) ? 1 : 0;
}

// ---------------- batched weight canonicalization -> bf16 (tail-scale for e2q/e2e) ----------------
struct CvtJobs{ const void* src[20]; bf16* dst[20]; int n[20]; int sc[20]; };
__global__ __launch_bounds__(256) void k_cvt(CvtJobs J, const int* dfl){
  const int isf=*dfl;
  int j=blockIdx.y;
  int n=J.n[j];
  int i4=(blockIdx.x*256+threadIdx.x)*4;
  if(i4>=n) return;
  float m = (J.sc[j] && ((i4%768)>=512)) ? 3.f : 1.f;
  bf16* d=J.dst[j]+i4;
  if(isf){
    const float* s=(const float*)J.src[j]+i4;
    if(i4+4<=n){ float4 t=*(const float4*)s; st4bf(d,t.x*m,t.y*m,t.z*m,t.w*m); }
    else for(int r=0;i4+r<n;r++) d[r]=f2b(s[r]*m);
  } else {
    const bf16* s=(const bf16*)J.src[j]+i4;
    if(i4+4<=n){ float v[4]; ld4bf(s,v); st4bf(d,v[0]*m,v[1]*m,v[2]*m,v[3]*m); }
    else for(int r=0;i4+r<n;r++) d[r]=f2b(b2f(s[r])*m);
  }
}

// w_hh (1024x256) -> MFMA-fragment-linear: wf[gt][kt][lane][8], gate=gt*16+(lane&15), k=kt*32+(lane>>4)*8+j
__global__ __launch_bounds__(256) void k_cvtwhh(const void* src, bf16* wf, const int* dfl){
  const int isf=*dfl;
  int fid=blockIdx.x*256+threadIdx.x;        // 0..32767
  int lane=fid&63, kt=(fid>>6)&7, gt=fid>>9;
  int l16=lane&15, q=lane>>4;
  long so=(long)(gt*16+l16)*256 + kt*32 + q*8;
  float v[8];
  if(isf){ const float* s=(const float*)src+so;
    #pragma unroll
    for(int j=0;j<8;j++) v[j]=s[j];
  } else { const bf16* s=(const bf16*)src+so; ld4bf(s,v); ld4bf(s+4,v+4); }
  bf16* d=wf+(long)fid*8;
  st4bf(d,v[0],v[1],v[2],v[3]); st4bf(d+4,v[4],v[5],v[6],v[7]);
}

// entity_lin_w (256x300) -> padded bf16 (256x320)
__global__ __launch_bounds__(256) void k_cvtelw(const void* src, bf16* dst, const int* dfl){
  const int isf=*dfl;
  int r=blockIdx.x;
  for(int c=threadIdx.x;c<320;c+=256){
    float v=0.f;
    if(c<300) v = isf ? ((const float*)src)[r*300+c] : b2f(((const bf16*)src)[r*300+c]);
    dst[(long)r*320+c]=f2b(v);
  }
}

// gathered, padded A0[32768][320] = entity_emb[local_entity]
__global__ __launch_bounds__(128) void k_ga0(const int* idx, const void* emb, bf16* A0, const int* dfl){
  const int isf=*dfl;
  int row=blockIdx.x; int ent=idx[row]; int t=threadIdx.x;
  bf16* dst=A0+(long)row*320;
  if(t<75){
    float v[4];
    if(isf){ float4 x=*(const float4*)((const float*)emb+(long)ent*WDIM+t*4);
             v[0]=x.x;v[1]=x.y;v[2]=x.z;v[3]=x.w; }
    else ld4bf((const bf16*)emb+(long)ent*WDIM+t*4, v);
    st4bf(dst+t*4, v[0],v[1],v[2],v[3]);
  } else if(t<80){
    st4bf(dst+t*4, 0.f,0.f,0.f,0.f);
  }
}

// ---------------- CSR bucketing of facts by (b, f2e_ent) ----------------
__global__ __launch_bounds__(256) void k_cnt(const int* f2e, int* cnt){
  int i=blockIdx.x*256+threadIdx.x;
  atomicAdd(&cnt[((i>>13)<<11)+f2e[i]], 1);
}
__global__ __launch_bounds__(1024) void k_scan(const int* cnt, int* bstart){
  __shared__ int ps[1024];
  int t=threadIdx.x;
  int loc[32]; int s=0;
  #pragma unroll
  for(int j=0;j<32;j++){ loc[j]=s; s+=cnt[t*32+j]; }
  ps[t]=s; __syncthreads();
  for(int off=1;off<1024;off<<=1){
    int v=(t>=off)?ps[t-off]:0;
    __syncthreads(); ps[t]+=v; __syncthreads();
  }
  int base=(t? ps[t-1]:0);
  #pragma unroll
  for(int j=0;j<32;j++) bstart[t*32+j]=base+loc[j];
  if(t==1023) bstart[32768]=ps[1023];
}
__global__ __launch_bounds__(256) void k_fill(const int* f2e, const int* bstart, int* cur, int* bidx){
  int i=blockIdx.x*256+threadIdx.x;
  int key=((i>>13)<<11)+f2e[i];
  int pos=bstart[key]+atomicAdd(&cur[key],1);
  bidx[pos]=i;
}

// ---------------- gx = wemb[qtext] @ w_ih^T + b_ih + b_hh ----------------
__global__ __launch_bounds__(256) void k_gx(const int* qtext, const void* wemb,
    const bf16* wih, const bf16* bih, const bf16* bhh, float* gx, const int* dfl){
  const int isf=*dfl;
  int bt=blockIdx.x;
  __shared__ float xr[WDIM];
  int w=qtext[bt];
  for(int k4=threadIdx.x*4;k4<WDIM;k4+=1024){
    if(isf){ float4 t=*(const float4*)((const float*)wemb+(long)w*WDIM+k4);
             xr[k4]=t.x;xr[k4+1]=t.y;xr[k4+2]=t.z;xr[k4+3]=t.w; }
    else   { float v[4]; ld4bf((const bf16*)wemb+(long)w*WDIM+k4,v);
             xr[k4]=v[0];xr[k4+1]=v[1];xr[k4+2]=v[2];xr[k4+3]=v[3]; }
  }
  __syncthreads();
  #pragma unroll
  for(int s=0;s<4;s++){
    int g=threadIdx.x+256*s;
    float acc=b2f(bih[g])+b2f(bhh[g]);
    const bf16* wr=wih+(long)g*WDIM;
    for(int k4=0;k4<WDIM;k4+=4){
      float v[4]; ld4bf(wr+k4,v);
      acc+=v[0]*xr[k4]+v[1]*xr[k4+1]+v[2]*xr[k4+2]+v[3]*xr[k4+3];
    }
    gx[bt*1024+g]=acc;
  }
}

// ---------------- distributed MFMA LSTM: 16 blocks, W slice in registers ----------------
// Block k owns hidden units [k*16, k*16+16) -> gate tiles gt = {k, 16+k, 32+k, 48+k}.
// Wave w handles gate-type w (i,f,g,o): gt = w*16+k, 8 K-frags held in 32 VGPRs (loaded once).
// Per step: all blocks read full h (16x256 bf16, double-buffered in global, agent-scope
// atomics for cross-XCD coherence), MFMA z-slice, cell update (256 cells/block), publish
// h slice + release flag; spin on acquire flag. 16 blocks are always co-resident.
#define NLB 16
__global__ __launch_bounds__(256) void k_lstm3(const float* gx, const bf16* wf,
    float* qh, float* qnode, bf16* hbuf, int* lcnt){
  __shared__ bf16  hlds[16*264];     // padded rows: 528B stride -> 2-way LDS aliasing (free)
  __shared__ float zs[4*16*16];      // [gate-type][batch][u_local]
  __shared__ bf16  hsl[256];         // outgoing h slice [batch][u_local]
  const int k=blockIdx.x;
  const int tid=threadIdx.x;
  const int wv=tid>>6, lane=tid&63, q=lane>>4, l16=lane&15;
  const int b=tid>>4, u=tid&15, gu=k*16+u;
  // W fragments for this wave's gate tile (gt = wv*16+k), canonical wf layout (k_cvtwhh)
  bf16x8 wreg[8];
  #pragma unroll
  for(int kt=0;kt<8;kt++)
    wreg[kt]=*(const bf16x8*)(wf + (((long)((wv*16+k)*8+kt))*64 + lane)*8);
  float c=0.f;
  float gxr[4];
  #pragma unroll
  for(int g=0;g<4;g++) gxr[g]=gx[(b*QQ+0)*1024 + g*256 + gu];
  for(int t=0;t<QQ;t++){
    f32x4 acc=(f32x4){0.f,0.f,0.f,0.f};
    if(t){
      if(tid==0){
        while(__hip_atomic_load(lcnt+(t-1), __ATOMIC_ACQUIRE, __HIP_MEMORY_SCOPE_AGENT) < NLB)
          __builtin_amdgcn_s_sleep(1);
      }
      __syncthreads();
      // pull full h (8KB) -> LDS via agent-scope loads (bypass stale per-XCD L2)
      const bf16* hb = hbuf + (t&1)*4096;
      #pragma unroll
      for(int ii=0;ii<4;ii++){
        int i=tid+ii*256;
        int r=i>>6, cc=i&63;
        unsigned long long v=__hip_atomic_load((const unsigned long long*)(hb + r*256 + cc*4),
                       __ATOMIC_RELAXED, __HIP_MEMORY_SCOPE_AGENT);
        *(unsigned long long*)&hlds[r*264 + cc*4] = v;
      }
      __syncthreads();
      #pragma unroll
      for(int kt=0;kt<8;kt++){
        bf16x8 af=*(const bf16x8*)&hlds[l16*264 + kt*32 + q*8];
        acc=__builtin_amdgcn_mfma_f32_16x16x32_bf16(af,wreg[kt],acc,0,0,0);
      }
    }
    #pragma unroll
    for(int r=0;r<4;r++) zs[wv*256 + (q*4+r)*16 + l16]=acc[r];
    __syncthreads();
    float zi=zs[0*256+tid]+gxr[0];
    float zf=zs[1*256+tid]+gxr[1];
    float zg=zs[2*256+tid]+gxr[2];
    float zo=zs[3*256+tid]+gxr[3];
    { // prefetch next step's gx (time-invariant data, safe to cache)
      int tn=(t<QQ-1)?t+1:t;
      #pragma unroll
      for(int g=0;g<4;g++) gxr[g]=gx[(b*QQ+tn)*1024 + g*256 + gu];
    }
    c=sigm(zf)*c+sigm(zi)*tanhf(zg);
    float hv=sigm(zo)*tanhf(c);
    hsl[tid]=f2b(hv);
    qh[(long)(b*QQ+t)*256+gu]=hv;
    if(t==QQ-1) qnode[(b<<8)+gu]=hv;
    __syncthreads();
    if(t<QQ-1){
      if(tid<64){ // publish our 512B h slice, agent-scope
        bf16* hw=hbuf + ((t+1)&1)*4096;
        int bb=tid>>2, p=tid&3;
        unsigned long long v=*(unsigned long long*)&hsl[bb*16+p*4];
        __hip_atomic_store((unsigned long long*)(hw + bb*256 + k*16 + p*4), v,
                           __ATOMIC_RELAXED, __HIP_MEMORY_SCOPE_AGENT);
      }
      __syncthreads();   // drains vmcnt: slice stores globally visible (sc1 -> MALL)
      if(tid==0){
        __threadfence();
        __hip_atomic_fetch_add(lcnt+t, 1, __ATOMIC_RELEASE, __HIP_MEMORY_SCOPE_AGENT);
      }
    }
  }
}

// ---------------- rel_lin ----------------
__global__ __launch_bounds__(256) void k_rel_lin(const void* remb, const bf16* rlw,
    const bf16* rlb, float* rel_lin, const int* dfl){
  const int isf=*dfl;
  int r=blockIdx.x;
  __shared__ float rr[2*WDIM];
  for(int k4=threadIdx.x*4;k4<2*WDIM;k4+=1024){
    if(isf){ float4 t=*(const float4*)((const float*)remb+(long)r*2*WDIM+k4);
             rr[k4]=t.x;rr[k4+1]=t.y;rr[k4+2]=t.z;rr[k4+3]=t.w; }
    else   { float v[4]; ld4bf((const bf16*)remb+(long)r*2*WDIM+k4,v);
             rr[k4]=v[0];rr[k4+1]=v[1];rr[k4+2]=v[2];rr[k4+3]=v[3]; }
  }
  __syncthreads();
  int d=threadIdx.x;
  float acc=b2f(rlb[d]);
  const bf16* wr=rlw+(long)d*2*WDIM;
  for(int k4=0;k4<2*WDIM;k4+=4){
    float v[4]; ld4bf(wr+k4,v);
    acc+=v[0]*rr[k4]+v[1]*rr[k4+1]+v[2]*rr[k4+2]+v[3]*rr[k4+3];
  }
  rel_lin[r*DD+d]=acc;
}

// ---------------- sim + masked softmax + Wr (relation space) ----------------
__global__ __launch_bounds__(256) void k_simwr(const float* qh, const float* rel_lin,
    const int* qtext, float* Wr){
  int b = blockIdx.x, rc = blockIdx.y;
  __shared__ float qhb[QQ*DD];
  __shared__ float qm[QQ];
  for(int i=threadIdx.x;i<QQ*DD;i+=256) qhb[i]=qh[b*QQ*DD+i];
  if(threadIdx.x<QQ) qm[threadIdx.x] = (qtext[b*QQ+threadIdx.x]!=NWORD)?0.f:VERY_NEG_F;
  __syncthreads();
  int r = rc*256+threadIdx.x;
  if(r>=601) return;
  float s[QQ];
  #pragma unroll
  for(int q=0;q<QQ;q++) s[q]=0.f;
  for(int k=0;k<DD;k++){
    float rl = rel_lin[r*DD+k];
    #pragma unroll
    for(int q=0;q<QQ;q++) s[q] += qhb[q*DD+k]*rl;
  }
  float m=-1e30f;
  #pragma unroll
  for(int q=0;q<QQ;q++){ s[q]*=0.0625f; m=fmaxf(m, s[q]+qm[q]); }
  float sum=0.f, w=0.f;
  #pragma unroll
  for(int q=0;q<QQ;q++){ float p=expf(s[q]+qm[q]-m); sum+=p; w+=p*s[q]; }
  Wr[b*601+r] = w/sum;
}

// ---------------- Wmax / W_tilde / e2f_softmax / pr init ----------------
__global__ __launch_bounds__(256) void k_wmax(const float* Wr, const int* rel, float* wmax){
  int b=blockIdx.x; __shared__ float red[256];
  float m=-1e30f;
  for(int f=threadIdx.x;f<FF;f+=256) m=fmaxf(m, Wr[b*601+rel[b*FF+f]]);
  red[threadIdx.x]=m; __syncthreads();
  for(int o=128;o;o>>=1){ if(threadIdx.x<o) red[threadIdx.x]=fmaxf(red[threadIdx.x],red[threadIdx.x+o]); __syncthreads(); }
  if(!threadIdx.x) wmax[b]=red[0];
}
__global__ __launch_bounds__(256) void k_wt(const float* Wr, const int* rel,
    const float* wmax, const int* e2f, float* wt, float* e2fs){
  int i = blockIdx.x*256+threadIdx.x;
  int b = i>>13;
  float v = expf(Wr[b*601+rel[i]] - wmax[b]);
  wt[i]=v;
  atomicAdd(e2fs + (b<<11) + e2f[i], v);
}
__global__ __launch_bounds__(256) void k_prinit(const void* adj, float* pr, const int* dfl){
  const int isf=*dfl;
  int i4=(blockIdx.x*256+threadIdx.x)*4;
  if(isf){ *(float4*)(pr+i4)=*(const float4*)((const float*)adj+i4); }
  else { float v[4]; ld4bf((const bf16*)adj+i4,v);
         float4 t; t.x=v[0];t.y=v[1];t.z=v[2];t.w=v[3]; *(float4*)(pr+i4)=t; }
}

// ---------------- MFMA GEMM: C[M,256] = A[M,K] @ W[256,K]^T, no LDS ----------------
struct MG {
  const bf16* A; const bf16* W; const bf16* bias;
  bf16* out; int K;
  const bf16* Aq2; const bf16* Af2;
  const int* cnt; const bf16* addb;
};
template<int CONCAT,int EPI>
__global__ __launch_bounds__(256) void k_mgemm(MG p){
  const int m0 = blockIdx.x*64;
  const int wave = threadIdx.x>>6, lane = threadIdx.x&63;
  const int q = lane>>4, l16 = lane&15;
  const int n0 = wave*64;
  const int bidx_ = m0>>11;
  f32x4 acc[4][4];
  #pragma unroll
  for(int i=0;i<4;i++)
    #pragma unroll
    for(int j=0;j<4;j++) acc[i][j]=(f32x4){0.f,0.f,0.f,0.f};
  const int K=p.K;
  for(int k0=0;k0<K;k0+=32){
    int kk=k0+q*8;
    bf16x8 af[4], bw[4];
    #pragma unroll
    for(int mi=0;mi<4;mi++){
      int row=m0+mi*16+l16;
      const bf16* ap;
      if(CONCAT){
        if(kk<256)      ap=p.A  +(long)row*256+kk;
        else if(kk<512) ap=p.Aq2+(bidx_<<8)+(kk-256);
        else            ap=p.Af2+(long)row*256+(kk-512);
      } else ap=p.A+(long)row*K+kk;
      af[mi]=*(const bf16x8*)ap;
    }
    #pragma unroll
    for(int ni=0;ni<4;ni++)
      bw[ni]=*(const bf16x8*)(p.W+(long)(n0+ni*16+l16)*K+kk);
    #pragma unroll
    for(int mi=0;mi<4;mi++)
      #pragma unroll
      for(int ni=0;ni<4;ni++)
        acc[mi][ni]=__builtin_amdgcn_mfma_f32_16x16x32_bf16(af[mi],bw[ni],acc[mi][ni],0,0,0);
  }
  #pragma unroll
  for(int ni=0;ni<4;ni++){
    int col=n0+ni*16+l16;
    float bv=b2f(p.bias[col]);
    #pragma unroll
    for(int mi=0;mi<4;mi++){
      #pragma unroll
      for(int r=0;r<4;r++){
        int row=m0+mi*16+q*4+r;
        float v=acc[mi][ni][r];
        if(EPI==0) v+=bv;
        else if(EPI==1) v=fmaxf(v+bv,0.f);
        else {
          v += (float)p.cnt[row]*bv + b2f(p.addb[(long)row*256+col]);
          v=fmaxf(v,0.f);
        }
        p.out[(long)row*256+col]=f2b(v);
      }
    }
  }
}

// ---------------- per-layer small mats ----------------
__global__ __launch_bounds__(256) void k_small(const float* rel_lin, const bf16* selfw,
    const bf16* selfb, const float* qnode, const bf16* q2ew, const bf16* q2eb,
    float* relself, float* q2ev, bf16* q2evb){
  __shared__ float xr[DD];
  int d=threadIdx.x;
  if(blockIdx.x<601){
    int r=blockIdx.x;
    xr[d]=rel_lin[r*DD+d]; __syncthreads();
    float acc=b2f(selfb[d]);
    const bf16* wr=selfw+(long)d*DD;
    for(int k4=0;k4<DD;k4+=4){
      float v[4]; ld4bf(wr+k4,v);
      acc+=v[0]*xr[k4]+v[1]*xr[k4+1]+v[2]*xr[k4+2]+v[3]*xr[k4+3];
    }
    relself[r*DD+d]=acc;
  } else {
    int b=blockIdx.x-601;
    xr[d]=qnode[(b<<8)+d]; __syncthreads();
    float acc=b2f(q2eb[d]);
    const bf16* wr=q2ew+(long)d*DD;
    for(int k4=0;k4<DD;k4+=4){
      float v[4]; ld4bf(wr+k4,v);
      acc+=v[0]*xr[k4]+v[1]*xr[k4+1]+v[2]*xr[k4+2]+v[3]*xr[k4+3];
    }
    q2ev[(b<<8)+d]=acc;
    q2evb[(b<<8)+d]=f2b(acc);
  }
}

// ---------------- norm + pagerank numerator scatter ----------------
__global__ __launch_bounds__(256) void k_norm(const float* wt, const float* pr,
    const float* e2fs, const int* e2f, const int* f2e, float* normv, float* pragg){
  int i=blockIdx.x*256+threadIdx.x;
  int b=i>>13;
  int e=e2f[i];
  float v=wt[i]*pr[(b<<11)+e]/fmaxf(e2fs[(b<<11)+e],1e-10f);
  normv[i]=v;
  atomicAdd(pragg+(b<<11)+f2e[i], v);
}

// ---------------- segmented fact aggregation (atomic-free) ----------------
__global__ __launch_bounds__(256) void k_agg(const int* bstart, const int* bidx,
    const int* rel, const int* e2f, const float* normv, const float* relself,
    const bf16* head, bf16* agg){
  int eidx=blockIdx.x*4+(threadIdx.x>>6);
  int lane=threadIdx.x&63;
  int b=eidx>>11;
  float a0=0.f,a1=0.f,a2=0.f,a3=0.f;
  int s=bstart[eidx], e=bstart[eidx+1];
  for(int i=s;i<e;i++){
    int f=bidx[i];
    int r=rel[f]; int ent=e2f[f]; float nv=normv[f];
    float4 rs=*(const float4*)&relself[r*DD+lane*4];
    float hd[4]; ld4bf(head+(long)(((b<<11)+ent)*DD+lane*4),hd);
    a0+=fmaxf(rs.x+hd[0],0.f)*nv; a1+=fmaxf(rs.y+hd[1],0.f)*nv;
    a2+=fmaxf(rs.z+hd[2],0.f)*nv; a3+=fmaxf(rs.w+hd[3],0.f)*nv;
  }
  st4bf(agg+(long)eidx*DD+lane*4, a0,a1,a2,a3);
}

// ---------------- weighted row-sums (fused pagerank update) ----------------
__global__ __launch_bounds__(256) void k_wnxt(const float* pragg, float* pr, const bf16* le,
    const bf16* f2e, float* wnxt, float* prsum){
  int b=blockIdx.x, ch=blockIdx.y, d=threadIdx.x;
  float a1=0.f,a3=0.f,ap=0.f;
  int e0=ch*256;
  #pragma unroll 4
  for(int e=e0;e<e0+256;e++){
    int pe=(b<<11)+e;
    float p=0.8f*pragg[pe]+0.2f*pr[pe];
    if(d==0) pr[pe]=p;
    long base=(long)pe<<8;
    a1+=p*b2f(le[base+d]);
    a3+=p*b2f(f2e[base+d]);
    ap+=p;
  }
  atomicAdd(&wnxt[b*768+d],a1);
  atomicAdd(&wnxt[b*768+512+d],a3);
  if(d==0) atomicAdd(&prsum[b],ap);
}

// note: e2q_w tail cols pre-scaled by 3 at cvt -> xr segment 3 is plain a3
__global__ __launch_bounds__(256) void k_qnode(const float* wnxt, const float* prsum,
    const float* q2ev, const bf16* w, const bf16* bias, float* qnode){
  int b=blockIdx.x, d=threadIdx.x;
  __shared__ float xr[768];
  float ps=prsum[b];
  xr[d]=wnxt[b*768+d];
  xr[256+d]=ps*q2ev[(b<<8)+d];
  xr[512+d]=wnxt[b*768+512+d];
  __syncthreads();
  float acc=0.f;
  const bf16* wr=w+(long)d*768;
  for(int k4=0;k4<768;k4+=4){
    float v[4]; ld4bf(wr+k4,v);
    acc+=v[0]*xr[k4]+v[1]*xr[k4+1]+v[2]*xr[k4+2]+v[3]*xr[k4+3];
  }
  qnode[(b<<8)+d]=acc+ps*b2f(bias[d]);
}

// ---------------- score ----------------
__global__ __launch_bounds__(256) void k_score(const bf16* le, const bf16* sw,
    const bf16* sb, void* out, const int* dfl){
  const int isf=*dfl;
  int o=blockIdx.x*4 + (threadIdx.x>>6);
  int lane=threadIdx.x&63;
  float v[4],wv[4];
  ld4bf(le+(long)o*DD+lane*4,v); ld4bf(sw+lane*4,wv);
  float acc=v[0]*wv[0]+v[1]*wv[1]+v[2]*wv[2]+v[3]*wv[3];
  for(int off=32;off;off>>=1) acc+=__shfl_down(acc,off,64);
  if(!lane){
    float r=acc+b2f(sb[0]);
    if(isf) ((float*)out)[o]=r; else ((bf16*)out)[o]=f2b(r);
  }
}

// ---------------- host ----------------
extern "C" void kernel_launch(void* const* d_in, const int* in_sizes, int n_in,
                              void* d_out, int out_size, void* d_ws, size_t ws_size,
                              hipStream_t stream){
  const int*  local_entity=(const int*)d_in[0];
  const void* q2e_adj     =d_in[1];
  const int*  kb_fact_rel =(const int*)d_in[2];
  const int*  query_text  =(const int*)d_in[3];
  const int*  e2f_ent     =(const int*)d_in[5];
  const int*  f2e_ent     =(const int*)d_in[6];
  const void* word_emb    =d_in[7];
  const void* entity_emb  =d_in[8];
  const void* relation_emb=d_in[9];

  char* ws=(char*)d_ws;
  float* gx      =(float*)(ws+O_GX);
  float* qh      =(float*)(ws+O_QH);
  float* qnode   =(float*)(ws+O_QNODE);
  float* rel_lin =(float*)(ws+O_RELLIN);
  float* Wr      =(float*)(ws+O_WR);
  float* wmax    =(float*)(ws+O_WMAX);
  float* wt      =(float*)(ws+O_WT);
  float* e2fs    =(float*)(ws+O_E2FS);
  float* pr      =(float*)(ws+O_PR);
  float* pragg   =(float*)(ws+O_PRAGG);
  float* q2ev    =(float*)(ws+O_Q2EV);
  bf16*  q2evb   =(bf16*)(ws+O_Q2EVB);
  float* relself =(float*)(ws+O_RELSELF);
  float* normv   =(float*)(ws+O_NORM);
  float* wnxt    =(float*)(ws+O_WNXT);
  float* prsum   =(float*)(ws+O_PRSUM);
  int*   cnt     =(int*)(ws+O_CNT);
  int*   cur     =(int*)(ws+O_CUR);
  int*   bstart  =(int*)(ws+O_BSTART);
  int*   bidx    =(int*)(ws+O_BIDX);
  bf16*  elwpad  =(bf16*)(ws+O_ELWPAD);
  int*   dflag   =(int*)(ws+O_FLAG);
  bf16*  cw      =(bf16*)(ws+O_CVT);
  bf16*  agg     =(bf16*)(ws+O_AGG);
  bf16*  A0      =(bf16*)(ws+O_AGG);      // aliases agg + start of entself (pre-layer use only)
  bf16*  entself =(bf16*)(ws+O_ENTSELF);
  bf16*  leA     =(bf16*)(ws+O_LEA);
  bf16*  leB     =(bf16*)(ws+O_LEB);
  bf16*  headb   =(bf16*)(ws+O_HEAD);
  bf16*  f2eemb  =(bf16*)(ws+O_F2EEMB);
  // LSTM h-exchange: aliases leA (dead until the first mgemm, which runs after the LSTM)
  bf16*  hbuf    =(bf16*)(ws+O_LEA);              // 2 slots x 16x256 bf16 = 16KB
  int*   lcnt    =(int*)(ws+O_LEA+16384);         // 20 step flags

  k_sniff<<<1,256,0,stream>>>((const unsigned short*)entity_emb, dflag);

  CvtJobs J;
  int cntj=0;
  auto add=[&](int in_idx, long coff, int n, int sc){
    J.src[cntj]=d_in[in_idx]; J.dst[cntj]=cw+coff; J.n[cntj]=n; J.sc[cntj]=sc; cntj++;
  };
  add(11,C_ELB,256,0);
  add(12,C_RLW,153600,0);  add(13,C_RLB,256,0);
  add(14,C_WIH,307200,0);
  add(16,C_BIH,1024,0);    add(17,C_BHH,1024,0);
  add(18,C_Q2EW,196608,0); add(19,C_Q2EB,768,0);
  add(20,C_E2QW,589824,1); add(21,C_E2QB,768,0);
  add(22,C_E2EW,589824,1); add(23,C_E2EB,768,0);
  add(24,C_KHW,196608,0);  add(25,C_KHB,768,0);
  add(26,C_KTW,196608,0);  add(27,C_KTB,768,0);
  add(28,C_KSW,196608,0);  add(29,C_KSB,768,0);
  add(30,C_SCW,256,0);     add(31,C_SCB,1,0);
  k_cvt<<<dim3(576,20),256,0,stream>>>(J, dflag);
  k_cvtwhh<<<128,256,0,stream>>>(d_in[15], cw+C_WHH, dflag);
  k_cvtelw<<<256,256,0,stream>>>(d_in[10], elwpad, dflag);

  // CSR bucketing (fact graph is launch-constant); cnt+cur adjacent -> one memset
  hipMemsetAsync(cnt, 0, (size_t)2*BB*EE*4, stream);
  k_cnt <<<BB*FF/256,256,0,stream>>>(f2e_ent, cnt);
  k_scan<<<1,1024,0,stream>>>(cnt, bstart);
  k_fill<<<BB*FF/256,256,0,stream>>>(f2e_ent, bstart, cur, bidx);

  k_gx   <<<BB*QQ,256,0,stream>>>(query_text, word_emb, cw+C_WIH, cw+C_BIH, cw+C_BHH, gx, dflag);
  hipMemsetAsync(lcnt, 0, 128, stream);
  k_lstm3<<<NLB,256,0,stream>>>(gx, cw+C_WHH, qh, qnode, hbuf, lcnt);
  k_rel_lin<<<601,256,0,stream>>>(relation_emb, cw+C_RLW, cw+C_RLB, rel_lin, dflag);
  k_simwr<<<dim3(BB,3),256,0,stream>>>(qh, rel_lin, query_text, Wr);
  k_wmax <<<BB,256,0,stream>>>(Wr, kb_fact_rel, wmax);
  hipMemsetAsync(e2fs, 0, (size_t)BB*EE*4, stream);
  k_wt   <<<BB*FF/256,256,0,stream>>>(Wr, kb_fact_rel, wmax, e2f_ent, wt, e2fs);
  k_prinit<<<BB*EE/1024,256,0,stream>>>(q2e_adj, pr, dflag);

  // le = entity_emb[local_entity] @ elw^T + elb   (K padded to 320)
  k_ga0<<<BB*EE,128,0,stream>>>(local_entity, entity_emb, A0, dflag);
  {
    MG p{}; p.A=A0; p.W=elwpad; p.bias=cw+C_ELB; p.out=leA; p.K=320;
    k_mgemm<0,0><<<BB*EE/64,256,0,stream>>>(p);
  }

  bf16* le_cur=leA; bf16* le_nxt=leB;
  for(int i=0;i<3;i++){
    k_small<<<617,256,0,stream>>>(rel_lin, cw+C_KSW+(long)i*65536, cw+C_KSB+(long)i*256,
        qnode, cw+C_Q2EW+(long)i*65536, cw+C_Q2EB+(long)i*256, relself, q2ev, q2evb);
    {
      MG p{}; p.A=le_cur; p.W=cw+C_KHW+(long)i*65536; p.bias=cw+C_KHB+(long)i*256;
      p.out=headb; p.K=256;
      k_mgemm<0,0><<<BB*EE/64,256,0,stream>>>(p);
    }
    {
      MG p{}; p.A=le_cur; p.W=cw+C_KSW+(long)i*65536; p.bias=cw+C_KSB+(long)i*256;
      p.out=entself; p.K=256;
      k_mgemm<0,0><<<BB*EE/64,256,0,stream>>>(p);
    }
    hipMemsetAsync(pragg, 0, (size_t)BB*EE*4, stream);
    k_norm<<<BB*FF/256,256,0,stream>>>(wt, pr, e2fs, e2f_ent, f2e_ent, normv, pragg);
    k_agg <<<BB*EE/4,256,0,stream>>>(bstart, bidx, kb_fact_rel, e2f_ent, normv, relself, headb, agg);
    {
      MG p{}; p.A=agg; p.W=cw+C_KTW+(long)i*65536; p.bias=cw+C_KTB+(long)i*256;
      p.out=f2eemb; p.K=256; p.cnt=cnt; p.addb=entself;
      k_mgemm<0,2><<<BB*EE/64,256,0,stream>>>(p);
    }
    hipMemsetAsync(wnxt, 0, (size_t)(BB*768*4+256), stream);
    k_wnxt <<<dim3(BB,8),256,0,stream>>>(pragg, pr, le_cur, f2eemb, wnxt, prsum);
    k_qnode<<<BB,256,0,stream>>>(wnxt, prsum, q2ev, cw+C_E2QW+(long)i*196608, cw+C_E2QB+(long)i*256, qnode);
    {
      MG p{}; p.A=le_cur; p.W=cw+C_E2EW+(long)i*196608; p.bias=cw+C_E2EB+(long)i*256;
      p.out=le_nxt; p.K=768; p.Aq2=q2evb; p.Af2=f2eemb;
      k_mgemm<1,1><<<BB*EE/64,256,0,stream>>>(p);
    }
    bf16* t=le_cur; le_cur=le_nxt; le_nxt=t;
  }

  k_score<<<BB*EE/4,256,0,stream>>>(le_cur, cw+C_SCW, cw+C_SCB, d_out, dflag);
}

// Round 2
// 1126.561 us; speedup vs baseline: 1.2437x; 1.1494x over previous
//
#include <hip/hip_runtime.h>
#include <hip/hip_bf16.h>

typedef __hip_bfloat16 bf16;
typedef __attribute__((ext_vector_type(8))) short bf16x8;
typedef __attribute__((ext_vector_type(4))) float f32x4;

#define BB 16
#define EE 2048
#define FF 8192
#define QQ 20
#define DD 256
#define WDIM 300
#define NWORD 50000
#define VERY_NEG_F (-1.0e11f)

static __device__ __forceinline__ float b2f(bf16 x){ return __bfloat162float(x); }
static __device__ __forceinline__ bf16 f2b(float x){ return __float2bfloat16(x); }
static __device__ __forceinline__ float sigm(float x){ return 1.f/(1.f+expf(-x)); }
static __device__ __forceinline__ void ld4bf(const bf16* p, float v[4]){
  short4 s = *(const short4*)p;
  v[0]=b2f(*(const bf16*)&s.x); v[1]=b2f(*(const bf16*)&s.y);
  v[2]=b2f(*(const bf16*)&s.z); v[3]=b2f(*(const bf16*)&s.w);
}
static __device__ __forceinline__ void st4bf(bf16* p, float a,float b,float c,float d){
  unsigned short u[4]; bf16 t;
  t=f2b(a);u[0]=*(unsigned short*)&t; t=f2b(b);u[1]=*(unsigned short*)&t;
  t=f2b(c);u[2]=*(unsigned short*)&t; t=f2b(d);u[3]=*(unsigned short*)&t;
  *(short4*)p=*(short4*)u;
}

// ---------------- workspace offsets (bytes) ----------------
#define O_GX       0UL
#define O_QH       1310720UL
#define O_QNODE    1638400UL
#define O_RELLIN   1654784UL
#define O_WR       2270208UL
#define O_WMAX     2308864UL
#define O_WT       2309120UL
#define O_E2FS     2833408UL
#define O_PR       2964480UL
#define O_PRAGG    3095552UL
#define O_Q2EV     3226624UL
#define O_Q2EVB    3243008UL
#define O_RELSELF  3251200UL
#define O_NORM     3866624UL
#define O_WNXT     4390912UL
#define O_PRSUM    4440064UL
#define O_CNT      4440320UL
#define O_CUR      4571392UL
#define O_BSTART   4702464UL
#define O_BIDX     4834048UL
#define O_ELWPAD   5358336UL
#define O_FLAG     5522176UL
#define O_CVT      5522432UL   // 5393152 B
#define O_AGG      10915584UL  // bf16 16.7MB; A0 (21MB) aliases AGG+start of ENTSELF
#define O_ENTSELF  27692800UL
#define O_LEA      44470016UL
#define O_LEB      61247232UL
#define O_HEAD     78024448UL
#define O_F2EEMB   94801664UL  // end ~111.6MB

// canonical element offsets within O_CVT (all mult of 8)
#define C_ELB   0
#define C_RLW   256
#define C_RLB   153856
#define C_WIH   154112
#define C_WHH   461312   // frag-linear w_hh (262144 elems)
#define C_BIH   723456
#define C_BHH   724480
#define C_Q2EW  725504
#define C_Q2EB  922112
#define C_E2QW  922880
#define C_E2QB  1512704
#define C_E2EW  1513472
#define C_E2EB  2103296
#define C_KHW   2104064
#define C_KHB   2300672
#define C_KTW   2301440
#define C_KTB   2498048
#define C_KSW   2498816
#define C_KSB   2695424
#define C_SCW   2696192
#define C_SCB   2696448

// ---------------- dtype sniffer (verified r2) ----------------
__global__ __launch_bounds__(256) void k_sniff(const unsigned short* ee, int* flag){
  __shared__ int red[256];
  int c=0;
  for(int i=threadIdx.x;i<4096;i+=256){
    int ex=(ee[2*i]>>7)&0xFF;
    c += (ex>=192);
  }
  red[threadIdx.x]=c; __syncthreads();
  for(int o=128;o;o>>=1){ if(threadIdx.x<o) red[threadIdx.x]+=red[threadIdx.x+o]; __syncthreads(); }
  if(!threadIdx.x) flag[0] = (red[0]>64) ? 1 : 0;
}

// ---------------- batched weight canonicalization -> bf16 (tail-scale for e2q/e2e) ----------------
struct CvtJobs{ const void* src[20]; bf16* dst[20]; int n[20]; int sc[20]; };
__global__ __launch_bounds__(256) void k_cvt(CvtJobs J, const int* dfl){
  const int isf=*dfl;
  int j=blockIdx.y;
  int n=J.n[j];
  int i4=(blockIdx.x*256+threadIdx.x)*4;
  if(i4>=n) return;
  float m = (J.sc[j] && ((i4%768)>=512)) ? 3.f : 1.f;
  bf16* d=J.dst[j]+i4;
  if(isf){
    const float* s=(const float*)J.src[j]+i4;
    if(i4+4<=n){ float4 t=*(const float4*)s; st4bf(d,t.x*m,t.y*m,t.z*m,t.w*m); }
    else for(int r=0;i4+r<n;r++) d[r]=f2b(s[r]*m);
  } else {
    const bf16* s=(const bf16*)J.src[j]+i4;
    if(i4+4<=n){ float v[4]; ld4bf(s,v); st4bf(d,v[0]*m,v[1]*m,v[2]*m,v[3]*m); }
    else for(int r=0;i4+r<n;r++) d[r]=f2b(b2f(s[r])*m);
  }
}

// w_hh (1024x256) -> MFMA-fragment-linear: wf[gt][kt][lane][8], gate=gt*16+(lane&15), k=kt*32+(lane>>4)*8+j
__global__ __launch_bounds__(256) void k_cvtwhh(const void* src, bf16* wf, const int* dfl){
  const int isf=*dfl;
  int fid=blockIdx.x*256+threadIdx.x;        // 0..32767
  int lane=fid&63, kt=(fid>>6)&7, gt=fid>>9;
  int l16=lane&15, q=lane>>4;
  long so=(long)(gt*16+l16)*256 + kt*32 + q*8;
  float v[8];
  if(isf){ const float* s=(const float*)src+so;
    #pragma unroll
    for(int j=0;j<8;j++) v[j]=s[j];
  } else { const bf16* s=(const bf16*)src+so; ld4bf(s,v); ld4bf(s+4,v+4); }
  bf16* d=wf+(long)fid*8;
  st4bf(d,v[0],v[1],v[2],v[3]); st4bf(d+4,v[4],v[5],v[6],v[7]);
}

// entity_lin_w (256x300) -> padded bf16 (256x320)
__global__ __launch_bounds__(256) void k_cvtelw(const void* src, bf16* dst, const int* dfl){
  const int isf=*dfl;
  int r=blockIdx.x;
  for(int c=threadIdx.x;c<320;c+=256){
    float v=0.f;
    if(c<300) v = isf ? ((const float*)src)[r*300+c] : b2f(((const bf16*)src)[r*300+c]);
    dst[(long)r*320+c]=f2b(v);
  }
}

// gathered, padded A0[32768][320] = entity_emb[local_entity]
__global__ __launch_bounds__(128) void k_ga0(const int* idx, const void* emb, bf16* A0, const int* dfl){
  const int isf=*dfl;
  int row=blockIdx.x; int ent=idx[row]; int t=threadIdx.x;
  bf16* dst=A0+(long)row*320;
  if(t<75){
    float v[4];
    if(isf){ float4 x=*(const float4*)((const float*)emb+(long)ent*WDIM+t*4);
             v[0]=x.x;v[1]=x.y;v[2]=x.z;v[3]=x.w; }
    else ld4bf((const bf16*)emb+(long)ent*WDIM+t*4, v);
    st4bf(dst+t*4, v[0],v[1],v[2],v[3]);
  } else if(t<80){
    st4bf(dst+t*4, 0.f,0.f,0.f,0.f);
  }
}

// ---------------- CSR bucketing of facts by (b, f2e_ent) ----------------
__global__ __launch_bounds__(256) void k_cnt(const int* f2e, int* cnt){
  int i=blockIdx.x*256+threadIdx.x;
  atomicAdd(&cnt[((i>>13)<<11)+f2e[i]], 1);
}
__global__ __launch_bounds__(1024) void k_scan(const int* cnt, int* bstart){
  __shared__ int ps[1024];
  int t=threadIdx.x;
  int loc[32]; int s=0;
  #pragma unroll
  for(int j=0;j<32;j++){ loc[j]=s; s+=cnt[t*32+j]; }
  ps[t]=s; __syncthreads();
  for(int off=1;off<1024;off<<=1){
    int v=(t>=off)?ps[t-off]:0;
    __syncthreads(); ps[t]+=v; __syncthreads();
  }
  int base=(t? ps[t-1]:0);
  #pragma unroll
  for(int j=0;j<32;j++) bstart[t*32+j]=base+loc[j];
  if(t==1023) bstart[32768]=ps[1023];
}
__global__ __launch_bounds__(256) void k_fill(const int* f2e, const int* bstart, int* cur, int* bidx){
  int i=blockIdx.x*256+threadIdx.x;
  int key=((i>>13)<<11)+f2e[i];
  int pos=bstart[key]+atomicAdd(&cur[key],1);
  bidx[pos]=i;
}

// ---------------- gx = wemb[qtext] @ w_ih^T + b_ih + b_hh ----------------
__global__ __launch_bounds__(256) void k_gx(const int* qtext, const void* wemb,
    const bf16* wih, const bf16* bih, const bf16* bhh, float* gx, const int* dfl){
  const int isf=*dfl;
  int bt=blockIdx.x;
  __shared__ float xr[WDIM];
  int w=qtext[bt];
  for(int k4=threadIdx.x*4;k4<WDIM;k4+=1024){
    if(isf){ float4 t=*(const float4*)((const float*)wemb+(long)w*WDIM+k4);
             xr[k4]=t.x;xr[k4+1]=t.y;xr[k4+2]=t.z;xr[k4+3]=t.w; }
    else   { float v[4]; ld4bf((const bf16*)wemb+(long)w*WDIM+k4,v);
             xr[k4]=v[0];xr[k4+1]=v[1];xr[k4+2]=v[2];xr[k4+3]=v[3]; }
  }
  __syncthreads();
  #pragma unroll
  for(int s=0;s<4;s++){
    int g=threadIdx.x+256*s;
    float acc=b2f(bih[g])+b2f(bhh[g]);
    const bf16* wr=wih+(long)g*WDIM;
    for(int k4=0;k4<WDIM;k4+=4){
      float v[4]; ld4bf(wr+k4,v);
      acc+=v[0]*xr[k4]+v[1]*xr[k4+1]+v[2]*xr[k4+2]+v[3]*xr[k4+3];
    }
    gx[bt*1024+g]=acc;
  }
}

// ---------------- distributed MFMA LSTM: 16 blocks, W slice in registers ----------------
#define NLB 16
__global__ __launch_bounds__(256) void k_lstm3(const float* gx, const bf16* wf,
    float* qh, float* qnode, bf16* hbuf, int* lcnt){
  __shared__ bf16  hlds[16*264];     // padded rows: 528B stride -> 2-way LDS aliasing (free)
  __shared__ float zs[4*16*16];      // [gate-type][batch][u_local]
  __shared__ bf16  hsl[256];         // outgoing h slice [batch][u_local]
  const int k=blockIdx.x;
  const int tid=threadIdx.x;
  const int wv=tid>>6, lane=tid&63, q=lane>>4, l16=lane&15;
  const int b=tid>>4, u=tid&15, gu=k*16+u;
  // W fragments for this wave's gate tile (gt = wv*16+k), canonical wf layout (k_cvtwhh)
  bf16x8 wreg[8];
  #pragma unroll
  for(int kt=0;kt<8;kt++)
    wreg[kt]=*(const bf16x8*)(wf + (((long)((wv*16+k)*8+kt))*64 + lane)*8);
  float c=0.f;
  float gxr[4];
  #pragma unroll
  for(int g=0;g<4;g++) gxr[g]=gx[(b*QQ+0)*1024 + g*256 + gu];
  for(int t=0;t<QQ;t++){
    f32x4 acc=(f32x4){0.f,0.f,0.f,0.f};
    if(t){
      if(tid==0){
        while(__hip_atomic_load(lcnt+(t-1), __ATOMIC_ACQUIRE, __HIP_MEMORY_SCOPE_AGENT) < NLB)
          __builtin_amdgcn_s_sleep(1);
      }
      __syncthreads();
      // pull full h (8KB) -> LDS via agent-scope loads (bypass stale per-XCD L2)
      const bf16* hb = hbuf + (t&1)*4096;
      #pragma unroll
      for(int ii=0;ii<4;ii++){
        int i=tid+ii*256;
        int r=i>>6, cc=i&63;
        unsigned long long v=__hip_atomic_load((const unsigned long long*)(hb + r*256 + cc*4),
                       __ATOMIC_RELAXED, __HIP_MEMORY_SCOPE_AGENT);
        *(unsigned long long*)&hlds[r*264 + cc*4] = v;
      }
      __syncthreads();
      #pragma unroll
      for(int kt=0;kt<8;kt++){
        bf16x8 af=*(const bf16x8*)&hlds[l16*264 + kt*32 + q*8];
        acc=__builtin_amdgcn_mfma_f32_16x16x32_bf16(af,wreg[kt],acc,0,0,0);
      }
    }
    #pragma unroll
    for(int r=0;r<4;r++) zs[wv*256 + (q*4+r)*16 + l16]=acc[r];
    __syncthreads();
    float zi=zs[0*256+tid]+gxr[0];
    float zf=zs[1*256+tid]+gxr[1];
    float zg=zs[2*256+tid]+gxr[2];
    float zo=zs[3*256+tid]+gxr[3];
    { // prefetch next step's gx (time-invariant data, safe to cache)
      int tn=(t<QQ-1)?t+1:t;
      #pragma unroll
      for(int g=0;g<4;g++) gxr[g]=gx[(b*QQ+tn)*1024 + g*256 + gu];
    }
    c=sigm(zf)*c+sigm(zi)*tanhf(zg);
    float hv=sigm(zo)*tanhf(c);
    hsl[tid]=f2b(hv);
    qh[(long)(b*QQ+t)*256+gu]=hv;
    if(t==QQ-1) qnode[(b<<8)+gu]=hv;
    __syncthreads();
    if(t<QQ-1){
      if(tid<64){ // publish our 512B h slice, agent-scope
        bf16* hw=hbuf + ((t+1)&1)*4096;
        int bb=tid>>2, p=tid&3;
        unsigned long long v=*(unsigned long long*)&hsl[bb*16+p*4];
        __hip_atomic_store((unsigned long long*)(hw + bb*256 + k*16 + p*4), v,
                           __ATOMIC_RELAXED, __HIP_MEMORY_SCOPE_AGENT);
      }
      __syncthreads();   // drains vmcnt: slice stores globally visible
      if(tid==0){
        __threadfence();
        __hip_atomic_fetch_add(lcnt+t, 1, __ATOMIC_RELEASE, __HIP_MEMORY_SCOPE_AGENT);
      }
    }
  }
}

// ---------------- rel_lin ----------------
__global__ __launch_bounds__(256) void k_rel_lin(const void* remb, const bf16* rlw,
    const bf16* rlb, float* rel_lin, const int* dfl){
  const int isf=*dfl;
  int r=blockIdx.x;
  __shared__ float rr[2*WDIM];
  for(int k4=threadIdx.x*4;k4<2*WDIM;k4+=1024){
    if(isf){ float4 t=*(const float4*)((const float*)remb+(long)r*2*WDIM+k4);
             rr[k4]=t.x;rr[k4+1]=t.y;rr[k4+2]=t.z;rr[k4+3]=t.w; }
    else   { float v[4]; ld4bf((const bf16*)remb+(long)r*2*WDIM+k4,v);
             rr[k4]=v[0];rr[k4+1]=v[1];rr[k4+2]=v[2];rr[k4+3]=v[3]; }
  }
  __syncthreads();
  int d=threadIdx.x;
  float acc=b2f(rlb[d]);
  const bf16* wr=rlw+(long)d*2*WDIM;
  for(int k4=0;k4<2*WDIM;k4+=4){
    float v[4]; ld4bf(wr+k4,v);
    acc+=v[0]*rr[k4]+v[1]*rr[k4+1]+v[2]*rr[k4+2]+v[3]*rr[k4+3];
  }
  rel_lin[r*DD+d]=acc;
}

// ---------------- sim + masked softmax + Wr (relation space) ----------------
__global__ __launch_bounds__(256) void k_simwr(const float* qh, const float* rel_lin,
    const int* qtext, float* Wr){
  int b = blockIdx.x, rc = blockIdx.y;
  __shared__ float qhb[QQ*DD];
  __shared__ float qm[QQ];
  for(int i=threadIdx.x;i<QQ*DD;i+=256) qhb[i]=qh[b*QQ*DD+i];
  if(threadIdx.x<QQ) qm[threadIdx.x] = (qtext[b*QQ+threadIdx.x]!=NWORD)?0.f:VERY_NEG_F;
  __syncthreads();
  int r = rc*256+threadIdx.x;
  if(r>=601) return;
  float s[QQ];
  #pragma unroll
  for(int q=0;q<QQ;q++) s[q]=0.f;
  for(int k=0;k<DD;k++){
    float rl = rel_lin[r*DD+k];
    #pragma unroll
    for(int q=0;q<QQ;q++) s[q] += qhb[q*DD+k]*rl;
  }
  float m=-1e30f;
  #pragma unroll
  for(int q=0;q<QQ;q++){ s[q]*=0.0625f; m=fmaxf(m, s[q]+qm[q]); }
  float sum=0.f, w=0.f;
  #pragma unroll
  for(int q=0;q<QQ;q++){ float p=expf(s[q]+qm[q]-m); sum+=p; w+=p*s[q]; }
  Wr[b*601+r] = w/sum;
}

// ---------------- Wmax / W_tilde / e2f_softmax / pr init ----------------
__global__ __launch_bounds__(256) void k_wmax(const float* Wr, const int* rel, float* wmax){
  int b=blockIdx.x; __shared__ float red[256];
  float m=-1e30f;
  for(int f=threadIdx.x;f<FF;f+=256) m=fmaxf(m, Wr[b*601+rel[b*FF+f]]);
  red[threadIdx.x]=m; __syncthreads();
  for(int o=128;o;o>>=1){ if(threadIdx.x<o) red[threadIdx.x]=fmaxf(red[threadIdx.x],red[threadIdx.x+o]); __syncthreads(); }
  if(!threadIdx.x) wmax[b]=red[0];
}
__global__ __launch_bounds__(256) void k_wt(const float* Wr, const int* rel,
    const float* wmax, const int* e2f, float* wt, float* e2fs){
  int i = blockIdx.x*256+threadIdx.x;
  int b = i>>13;
  float v = expf(Wr[b*601+rel[i]] - wmax[b]);
  wt[i]=v;
  atomicAdd(e2fs + (b<<11) + e2f[i], v);
}
__global__ __launch_bounds__(256) void k_prinit(const void* adj, float* pr, const int* dfl){
  const int isf=*dfl;
  int i4=(blockIdx.x*256+threadIdx.x)*4;
  if(isf){ *(float4*)(pr+i4)=*(const float4*)((const float*)adj+i4); }
  else { float v[4]; ld4bf((const bf16*)adj+i4,v);
         float4 t; t.x=v[0];t.y=v[1];t.z=v[2];t.w=v[3]; *(float4*)(pr+i4)=t; }
}

// ---------------- MFMA GEMM: C[M,256] = A[M,K] @ W[256,K]^T, no LDS ----------------
struct MG {
  const bf16* A; const bf16* W; const bf16* bias;
  bf16* out; int K;
  const bf16* Aq2; const bf16* Af2;
  const int* cnt; const bf16* addb;
};
template<int CONCAT,int EPI>
__global__ __launch_bounds__(256) void k_mgemm(MG p){
  const int m0 = blockIdx.x*64;
  const int wave = threadIdx.x>>6, lane = threadIdx.x&63;
  const int q = lane>>4, l16 = lane&15;
  const int n0 = wave*64;
  const int bidx_ = m0>>11;
  f32x4 acc[4][4];
  #pragma unroll
  for(int i=0;i<4;i++)
    #pragma unroll
    for(int j=0;j<4;j++) acc[i][j]=(f32x4){0.f,0.f,0.f,0.f};
  const int K=p.K;
  for(int k0=0;k0<K;k0+=32){
    int kk=k0+q*8;
    bf16x8 af[4], bw[4];
    #pragma unroll
    for(int mi=0;mi<4;mi++){
      int row=m0+mi*16+l16;
      const bf16* ap;
      if(CONCAT){
        if(kk<256)      ap=p.A  +(long)row*256+kk;
        else if(kk<512) ap=p.Aq2+(bidx_<<8)+(kk-256);
        else            ap=p.Af2+(long)row*256+(kk-512);
      } else ap=p.A+(long)row*K+kk;
      af[mi]=*(const bf16x8*)ap;
    }
    #pragma unroll
    for(int ni=0;ni<4;ni++)
      bw[ni]=*(const bf16x8*)(p.W+(long)(n0+ni*16+l16)*K+kk);
    #pragma unroll
    for(int mi=0;mi<4;mi++)
      #pragma unroll
      for(int ni=0;ni<4;ni++)
        acc[mi][ni]=__builtin_amdgcn_mfma_f32_16x16x32_bf16(af[mi],bw[ni],acc[mi][ni],0,0,0);
  }
  #pragma unroll
  for(int ni=0;ni<4;ni++){
    int col=n0+ni*16+l16;
    float bv=b2f(p.bias[col]);
    #pragma unroll
    for(int mi=0;mi<4;mi++){
      #pragma unroll
      for(int r=0;r<4;r++){
        int row=m0+mi*16+q*4+r;
        float v=acc[mi][ni][r];
        if(EPI==0) v+=bv;
        else if(EPI==1) v=fmaxf(v+bv,0.f);
        else {
          v += (float)p.cnt[row]*bv + b2f(p.addb[(long)row*256+col]);
          v=fmaxf(v,0.f);
        }
        p.out[(long)row*256+col]=f2b(v);
      }
    }
  }
}

// ---------------- per-layer small mats ----------------
__global__ __launch_bounds__(256) void k_small(const float* rel_lin, const bf16* selfw,
    const bf16* selfb, const float* qnode, const bf16* q2ew, const bf16* q2eb,
    float* relself, float* q2ev, bf16* q2evb){
  __shared__ float xr[DD];
  int d=threadIdx.x;
  if(blockIdx.x<601){
    int r=blockIdx.x;
    xr[d]=rel_lin[r*DD+d]; __syncthreads();
    float acc=b2f(selfb[d]);
    const bf16* wr=selfw+(long)d*DD;
    for(int k4=0;k4<DD;k4+=4){
      float v[4]; ld4bf(wr+k4,v);
      acc+=v[0]*xr[k4]+v[1]*xr[k4+1]+v[2]*xr[k4+2]+v[3]*xr[k4+3];
    }
    relself[r*DD+d]=acc;
  } else {
    int b=blockIdx.x-601;
    xr[d]=qnode[(b<<8)+d]; __syncthreads();
    float acc=b2f(q2eb[d]);
    const bf16* wr=q2ew+(long)d*DD;
    for(int k4=0;k4<DD;k4+=4){
      float v[4]; ld4bf(wr+k4,v);
      acc+=v[0]*xr[k4]+v[1]*xr[k4+1]+v[2]*xr[k4+2]+v[3]*xr[k4+3];
    }
    q2ev[(b<<8)+d]=acc;
    q2evb[(b<<8)+d]=f2b(acc);
  }
}

// ---------------- norm + pagerank numerator scatter ----------------
__global__ __launch_bounds__(256) void k_norm(const float* wt, const float* pr,
    const float* e2fs, const int* e2f, const int* f2e, float* normv, float* pragg){
  int i=blockIdx.x*256+threadIdx.x;
  int b=i>>13;
  int e=e2f[i];
  float v=wt[i]*pr[(b<<11)+e]/fmaxf(e2fs[(b<<11)+e],1e-10f);
  normv[i]=v;
  atomicAdd(pragg+(b<<11)+f2e[i], v);
}

// ---------------- segmented fact aggregation (atomic-free) ----------------
__global__ __launch_bounds__(256) void k_agg(const int* bstart, const int* bidx,
    const int* rel, const int* e2f, const float* normv, const float* relself,
    const bf16* head, bf16* agg){
  int eidx=blockIdx.x*4+(threadIdx.x>>6);
  int lane=threadIdx.x&63;
  int b=eidx>>11;
  float a0=0.f,a1=0.f,a2=0.f,a3=0.f;
  int s=bstart[eidx], e=bstart[eidx+1];
  for(int i=s;i<e;i++){
    int f=bidx[i];
    int r=rel[f]; int ent=e2f[f]; float nv=normv[f];
    float4 rs=*(const float4*)&relself[r*DD+lane*4];
    float hd[4]; ld4bf(head+(long)(((b<<11)+ent)*DD+lane*4),hd);
    a0+=fmaxf(rs.x+hd[0],0.f)*nv; a1+=fmaxf(rs.y+hd[1],0.f)*nv;
    a2+=fmaxf(rs.z+hd[2],0.f)*nv; a3+=fmaxf(rs.w+hd[3],0.f)*nv;
  }
  st4bf(agg+(long)eidx*DD+lane*4, a0,a1,a2,a3);
}

// ---------------- weighted row-sums (fused pagerank update) ----------------
// latency-optimized: 512 blocks, wave-per-16-rows, lane-per-4-cols vector loads,
// p computed by lanes 0..15 and shfl-broadcast; cross-wave reduce in LDS.
__global__ __launch_bounds__(256) void k_wnxt(const float* pragg, float* pr, const bf16* le,
    const bf16* f2e, float* wnxt, float* prsum){
  __shared__ float r1[4*256];
  __shared__ float r3[4*256];
  __shared__ float rp[4];
  const int b=blockIdx.x, ch=blockIdx.y;
  const int wv=threadIdx.x>>6, lane=threadIdx.x&63;
  const int pe0=(b<<11)+ch*64+wv*16;
  // lanes 0..15: per-row pagerank update
  float pv=0.f;
  if(lane<16){
    pv=0.8f*pragg[pe0+lane]+0.2f*pr[pe0+lane];
    pr[pe0+lane]=pv;
  }
  float a1[4]={0.f,0.f,0.f,0.f}, a3[4]={0.f,0.f,0.f,0.f}, ap=0.f;
  #pragma unroll
  for(int r=0;r<16;r++){
    float p=__shfl(pv, r, 64);
    long base=((long)(pe0+r))<<8;
    float v1[4],v3[4];
    ld4bf(le +base+lane*4, v1);
    ld4bf(f2e+base+lane*4, v3);
    #pragma unroll
    for(int j=0;j<4;j++){ a1[j]+=p*v1[j]; a3[j]+=p*v3[j]; }
    ap+=p;
  }
  #pragma unroll
  for(int j=0;j<4;j++){ r1[wv*256+lane*4+j]=a1[j]; r3[wv*256+lane*4+j]=a3[j]; }
  if(!lane) rp[wv]=ap;
  __syncthreads();
  const int t=threadIdx.x;
  float s1=r1[t]+r1[256+t]+r1[512+t]+r1[768+t];
  float s3=r3[t]+r3[256+t]+r3[512+t]+r3[768+t];
  atomicAdd(&wnxt[b*768+t], s1);
  atomicAdd(&wnxt[b*768+512+t], s3);
  if(!t) atomicAdd(&prsum[b], rp[0]+rp[1]+rp[2]+rp[3]);
}

// note: e2q_w tail cols pre-scaled by 3 at cvt -> xr segment 3 is plain a3
__global__ __launch_bounds__(256) void k_qnode(const float* wnxt, const float* prsum,
    const float* q2ev, const bf16* w, const bf16* bias, float* qnode){
  int b=blockIdx.x, d=threadIdx.x;
  __shared__ float xr[768];
  float ps=prsum[b];
  xr[d]=wnxt[b*768+d];
  xr[256+d]=ps*q2ev[(b<<8)+d];
  xr[512+d]=wnxt[b*768+512+d];
  __syncthreads();
  float acc=0.f;
  const bf16* wr=w+(long)d*768;
  for(int k4=0;k4<768;k4+=4){
    float v[4]; ld4bf(wr+k4,v);
    acc+=v[0]*xr[k4]+v[1]*xr[k4+1]+v[2]*xr[k4+2]+v[3]*xr[k4+3];
  }
  qnode[(b<<8)+d]=acc+ps*b2f(bias[d]);
}

// ---------------- score ----------------
__global__ __launch_bounds__(256) void k_score(const bf16* le, const bf16* sw,
    const bf16* sb, void* out, const int* dfl){
  const int isf=*dfl;
  int o=blockIdx.x*4 + (threadIdx.x>>6);
  int lane=threadIdx.x&63;
  float v[4],wv[4];
  ld4bf(le+(long)o*DD+lane*4,v); ld4bf(sw+lane*4,wv);
  float acc=v[0]*wv[0]+v[1]*wv[1]+v[2]*wv[2]+v[3]*wv[3];
  for(int off=32;off;off>>=1) acc+=__shfl_down(acc,off,64);
  if(!lane){
    float r=acc+b2f(sb[0]);
    if(isf) ((float*)out)[o]=r; else ((bf16*)out)[o]=f2b(r);
  }
}

// ---------------- host ----------------
extern "C" void kernel_launch(void* const* d_in, const int* in_sizes, int n_in,
                              void* d_out, int out_size, void* d_ws, size_t ws_size,
                              hipStream_t stream){
  const int*  local_entity=(const int*)d_in[0];
  const void* q2e_adj     =d_in[1];
  const int*  kb_fact_rel =(const int*)d_in[2];
  const int*  query_text  =(const int*)d_in[3];
  const int*  e2f_ent     =(const int*)d_in[5];
  const int*  f2e_ent     =(const int*)d_in[6];
  const void* word_emb    =d_in[7];
  const void* entity_emb  =d_in[8];
  const void* relation_emb=d_in[9];

  char* ws=(char*)d_ws;
  float* gx      =(float*)(ws+O_GX);
  float* qh      =(float*)(ws+O_QH);
  float* qnode   =(float*)(ws+O_QNODE);
  float* rel_lin =(float*)(ws+O_RELLIN);
  float* Wr      =(float*)(ws+O_WR);
  float* wmax    =(float*)(ws+O_WMAX);
  float* wt      =(float*)(ws+O_WT);
  float* e2fs    =(float*)(ws+O_E2FS);
  float* pr      =(float*)(ws+O_PR);
  float* pragg   =(float*)(ws+O_PRAGG);
  float* q2ev    =(float*)(ws+O_Q2EV);
  bf16*  q2evb   =(bf16*)(ws+O_Q2EVB);
  float* relself =(float*)(ws+O_RELSELF);
  float* normv   =(float*)(ws+O_NORM);
  float* wnxt    =(float*)(ws+O_WNXT);
  float* prsum   =(float*)(ws+O_PRSUM);
  int*   cnt     =(int*)(ws+O_CNT);
  int*   cur     =(int*)(ws+O_CUR);
  int*   bstart  =(int*)(ws+O_BSTART);
  int*   bidx    =(int*)(ws+O_BIDX);
  bf16*  elwpad  =(bf16*)(ws+O_ELWPAD);
  int*   dflag   =(int*)(ws+O_FLAG);
  bf16*  cw      =(bf16*)(ws+O_CVT);
  bf16*  agg     =(bf16*)(ws+O_AGG);
  bf16*  A0      =(bf16*)(ws+O_AGG);      // aliases agg + start of entself (pre-layer use only)
  bf16*  entself =(bf16*)(ws+O_ENTSELF);
  bf16*  leA     =(bf16*)(ws+O_LEA);
  bf16*  leB     =(bf16*)(ws+O_LEB);
  bf16*  headb   =(bf16*)(ws+O_HEAD);
  bf16*  f2eemb  =(bf16*)(ws+O_F2EEMB);
  // LSTM h-exchange: aliases leA (dead until the first mgemm, which runs after the LSTM)
  bf16*  hbuf    =(bf16*)(ws+O_LEA);              // 2 slots x 16x256 bf16 = 16KB
  int*   lcnt    =(int*)(ws+O_LEA+16384);         // 20 step flags

  k_sniff<<<1,256,0,stream>>>((const unsigned short*)entity_emb, dflag);

  CvtJobs J;
  int cntj=0;
  auto add=[&](int in_idx, long coff, int n, int sc){
    J.src[cntj]=d_in[in_idx]; J.dst[cntj]=cw+coff; J.n[cntj]=n; J.sc[cntj]=sc; cntj++;
  };
  add(11,C_ELB,256,0);
  add(12,C_RLW,153600,0);  add(13,C_RLB,256,0);
  add(14,C_WIH,307200,0);
  add(16,C_BIH,1024,0);    add(17,C_BHH,1024,0);
  add(18,C_Q2EW,196608,0); add(19,C_Q2EB,768,0);
  add(20,C_E2QW,589824,1); add(21,C_E2QB,768,0);
  add(22,C_E2EW,589824,1); add(23,C_E2EB,768,0);
  add(24,C_KHW,196608,0);  add(25,C_KHB,768,0);
  add(26,C_KTW,196608,0);  add(27,C_KTB,768,0);
  add(28,C_KSW,196608,0);  add(29,C_KSB,768,0);
  add(30,C_SCW,256,0);     add(31,C_SCB,1,0);
  k_cvt<<<dim3(576,20),256,0,stream>>>(J, dflag);
  k_cvtwhh<<<128,256,0,stream>>>(d_in[15], cw+C_WHH, dflag);
  k_cvtelw<<<256,256,0,stream>>>(d_in[10], elwpad, dflag);

  // CSR bucketing (fact graph is launch-constant); cnt+cur adjacent -> one memset
  hipMemsetAsync(cnt, 0, (size_t)2*BB*EE*4, stream);
  k_cnt <<<BB*FF/256,256,0,stream>>>(f2e_ent, cnt);
  k_scan<<<1,1024,0,stream>>>(cnt, bstart);
  k_fill<<<BB*FF/256,256,0,stream>>>(f2e_ent, bstart, cur, bidx);

  k_gx   <<<BB*QQ,256,0,stream>>>(query_text, word_emb, cw+C_WIH, cw+C_BIH, cw+C_BHH, gx, dflag);
  hipMemsetAsync(lcnt, 0, 128, stream);
  k_lstm3<<<NLB,256,0,stream>>>(gx, cw+C_WHH, qh, qnode, hbuf, lcnt);
  k_rel_lin<<<601,256,0,stream>>>(relation_emb, cw+C_RLW, cw+C_RLB, rel_lin, dflag);
  k_simwr<<<dim3(BB,3),256,0,stream>>>(qh, rel_lin, query_text, Wr);
  k_wmax <<<BB,256,0,stream>>>(Wr, kb_fact_rel, wmax);
  hipMemsetAsync(e2fs, 0, (size_t)BB*EE*4, stream);
  k_wt   <<<BB*FF/256,256,0,stream>>>(Wr, kb_fact_rel, wmax, e2f_ent, wt, e2fs);
  k_prinit<<<BB*EE/1024,256,0,stream>>>(q2e_adj, pr, dflag);

  // le = entity_emb[local_entity] @ elw^T + elb   (K padded to 320)
  k_ga0<<<BB*EE,128,0,stream>>>(local_entity, entity_emb, A0, dflag);
  {
    MG p{}; p.A=A0; p.W=elwpad; p.bias=cw+C_ELB; p.out=leA; p.K=320;
    k_mgemm<0,0><<<BB*EE/64,256,0,stream>>>(p);
  }

  bf16* le_cur=leA; bf16* le_nxt=leB;
  for(int i=0;i<3;i++){
    k_small<<<617,256,0,stream>>>(rel_lin, cw+C_KSW+(long)i*65536, cw+C_KSB+(long)i*256,
        qnode, cw+C_Q2EW+(long)i*65536, cw+C_Q2EB+(long)i*256, relself, q2ev, q2evb);
    {
      MG p{}; p.A=le_cur; p.W=cw+C_KHW+(long)i*65536; p.bias=cw+C_KHB+(long)i*256;
      p.out=headb; p.K=256;
      k_mgemm<0,0><<<BB*EE/64,256,0,stream>>>(p);
    }
    {
      MG p{}; p.A=le_cur; p.W=cw+C_KSW+(long)i*65536; p.bias=cw+C_KSB+(long)i*256;
      p.out=entself; p.K=256;
      k_mgemm<0,0><<<BB*EE/64,256,0,stream>>>(p);
    }
    hipMemsetAsync(pragg, 0, (size_t)BB*EE*4, stream);
    k_norm<<<BB*FF/256,256,0,stream>>>(wt, pr, e2fs, e2f_ent, f2e_ent, normv, pragg);
    k_agg <<<BB*EE/4,256,0,stream>>>(bstart, bidx, kb_fact_rel, e2f_ent, normv, relself, headb, agg);
    {
      MG p{}; p.A=agg; p.W=cw+C_KTW+(long)i*65536; p.bias=cw+C_KTB+(long)i*256;
      p.out=f2eemb; p.K=256; p.cnt=cnt; p.addb=entself;
      k_mgemm<0,2><<<BB*EE/64,256,0,stream>>>(p);
    }
    hipMemsetAsync(wnxt, 0, (size_t)(BB*768*4+256), stream);
    k_wnxt <<<dim3(BB,32),256,0,stream>>>(pragg, pr, le_cur, f2eemb, wnxt, prsum);
    k_qnode<<<BB,256,0,stream>>>(wnxt, prsum, q2ev, cw+C_E2QW+(long)i*196608, cw+C_E2QB+(long)i*256, qnode);
    {
      MG p{}; p.A=le_cur; p.W=cw+C_E2EW+(long)i*196608; p.bias=cw+C_E2EB+(long)i*256;
      p.out=le_nxt; p.K=768; p.Aq2=q2evb; p.Af2=f2eemb;
      k_mgemm<1,1><<<BB*EE/64,256,0,stream>>>(p);
    }
    bf16* t=le_cur; le_cur=le_nxt; le_nxt=t;
  }

  k_score<<<BB*EE/4,256,0,stream>>>(le_cur, cw+C_SCW, cw+C_SCB, d_out, dflag);
}

// Round 3
// 1117.951 us; speedup vs baseline: 1.2533x; 1.0077x over previous
//
#include <hip/hip_runtime.h>
#include <hip/hip_bf16.h>

typedef __hip_bfloat16 bf16;
typedef __attribute__((ext_vector_type(8))) short bf16x8;
typedef __attribute__((ext_vector_type(4))) float f32x4;

#define BB 16
#define EE 2048
#define FF 8192
#define QQ 20
#define DD 256
#define WDIM 300
#define NWORD 50000
#define VERY_NEG_F (-1.0e11f)

static __device__ __forceinline__ float b2f(bf16 x){ return __bfloat162float(x); }
static __device__ __forceinline__ bf16 f2b(float x){ return __float2bfloat16(x); }
static __device__ __forceinline__ float sigm(float x){ return 1.f/(1.f+expf(-x)); }
static __device__ __forceinline__ void ld4bf(const bf16* p, float v[4]){
  short4 s = *(const short4*)p;
  v[0]=b2f(*(const bf16*)&s.x); v[1]=b2f(*(const bf16*)&s.y);
  v[2]=b2f(*(const bf16*)&s.z); v[3]=b2f(*(const bf16*)&s.w);
}
static __device__ __forceinline__ void st4bf(bf16* p, float a,float b,float c,float d){
  unsigned short u[4]; bf16 t;
  t=f2b(a);u[0]=*(unsigned short*)&t; t=f2b(b);u[1]=*(unsigned short*)&t;
  t=f2b(c);u[2]=*(unsigned short*)&t; t=f2b(d);u[3]=*(unsigned short*)&t;
  *(short4*)p=*(short4*)u;
}

// ---------------- workspace offsets (bytes) ----------------
#define O_GX       0UL
#define O_QH       1310720UL
#define O_QNODE    1638400UL
#define O_RELLIN   1654784UL
#define O_WR       2270208UL
#define O_WMAX     2308864UL
#define O_WT       2309120UL
#define O_E2FS     2833408UL
#define O_PR       2964480UL
#define O_PRAGG    3095552UL
#define O_Q2EV     3226624UL
#define O_Q2EVB    3243008UL
#define O_RELSELF  3251200UL
#define O_NORM     3866624UL
#define O_WNXT     4390912UL
#define O_PRSUM    4440064UL
#define O_CNT      4440320UL
#define O_CUR      4571392UL
#define O_BSTART   4702464UL
#define O_BIDX     4834048UL
#define O_ELWPAD   5358336UL
#define O_FLAG     5522176UL
#define O_CVT      5522432UL   // 5393152 B
#define O_AGG      10915584UL  // bf16 16.7MB; A0 (21MB) aliases AGG+start of ENTSELF
#define O_ENTSELF  27692800UL
#define O_LEA      44470016UL
#define O_LEB      61247232UL
#define O_HEAD     78024448UL
#define O_F2EEMB   94801664UL  // end ~111.6MB

// canonical element offsets within O_CVT (all mult of 8)
#define C_ELB   0
#define C_RLW   256
#define C_RLB   153856
#define C_WIH   154112
#define C_WHH   461312   // frag-linear w_hh (262144 elems)
#define C_BIH   723456
#define C_BHH   724480
#define C_Q2EW  725504
#define C_Q2EB  922112
#define C_E2QW  922880
#define C_E2QB  1512704
#define C_E2EW  1513472
#define C_E2EB  2103296
#define C_KHW   2104064
#define C_KHB   2300672
#define C_KTW   2301440
#define C_KTB   2498048
#define C_KSW   2498816
#define C_KSB   2695424
#define C_SCW   2696192
#define C_SCB   2696448

// ---------------- dtype sniffer (verified r2) ----------------
__global__ __launch_bounds__(256) void k_sniff(const unsigned short* ee, int* flag){
  __shared__ int red[256];
  int c=0;
  for(int i=threadIdx.x;i<4096;i+=256){
    int ex=(ee[2*i]>>7)&0xFF;
    c += (ex>=192);
  }
  red[threadIdx.x]=c; __syncthreads();
  for(int o=128;o;o>>=1){ if(threadIdx.x<o) red[threadIdx.x]+=red[threadIdx.x+o]; __syncthreads(); }
  if(!threadIdx.x) flag[0] = (red[0]>64) ? 1 : 0;
}

// ---------------- batched weight canonicalization -> bf16 (tail-scale for e2q/e2e) ----------------
struct CvtJobs{ const void* src[20]; bf16* dst[20]; int n[20]; int sc[20]; };
__global__ __launch_bounds__(256) void k_cvt(CvtJobs J, const int* dfl){
  const int isf=*dfl;
  int j=blockIdx.y;
  int n=J.n[j];
  int i4=(blockIdx.x*256+threadIdx.x)*4;
  if(i4>=n) return;
  float m = (J.sc[j] && ((i4%768)>=512)) ? 3.f : 1.f;
  bf16* d=J.dst[j]+i4;
  if(isf){
    const float* s=(const float*)J.src[j]+i4;
    if(i4+4<=n){ float4 t=*(const float4*)s; st4bf(d,t.x*m,t.y*m,t.z*m,t.w*m); }
    else for(int r=0;i4+r<n;r++) d[r]=f2b(s[r]*m);
  } else {
    const bf16* s=(const bf16*)J.src[j]+i4;
    if(i4+4<=n){ float v[4]; ld4bf(s,v); st4bf(d,v[0]*m,v[1]*m,v[2]*m,v[3]*m); }
    else for(int r=0;i4+r<n;r++) d[r]=f2b(b2f(s[r])*m);
  }
}

// w_hh (1024x256) -> MFMA-fragment-linear: wf[gt][kt][lane][8], gate=gt*16+(lane&15), k=kt*32+(lane>>4)*8+j
__global__ __launch_bounds__(256) void k_cvtwhh(const void* src, bf16* wf, const int* dfl){
  const int isf=*dfl;
  int fid=blockIdx.x*256+threadIdx.x;        // 0..32767
  int lane=fid&63, kt=(fid>>6)&7, gt=fid>>9;
  int l16=lane&15, q=lane>>4;
  long so=(long)(gt*16+l16)*256 + kt*32 + q*8;
  float v[8];
  if(isf){ const float* s=(const float*)src+so;
    #pragma unroll
    for(int j=0;j<8;j++) v[j]=s[j];
  } else { const bf16* s=(const bf16*)src+so; ld4bf(s,v); ld4bf(s+4,v+4); }
  bf16* d=wf+(long)fid*8;
  st4bf(d,v[0],v[1],v[2],v[3]); st4bf(d+4,v[4],v[5],v[6],v[7]);
}

// entity_lin_w (256x300) -> padded bf16 (256x320)
__global__ __launch_bounds__(256) void k_cvtelw(const void* src, bf16* dst, const int* dfl){
  const int isf=*dfl;
  int r=blockIdx.x;
  for(int c=threadIdx.x;c<320;c+=256){
    float v=0.f;
    if(c<300) v = isf ? ((const float*)src)[r*300+c] : b2f(((const bf16*)src)[r*300+c]);
    dst[(long)r*320+c]=f2b(v);
  }
}

// gathered, padded A0[32768][320] = entity_emb[local_entity]
__global__ __launch_bounds__(128) void k_ga0(const int* idx, const void* emb, bf16* A0, const int* dfl){
  const int isf=*dfl;
  int row=blockIdx.x; int ent=idx[row]; int t=threadIdx.x;
  bf16* dst=A0+(long)row*320;
  if(t<75){
    float v[4];
    if(isf){ float4 x=*(const float4*)((const float*)emb+(long)ent*WDIM+t*4);
             v[0]=x.x;v[1]=x.y;v[2]=x.z;v[3]=x.w; }
    else ld4bf((const bf16*)emb+(long)ent*WDIM+t*4, v);
    st4bf(dst+t*4, v[0],v[1],v[2],v[3]);
  } else if(t<80){
    st4bf(dst+t*4, 0.f,0.f,0.f,0.f);
  }
}

// ---------------- CSR bucketing of facts by (b, f2e_ent) ----------------
__global__ __launch_bounds__(256) void k_cnt(const int* f2e, int* cnt){
  int i=blockIdx.x*256+threadIdx.x;
  atomicAdd(&cnt[((i>>13)<<11)+f2e[i]], 1);
}
__global__ __launch_bounds__(1024) void k_scan(const int* cnt, int* bstart){
  __shared__ int ps[1024];
  int t=threadIdx.x;
  int loc[32]; int s=0;
  #pragma unroll
  for(int j=0;j<32;j++){ loc[j]=s; s+=cnt[t*32+j]; }
  ps[t]=s; __syncthreads();
  for(int off=1;off<1024;off<<=1){
    int v=(t>=off)?ps[t-off]:0;
    __syncthreads(); ps[t]+=v; __syncthreads();
  }
  int base=(t? ps[t-1]:0);
  #pragma unroll
  for(int j=0;j<32;j++) bstart[t*32+j]=base+loc[j];
  if(t==1023) bstart[32768]=ps[1023];
}
__global__ __launch_bounds__(256) void k_fill(const int* f2e, const int* bstart, int* cur, int* bidx){
  int i=blockIdx.x*256+threadIdx.x;
  int key=((i>>13)<<11)+f2e[i];
  int pos=bstart[key]+atomicAdd(&cur[key],1);
  bidx[pos]=i;
}

// ---------------- gx = wemb[qtext] @ w_ih^T + b_ih + b_hh ----------------
__global__ __launch_bounds__(256) void k_gx(const int* qtext, const void* wemb,
    const bf16* wih, const bf16* bih, const bf16* bhh, float* gx, const int* dfl){
  const int isf=*dfl;
  int bt=blockIdx.x;
  __shared__ float xr[WDIM];
  int w=qtext[bt];
  for(int k4=threadIdx.x*4;k4<WDIM;k4+=1024){
    if(isf){ float4 t=*(const float4*)((const float*)wemb+(long)w*WDIM+k4);
             xr[k4]=t.x;xr[k4+1]=t.y;xr[k4+2]=t.z;xr[k4+3]=t.w; }
    else   { float v[4]; ld4bf((const bf16*)wemb+(long)w*WDIM+k4,v);
             xr[k4]=v[0];xr[k4+1]=v[1];xr[k4+2]=v[2];xr[k4+3]=v[3]; }
  }
  __syncthreads();
  #pragma unroll
  for(int s=0;s<4;s++){
    int g=threadIdx.x+256*s;
    float acc=b2f(bih[g])+b2f(bhh[g]);
    const bf16* wr=wih+(long)g*WDIM;
    for(int k4=0;k4<WDIM;k4+=4){
      float v[4]; ld4bf(wr+k4,v);
      acc+=v[0]*xr[k4]+v[1]*xr[k4+1]+v[2]*xr[k4+2]+v[3]*xr[k4+3];
    }
    gx[bt*1024+g]=acc;
  }
}

// ---------------- distributed MFMA LSTM: 8 blocks x 512 thr, W slice in registers ----------------
// Block k owns hidden units [k*32, k*32+32). Wave wv: gtype=wv>>1, sub=wv&1 ->
// gate tile gt = gtype*16 + k*2 + sub; 8 K-frags in 32 VGPRs (loaded once).
// Sync per step: relaxed all-thread spin + one acquire fence (no per-poll invalidate);
// publish slice -> barrier (vmcnt drain) -> RELEASE add; qh/qnode stores AFTER the add
// (latency hidden under next spin), nontemporal so release's L2-writeback is cheap.
#define NLB 8
__global__ __launch_bounds__(512) void k_lstm4(const float* gx, const bf16* wf,
    float* qh, float* qnode, bf16* hbuf, int* lcnt){
  __shared__ bf16  hlds[16*264];     // 528B row stride -> 2-way bank alias (free)
  __shared__ float zs[4*16*32];      // [gtype][batch][u_local]
  __shared__ bf16  hsl[512];         // [batch][u_local] outgoing slice
  const int k=blockIdx.x, tid=threadIdx.x;
  const int wv=tid>>6, lane=tid&63, q=lane>>4, l16=lane&15;
  const int gt=(wv>>1)*16 + k*2 + (wv&1);
  const int b=tid>>5, u=tid&31, gu=k*32+u;
  bf16x8 wreg[8];
  #pragma unroll
  for(int kt=0;kt<8;kt++)
    wreg[kt]=*(const bf16x8*)(wf + (((long)(gt*8+kt))*64 + lane)*8);
  float c=0.f;
  float gxr[4];
  #pragma unroll
  for(int g=0;g<4;g++) gxr[g]=gx[(b*QQ+0)*1024 + g*256 + gu];
  for(int t=0;t<QQ;t++){
    f32x4 acc=(f32x4){0.f,0.f,0.f,0.f};
    if(t){
      // all-thread relaxed spin; one acquire fence after
      while(__hip_atomic_load(lcnt+(t-1), __ATOMIC_RELAXED, __HIP_MEMORY_SCOPE_AGENT) < NLB)
        __builtin_amdgcn_s_sleep(2);
      __builtin_amdgcn_fence(__ATOMIC_ACQUIRE, "agent");
      __builtin_amdgcn_sched_barrier(0);
      // pull full h (8KB) -> LDS; agent-scope loads bypass stale per-XCD L2
      const bf16* hb = hbuf + (t&1)*4096;
      {
        int r=tid>>5, cc=(tid&31)*8;
        unsigned long long v0=__hip_atomic_load((const unsigned long long*)(hb + r*256 + cc),
                       __ATOMIC_RELAXED, __HIP_MEMORY_SCOPE_AGENT);
        unsigned long long v1=__hip_atomic_load((const unsigned long long*)(hb + r*256 + cc + 4),
                       __ATOMIC_RELAXED, __HIP_MEMORY_SCOPE_AGENT);
        *(unsigned long long*)&hlds[r*264 + cc] = v0;
        *(unsigned long long*)&hlds[r*264 + cc + 4] = v1;
      }
      __syncthreads();
      #pragma unroll
      for(int kt=0;kt<8;kt++){
        bf16x8 af=*(const bf16x8*)&hlds[l16*264 + kt*32 + q*8];
        acc=__builtin_amdgcn_mfma_f32_16x16x32_bf16(af,wreg[kt],acc,0,0,0);
      }
    }
    // zs[gtype][batch=q*4+r][u_local=sub*16+l16]
    #pragma unroll
    for(int r=0;r<4;r++) zs[(wv>>1)*512 + (q*4+r)*32 + (wv&1)*16 + l16]=acc[r];
    __syncthreads();
    float zi=zs[0*512+b*32+u]+gxr[0];
    float zf=zs[1*512+b*32+u]+gxr[1];
    float zg=zs[2*512+b*32+u]+gxr[2];
    float zo=zs[3*512+b*32+u]+gxr[3];
    { // prefetch next step's gx
      int tn=(t<QQ-1)?t+1:t;
      #pragma unroll
      for(int g=0;g<4;g++) gxr[g]=gx[(b*QQ+tn)*1024 + g*256 + gu];
    }
    c=sigm(zf)*c+sigm(zi)*tanhf(zg);
    float hv=sigm(zo)*tanhf(c);
    hsl[tid]=f2b(hv);
    __syncthreads();
    if(t<QQ-1){
      if(tid<128){ // publish our 1KB slice, agent-scope
        bf16* hw=hbuf + ((t+1)&1)*4096;
        int bb=tid>>3, p=tid&7;
        unsigned long long v=*(unsigned long long*)&hsl[bb*32+p*4];
        __hip_atomic_store((unsigned long long*)(hw + bb*256 + k*32 + p*4), v,
                           __ATOMIC_RELAXED, __HIP_MEMORY_SCOPE_AGENT);
      }
      __syncthreads();   // vmcnt(0) drain: all publishers' stores at L3
      if(tid==0)
        __hip_atomic_fetch_add(lcnt+t, 1, __ATOMIC_RELEASE, __HIP_MEMORY_SCOPE_AGENT);
    }
    // off critical path: streamed, keeps L2 clean for the release writeback
    __builtin_nontemporal_store(hv, &qh[(long)(b*QQ+t)*256+gu]);
    if(t==QQ-1) qnode[(b<<8)+gu]=hv;
  }
}

// ---------------- rel_lin ----------------
__global__ __launch_bounds__(256) void k_rel_lin(const void* remb, const bf16* rlw,
    const bf16* rlb, float* rel_lin, const int* dfl){
  const int isf=*dfl;
  int r=blockIdx.x;
  __shared__ float rr[2*WDIM];
  for(int k4=threadIdx.x*4;k4<2*WDIM;k4+=1024){
    if(isf){ float4 t=*(const float4*)((const float*)remb+(long)r*2*WDIM+k4);
             rr[k4]=t.x;rr[k4+1]=t.y;rr[k4+2]=t.z;rr[k4+3]=t.w; }
    else   { float v[4]; ld4bf((const bf16*)remb+(long)r*2*WDIM+k4,v);
             rr[k4]=v[0];rr[k4+1]=v[1];rr[k4+2]=v[2];rr[k4+3]=v[3]; }
  }
  __syncthreads();
  int d=threadIdx.x;
  float acc=b2f(rlb[d]);
  const bf16* wr=rlw+(long)d*2*WDIM;
  for(int k4=0;k4<2*WDIM;k4+=4){
    float v[4]; ld4bf(wr+k4,v);
    acc+=v[0]*rr[k4]+v[1]*rr[k4+1]+v[2]*rr[k4+2]+v[3]*rr[k4+3];
  }
  rel_lin[r*DD+d]=acc;
}

// ---------------- sim + masked softmax + Wr (relation space) ----------------
__global__ __launch_bounds__(256) void k_simwr(const float* qh, const float* rel_lin,
    const int* qtext, float* Wr){
  int b = blockIdx.x, rc = blockIdx.y;
  __shared__ float qhb[QQ*DD];
  __shared__ float qm[QQ];
  for(int i=threadIdx.x;i<QQ*DD;i+=256) qhb[i]=qh[b*QQ*DD+i];
  if(threadIdx.x<QQ) qm[threadIdx.x] = (qtext[b*QQ+threadIdx.x]!=NWORD)?0.f:VERY_NEG_F;
  __syncthreads();
  int r = rc*256+threadIdx.x;
  if(r>=601) return;
  float s[QQ];
  #pragma unroll
  for(int q=0;q<QQ;q++) s[q]=0.f;
  for(int k=0;k<DD;k++){
    float rl = rel_lin[r*DD+k];
    #pragma unroll
    for(int q=0;q<QQ;q++) s[q] += qhb[q*DD+k]*rl;
  }
  float m=-1e30f;
  #pragma unroll
  for(int q=0;q<QQ;q++){ s[q]*=0.0625f; m=fmaxf(m, s[q]+qm[q]); }
  float sum=0.f, w=0.f;
  #pragma unroll
  for(int q=0;q<QQ;q++){ float p=expf(s[q]+qm[q]-m); sum+=p; w+=p*s[q]; }
  Wr[b*601+r] = w/sum;
}

// ---------------- Wmax / W_tilde / e2f_softmax / pr init ----------------
__global__ __launch_bounds__(256) void k_wmax(const float* Wr, const int* rel, float* wmax){
  int b=blockIdx.x; __shared__ float red[256];
  float m=-1e30f;
  for(int f=threadIdx.x;f<FF;f+=256) m=fmaxf(m, Wr[b*601+rel[b*FF+f]]);
  red[threadIdx.x]=m; __syncthreads();
  for(int o=128;o;o>>=1){ if(threadIdx.x<o) red[threadIdx.x]=fmaxf(red[threadIdx.x],red[threadIdx.x+o]); __syncthreads(); }
  if(!threadIdx.x) wmax[b]=red[0];
}
__global__ __launch_bounds__(256) void k_wt(const float* Wr, const int* rel,
    const float* wmax, const int* e2f, float* wt, float* e2fs){
  int i = blockIdx.x*256+threadIdx.x;
  int b = i>>13;
  float v = expf(Wr[b*601+rel[i]] - wmax[b]);
  wt[i]=v;
  atomicAdd(e2fs + (b<<11) + e2f[i], v);
}
__global__ __launch_bounds__(256) void k_prinit(const void* adj, float* pr, const int* dfl){
  const int isf=*dfl;
  int i4=(blockIdx.x*256+threadIdx.x)*4;
  if(isf){ *(float4*)(pr+i4)=*(const float4*)((const float*)adj+i4); }
  else { float v[4]; ld4bf((const bf16*)adj+i4,v);
         float4 t; t.x=v[0];t.y=v[1];t.z=v[2];t.w=v[3]; *(float4*)(pr+i4)=t; }
}

// ---------------- MFMA GEMM: C[M,256] = A[M,K] @ W[256,K]^T, no LDS ----------------
// TK compile-time -> full K unroll; DUAL: blockIdx.y selects (W2,bias2,out2)
struct MG {
  const bf16* A; const bf16* W; const bf16* bias;
  bf16* out; int K;
  const bf16* Aq2; const bf16* Af2;
  const int* cnt; const bf16* addb;
  const bf16* W2; const bf16* bias2; bf16* out2;
};
template<int CONCAT,int EPI,int TK,int DUAL>
__global__ __launch_bounds__(256) void k_mgemm(MG p){
  const int m0 = blockIdx.x*64;
  const int wave = threadIdx.x>>6, lane = threadIdx.x&63;
  const int q = lane>>4, l16 = lane&15;
  const int n0 = wave*64;
  const int bidx_ = m0>>11;
  const bf16* Wp = p.W; const bf16* biasp = p.bias; bf16* outp = p.out;
  if(DUAL && blockIdx.y){ Wp=p.W2; biasp=p.bias2; outp=p.out2; }
  f32x4 acc[4][4];
  #pragma unroll
  for(int i=0;i<4;i++)
    #pragma unroll
    for(int j=0;j<4;j++) acc[i][j]=(f32x4){0.f,0.f,0.f,0.f};
  #pragma unroll
  for(int k0=0;k0<TK;k0+=32){
    int kk=k0+q*8;
    bf16x8 af[4], bw[4];
    #pragma unroll
    for(int mi=0;mi<4;mi++){
      int row=m0+mi*16+l16;
      const bf16* ap;
      if(CONCAT){
        if(kk<256)      ap=p.A  +(long)row*256+kk;
        else if(kk<512) ap=p.Aq2+(bidx_<<8)+(kk-256);
        else            ap=p.Af2+(long)row*256+(kk-512);
      } else ap=p.A+(long)row*TK+kk;
      af[mi]=*(const bf16x8*)ap;
    }
    #pragma unroll
    for(int ni=0;ni<4;ni++)
      bw[ni]=*(const bf16x8*)(Wp+(long)(n0+ni*16+l16)*TK+kk);
    #pragma unroll
    for(int mi=0;mi<4;mi++)
      #pragma unroll
      for(int ni=0;ni<4;ni++)
        acc[mi][ni]=__builtin_amdgcn_mfma_f32_16x16x32_bf16(af[mi],bw[ni],acc[mi][ni],0,0,0);
  }
  #pragma unroll
  for(int ni=0;ni<4;ni++){
    int col=n0+ni*16+l16;
    float bv=b2f(biasp[col]);
    #pragma unroll
    for(int mi=0;mi<4;mi++){
      #pragma unroll
      for(int r=0;r<4;r++){
        int row=m0+mi*16+q*4+r;
        float v=acc[mi][ni][r];
        if(EPI==0) v+=bv;
        else if(EPI==1) v=fmaxf(v+bv,0.f);
        else {
          v += (float)p.cnt[row]*bv + b2f(p.addb[(long)row*256+col]);
          v=fmaxf(v,0.f);
        }
        outp[(long)row*256+col]=f2b(v);
      }
    }
  }
}

// ---------------- per-layer small mats ----------------
__global__ __launch_bounds__(256) void k_small(const float* rel_lin, const bf16* selfw,
    const bf16* selfb, const float* qnode, const bf16* q2ew, const bf16* q2eb,
    float* relself, float* q2ev, bf16* q2evb){
  __shared__ float xr[DD];
  int d=threadIdx.x;
  if(blockIdx.x<601){
    int r=blockIdx.x;
    xr[d]=rel_lin[r*DD+d]; __syncthreads();
    float acc=b2f(selfb[d]);
    const bf16* wr=selfw+(long)d*DD;
    for(int k4=0;k4<DD;k4+=4){
      float v[4]; ld4bf(wr+k4,v);
      acc+=v[0]*xr[k4]+v[1]*xr[k4+1]+v[2]*xr[k4+2]+v[3]*xr[k4+3];
    }
    relself[r*DD+d]=acc;
  } else {
    int b=blockIdx.x-601;
    xr[d]=qnode[(b<<8)+d]; __syncthreads();
    float acc=b2f(q2eb[d]);
    const bf16* wr=q2ew+(long)d*DD;
    for(int k4=0;k4<DD;k4+=4){
      float v[4]; ld4bf(wr+k4,v);
      acc+=v[0]*xr[k4]+v[1]*xr[k4+1]+v[2]*xr[k4+2]+v[3]*xr[k4+3];
    }
    q2ev[(b<<8)+d]=acc;
    q2evb[(b<<8)+d]=f2b(acc);
  }
}

// ---------------- norm + pagerank numerator scatter ----------------
__global__ __launch_bounds__(256) void k_norm(const float* wt, const float* pr,
    const float* e2fs, const int* e2f, const int* f2e, float* normv, float* pragg){
  int i=blockIdx.x*256+threadIdx.x;
  int b=i>>13;
  int e=e2f[i];
  float v=wt[i]*pr[(b<<11)+e]/fmaxf(e2fs[(b<<11)+e],1e-10f);
  normv[i]=v;
  atomicAdd(pragg+(b<<11)+f2e[i], v);
}

// ---------------- segmented fact aggregation (atomic-free) ----------------
__global__ __launch_bounds__(256) void k_agg(const int* bstart, const int* bidx,
    const int* rel, const int* e2f, const float* normv, const float* relself,
    const bf16* head, bf16* agg){
  int eidx=blockIdx.x*4+(threadIdx.x>>6);
  int lane=threadIdx.x&63;
  int b=eidx>>11;
  float a0=0.f,a1=0.f,a2=0.f,a3=0.f;
  int s=bstart[eidx], e=bstart[eidx+1];
  for(int i=s;i<e;i++){
    int f=bidx[i];
    int r=rel[f]; int ent=e2f[f]; float nv=normv[f];
    float4 rs=*(const float4*)&relself[r*DD+lane*4];
    float hd[4]; ld4bf(head+(long)(((b<<11)+ent)*DD+lane*4),hd);
    a0+=fmaxf(rs.x+hd[0],0.f)*nv; a1+=fmaxf(rs.y+hd[1],0.f)*nv;
    a2+=fmaxf(rs.z+hd[2],0.f)*nv; a3+=fmaxf(rs.w+hd[3],0.f)*nv;
  }
  st4bf(agg+(long)eidx*DD+lane*4, a0,a1,a2,a3);
}

// ---------------- weighted row-sums (fused pagerank update) ----------------
__global__ __launch_bounds__(256) void k_wnxt(const float* pragg, float* pr, const bf16* le,
    const bf16* f2e, float* wnxt, float* prsum){
  __shared__ float r1[4*256];
  __shared__ float r3[4*256];
  __shared__ float rp[4];
  const int b=blockIdx.x, ch=blockIdx.y;
  const int wv=threadIdx.x>>6, lane=threadIdx.x&63;
  const int pe0=(b<<11)+ch*64+wv*16;
  float pv=0.f;
  if(lane<16){
    pv=0.8f*pragg[pe0+lane]+0.2f*pr[pe0+lane];
    pr[pe0+lane]=pv;
  }
  float a1[4]={0.f,0.f,0.f,0.f}, a3[4]={0.f,0.f,0.f,0.f}, ap=0.f;
  #pragma unroll
  for(int r=0;r<16;r++){
    float p=__shfl(pv, r, 64);
    long base=((long)(pe0+r))<<8;
    float v1[4],v3[4];
    ld4bf(le +base+lane*4, v1);
    ld4bf(f2e+base+lane*4, v3);
    #pragma unroll
    for(int j=0;j<4;j++){ a1[j]+=p*v1[j]; a3[j]+=p*v3[j]; }
    ap+=p;
  }
  #pragma unroll
  for(int j=0;j<4;j++){ r1[wv*256+lane*4+j]=a1[j]; r3[wv*256+lane*4+j]=a3[j]; }
  if(!lane) rp[wv]=ap;
  __syncthreads();
  const int t=threadIdx.x;
  float s1=r1[t]+r1[256+t]+r1[512+t]+r1[768+t];
  float s3=r3[t]+r3[256+t]+r3[512+t]+r3[768+t];
  atomicAdd(&wnxt[b*768+t], s1);
  atomicAdd(&wnxt[b*768+512+t], s3);
  if(!t) atomicAdd(&prsum[b], rp[0]+rp[1]+rp[2]+rp[3]);
}

// note: e2q_w tail cols pre-scaled by 3 at cvt -> xr segment 3 is plain a3
__global__ __launch_bounds__(256) void k_qnode(const float* wnxt, const float* prsum,
    const float* q2ev, const bf16* w, const bf16* bias, float* qnode){
  int b=blockIdx.x, d=threadIdx.x;
  __shared__ float xr[768];
  float ps=prsum[b];
  xr[d]=wnxt[b*768+d];
  xr[256+d]=ps*q2ev[(b<<8)+d];
  xr[512+d]=wnxt[b*768+512+d];
  __syncthreads();
  float acc=0.f;
  const bf16* wr=w+(long)d*768;
  for(int k4=0;k4<768;k4+=4){
    float v[4]; ld4bf(wr+k4,v);
    acc+=v[0]*xr[k4]+v[1]*xr[k4+1]+v[2]*xr[k4+2]+v[3]*xr[k4+3];
  }
  qnode[(b<<8)+d]=acc+ps*b2f(bias[d]);
}

// ---------------- score ----------------
__global__ __launch_bounds__(256) void k_score(const bf16* le, const bf16* sw,
    const bf16* sb, void* out, const int* dfl){
  const int isf=*dfl;
  int o=blockIdx.x*4 + (threadIdx.x>>6);
  int lane=threadIdx.x&63;
  float v[4],wv[4];
  ld4bf(le+(long)o*DD+lane*4,v); ld4bf(sw+lane*4,wv);
  float acc=v[0]*wv[0]+v[1]*wv[1]+v[2]*wv[2]+v[3]*wv[3];
  for(int off=32;off;off>>=1) acc+=__shfl_down(acc,off,64);
  if(!lane){
    float r=acc+b2f(sb[0]);
    if(isf) ((float*)out)[o]=r; else ((bf16*)out)[o]=f2b(r);
  }
}

// ---------------- host ----------------
extern "C" void kernel_launch(void* const* d_in, const int* in_sizes, int n_in,
                              void* d_out, int out_size, void* d_ws, size_t ws_size,
                              hipStream_t stream){
  const int*  local_entity=(const int*)d_in[0];
  const void* q2e_adj     =d_in[1];
  const int*  kb_fact_rel =(const int*)d_in[2];
  const int*  query_text  =(const int*)d_in[3];
  const int*  e2f_ent     =(const int*)d_in[5];
  const int*  f2e_ent     =(const int*)d_in[6];
  const void* word_emb    =d_in[7];
  const void* entity_emb  =d_in[8];
  const void* relation_emb=d_in[9];

  char* ws=(char*)d_ws;
  float* gx      =(float*)(ws+O_GX);
  float* qh      =(float*)(ws+O_QH);
  float* qnode   =(float*)(ws+O_QNODE);
  float* rel_lin =(float*)(ws+O_RELLIN);
  float* Wr      =(float*)(ws+O_WR);
  float* wmax    =(float*)(ws+O_WMAX);
  float* wt      =(float*)(ws+O_WT);
  float* e2fs    =(float*)(ws+O_E2FS);
  float* pr      =(float*)(ws+O_PR);
  float* pragg   =(float*)(ws+O_PRAGG);
  float* q2ev    =(float*)(ws+O_Q2EV);
  bf16*  q2evb   =(bf16*)(ws+O_Q2EVB);
  float* relself =(float*)(ws+O_RELSELF);
  float* normv   =(float*)(ws+O_NORM);
  float* wnxt    =(float*)(ws+O_WNXT);
  float* prsum   =(float*)(ws+O_PRSUM);
  int*   cnt     =(int*)(ws+O_CNT);
  int*   cur     =(int*)(ws+O_CUR);
  int*   bstart  =(int*)(ws+O_BSTART);
  int*   bidx    =(int*)(ws+O_BIDX);
  bf16*  elwpad  =(bf16*)(ws+O_ELWPAD);
  int*   dflag   =(int*)(ws+O_FLAG);
  bf16*  cw      =(bf16*)(ws+O_CVT);
  bf16*  agg     =(bf16*)(ws+O_AGG);
  bf16*  A0      =(bf16*)(ws+O_AGG);      // aliases agg + start of entself (pre-layer use only)
  bf16*  entself =(bf16*)(ws+O_ENTSELF);
  bf16*  leA     =(bf16*)(ws+O_LEA);
  bf16*  leB     =(bf16*)(ws+O_LEB);
  bf16*  headb   =(bf16*)(ws+O_HEAD);
  bf16*  f2eemb  =(bf16*)(ws+O_F2EEMB);
  // LSTM h-exchange: aliases leA (dead until the first mgemm, which runs after the LSTM)
  bf16*  hbuf    =(bf16*)(ws+O_LEA);              // 2 slots x 16x256 bf16 = 16KB
  int*   lcnt    =(int*)(ws+O_LEA+16384);         // 20 step flags

  k_sniff<<<1,256,0,stream>>>((const unsigned short*)entity_emb, dflag);

  CvtJobs J;
  int cntj=0;
  auto add=[&](int in_idx, long coff, int n, int sc){
    J.src[cntj]=d_in[in_idx]; J.dst[cntj]=cw+coff; J.n[cntj]=n; J.sc[cntj]=sc; cntj++;
  };
  add(11,C_ELB,256,0);
  add(12,C_RLW,153600,0);  add(13,C_RLB,256,0);
  add(14,C_WIH,307200,0);
  add(16,C_BIH,1024,0);    add(17,C_BHH,1024,0);
  add(18,C_Q2EW,196608,0); add(19,C_Q2EB,768,0);
  add(20,C_E2QW,589824,1); add(21,C_E2QB,768,0);
  add(22,C_E2EW,589824,1); add(23,C_E2EB,768,0);
  add(24,C_KHW,196608,0);  add(25,C_KHB,768,0);
  add(26,C_KTW,196608,0);  add(27,C_KTB,768,0);
  add(28,C_KSW,196608,0);  add(29,C_KSB,768,0);
  add(30,C_SCW,256,0);     add(31,C_SCB,1,0);
  k_cvt<<<dim3(576,20),256,0,stream>>>(J, dflag);
  k_cvtwhh<<<128,256,0,stream>>>(d_in[15], cw+C_WHH, dflag);
  k_cvtelw<<<256,256,0,stream>>>(d_in[10], elwpad, dflag);

  // CSR bucketing (fact graph is launch-constant); cnt+cur adjacent -> one memset
  hipMemsetAsync(cnt, 0, (size_t)2*BB*EE*4, stream);
  k_cnt <<<BB*FF/256,256,0,stream>>>(f2e_ent, cnt);
  k_scan<<<1,1024,0,stream>>>(cnt, bstart);
  k_fill<<<BB*FF/256,256,0,stream>>>(f2e_ent, bstart, cur, bidx);

  k_gx   <<<BB*QQ,256,0,stream>>>(query_text, word_emb, cw+C_WIH, cw+C_BIH, cw+C_BHH, gx, dflag);
  hipMemsetAsync(lcnt, 0, 128, stream);
  k_lstm4<<<NLB,512,0,stream>>>(gx, cw+C_WHH, qh, qnode, hbuf, lcnt);
  k_rel_lin<<<601,256,0,stream>>>(relation_emb, cw+C_RLW, cw+C_RLB, rel_lin, dflag);
  k_simwr<<<dim3(BB,3),256,0,stream>>>(qh, rel_lin, query_text, Wr);
  k_wmax <<<BB,256,0,stream>>>(Wr, kb_fact_rel, wmax);
  hipMemsetAsync(e2fs, 0, (size_t)BB*EE*4, stream);
  k_wt   <<<BB*FF/256,256,0,stream>>>(Wr, kb_fact_rel, wmax, e2f_ent, wt, e2fs);
  k_prinit<<<BB*EE/1024,256,0,stream>>>(q2e_adj, pr, dflag);

  // le = entity_emb[local_entity] @ elw^T + elb   (K padded to 320)
  k_ga0<<<BB*EE,128,0,stream>>>(local_entity, entity_emb, A0, dflag);
  {
    MG p{}; p.A=A0; p.W=elwpad; p.bias=cw+C_ELB; p.out=leA; p.K=320;
    k_mgemm<0,0,320,0><<<BB*EE/64,256,0,stream>>>(p);
  }

  bf16* le_cur=leA; bf16* le_nxt=leB;
  for(int i=0;i<3;i++){
    k_small<<<617,256,0,stream>>>(rel_lin, cw+C_KSW+(long)i*65536, cw+C_KSB+(long)i*256,
        qnode, cw+C_Q2EW+(long)i*65536, cw+C_Q2EB+(long)i*256, relself, q2ev, q2evb);
    { // fused head + self GEMMs (same A): y=0 -> head, y=1 -> self
      MG p{}; p.A=le_cur; p.K=256;
      p.W=cw+C_KHW+(long)i*65536;  p.bias=cw+C_KHB+(long)i*256;  p.out=headb;
      p.W2=cw+C_KSW+(long)i*65536; p.bias2=cw+C_KSB+(long)i*256; p.out2=entself;
      k_mgemm<0,0,256,1><<<dim3(BB*EE/64,2),256,0,stream>>>(p);
    }
    hipMemsetAsync(pragg, 0, (size_t)BB*EE*4, stream);
    k_norm<<<BB*FF/256,256,0,stream>>>(wt, pr, e2fs, e2f_ent, f2e_ent, normv, pragg);
    k_agg <<<BB*EE/4,256,0,stream>>>(bstart, bidx, kb_fact_rel, e2f_ent, normv, relself, headb, agg);
    {
      MG p{}; p.A=agg; p.W=cw+C_KTW+(long)i*65536; p.bias=cw+C_KTB+(long)i*256;
      p.out=f2eemb; p.K=256; p.cnt=cnt; p.addb=entself;
      k_mgemm<0,2,256,0><<<BB*EE/64,256,0,stream>>>(p);
    }
    hipMemsetAsync(wnxt, 0, (size_t)(BB*768*4+256), stream);
    k_wnxt <<<dim3(BB,32),256,0,stream>>>(pragg, pr, le_cur, f2eemb, wnxt, prsum);
    k_qnode<<<BB,256,0,stream>>>(wnxt, prsum, q2ev, cw+C_E2QW+(long)i*196608, cw+C_E2QB+(long)i*256, qnode);
    {
      MG p{}; p.A=le_cur; p.W=cw+C_E2EW+(long)i*196608; p.bias=cw+C_E2EB+(long)i*256;
      p.out=le_nxt; p.K=768; p.Aq2=q2evb; p.Af2=f2eemb;
      k_mgemm<1,1,768,0><<<BB*EE/64,256,0,stream>>>(p);
    }
    bf16* t=le_cur; le_cur=le_nxt; le_nxt=t;
  }

  k_score<<<BB*EE/4,256,0,stream>>>(le_cur, cw+C_SCW, cw+C_SCB, d_out, dflag);
}

// Round 5
// 1081.127 us; speedup vs baseline: 1.2960x; 1.0341x over previous
//
#include <hip/hip_runtime.h>
#include <hip/hip_bf16.h>

typedef __hip_bfloat16 bf16;
typedef __attribute__((ext_vector_type(8))) short bf16x8;
typedef __attribute__((ext_vector_type(4))) float f32x4;

#define BB 16
#define EE 2048
#define FF 8192
#define QQ 20
#define DD 256
#define WDIM 300
#define NWORD 50000
#define VERY_NEG_F (-1.0e11f)

static __device__ __forceinline__ float b2f(bf16 x){ return __bfloat162float(x); }
static __device__ __forceinline__ bf16 f2b(float x){ return __float2bfloat16(x); }
static __device__ __forceinline__ float sigm(float x){ return 1.f/(1.f+expf(-x)); }
static __device__ __forceinline__ void ld4bf(const bf16* p, float v[4]){
  short4 s = *(const short4*)p;
  v[0]=b2f(*(const bf16*)&s.x); v[1]=b2f(*(const bf16*)&s.y);
  v[2]=b2f(*(const bf16*)&s.z); v[3]=b2f(*(const bf16*)&s.w);
}
static __device__ __forceinline__ void st4bf(bf16* p, float a,float b,float c,float d){
  unsigned short u[4]; bf16 t;
  t=f2b(a);u[0]=*(unsigned short*)&t; t=f2b(b);u[1]=*(unsigned short*)&t;
  t=f2b(c);u[2]=*(unsigned short*)&t; t=f2b(d);u[3]=*(unsigned short*)&t;
  *(short4*)p=*(short4*)u;
}

// ---------------- workspace offsets (bytes) ----------------
#define O_GX       0UL
#define O_QH       1310720UL
#define O_QNODE    1638400UL
#define O_RELLIN   1654784UL
#define O_WR       2270208UL
#define O_WMAX     2308864UL
#define O_WT       2309120UL
#define O_E2FS     2833408UL
#define O_PR       2964480UL
#define O_PRAGG    3095552UL
#define O_Q2EV     3226624UL
#define O_Q2EVB    3243008UL
#define O_RELSELF  3251200UL
#define O_NORM     3866624UL
#define O_WNXT     4390912UL
#define O_PRSUM    4440064UL
#define O_CNT      4440320UL
#define O_CUR      4571392UL
#define O_BSTART   4702464UL
#define O_BIDX     4834048UL
#define O_ELWPAD   5358336UL
#define O_FLAG     5522176UL
#define O_CVT      5522432UL   // 5393152 B
#define O_AGG      10915584UL  // bf16 16.7MB; A0 (21MB) aliases AGG+start of ENTSELF
#define O_ENTSELF  27692800UL
#define O_LEA      44470016UL
#define O_LEB      61247232UL
#define O_HEAD     78024448UL
#define O_F2EEMB   94801664UL  // end ~111.6MB

// canonical element offsets within O_CVT (all mult of 8)
#define C_ELB   0
#define C_RLW   256
#define C_RLB   153856
#define C_WIH   154112
#define C_WHH   461312   // frag-linear w_hh (262144 elems)
#define C_BIH   723456
#define C_BHH   724480
#define C_Q2EW  725504
#define C_Q2EB  922112
#define C_E2QW  922880
#define C_E2QB  1512704
#define C_E2EW  1513472
#define C_E2EB  2103296
#define C_KHW   2104064
#define C_KHB   2300672
#define C_KTW   2301440
#define C_KTB   2498048
#define C_KSW   2498816
#define C_KSB   2695424
#define C_SCW   2696192
#define C_SCB   2696448

// ---------------- dtype sniffer (verified r2) ----------------
__global__ __launch_bounds__(256) void k_sniff(const unsigned short* ee, int* flag){
  __shared__ int red[256];
  int c=0;
  for(int i=threadIdx.x;i<4096;i+=256){
    int ex=(ee[2*i]>>7)&0xFF;
    c += (ex>=192);
  }
  red[threadIdx.x]=c; __syncthreads();
  for(int o=128;o;o>>=1){ if(threadIdx.x<o) red[threadIdx.x]+=red[threadIdx.x+o]; __syncthreads(); }
  if(!threadIdx.x) flag[0] = (red[0]>64) ? 1 : 0;
}

// ---------------- batched weight canonicalization -> bf16 (tail-scale for e2q/e2e) ----------------
struct CvtJobs{ const void* src[20]; bf16* dst[20]; int n[20]; int sc[20]; };
__global__ __launch_bounds__(256) void k_cvt(CvtJobs J, const int* dfl){
  const int isf=*dfl;
  int j=blockIdx.y;
  int n=J.n[j];
  int i4=(blockIdx.x*256+threadIdx.x)*4;
  if(i4>=n) return;
  float m = (J.sc[j] && ((i4%768)>=512)) ? 3.f : 1.f;
  bf16* d=J.dst[j]+i4;
  if(isf){
    const float* s=(const float*)J.src[j]+i4;
    if(i4+4<=n){ float4 t=*(const float4*)s; st4bf(d,t.x*m,t.y*m,t.z*m,t.w*m); }
    else for(int r=0;i4+r<n;r++) d[r]=f2b(s[r]*m);
  } else {
    const bf16* s=(const bf16*)J.src[j]+i4;
    if(i4+4<=n){ float v[4]; ld4bf(s,v); st4bf(d,v[0]*m,v[1]*m,v[2]*m,v[3]*m); }
    else for(int r=0;i4+r<n;r++) d[r]=f2b(b2f(s[r])*m);
  }
}

// w_hh (1024x256) -> MFMA-fragment-linear: wf[gt][kt][lane][8], gate=gt*16+(lane&15), k=kt*32+(lane>>4)*8+j
__global__ __launch_bounds__(256) void k_cvtwhh(const void* src, bf16* wf, const int* dfl){
  const int isf=*dfl;
  int fid=blockIdx.x*256+threadIdx.x;        // 0..32767
  int lane=fid&63, kt=(fid>>6)&7, gt=fid>>9;
  int l16=lane&15, q=lane>>4;
  long so=(long)(gt*16+l16)*256 + kt*32 + q*8;
  float v[8];
  if(isf){ const float* s=(const float*)src+so;
    #pragma unroll
    for(int j=0;j<8;j++) v[j]=s[j];
  } else { const bf16* s=(const bf16*)src+so; ld4bf(s,v); ld4bf(s+4,v+4); }
  bf16* d=wf+(long)fid*8;
  st4bf(d,v[0],v[1],v[2],v[3]); st4bf(d+4,v[4],v[5],v[6],v[7]);
}

// entity_lin_w (256x300) -> padded bf16 (256x320)
__global__ __launch_bounds__(256) void k_cvtelw(const void* src, bf16* dst, const int* dfl){
  const int isf=*dfl;
  int r=blockIdx.x;
  for(int c=threadIdx.x;c<320;c+=256){
    float v=0.f;
    if(c<300) v = isf ? ((const float*)src)[r*300+c] : b2f(((const bf16*)src)[r*300+c]);
    dst[(long)r*320+c]=f2b(v);
  }
}

// ---------------- CSR bucketing of facts by (b, f2e_ent) ----------------
__global__ __launch_bounds__(256) void k_cnt(const int* f2e, int* cnt){
  int i=blockIdx.x*256+threadIdx.x;
  atomicAdd(&cnt[((i>>13)<<11)+f2e[i]], 1);
}
__global__ __launch_bounds__(1024) void k_scan(const int* cnt, int* bstart){
  __shared__ int ps[1024];
  int t=threadIdx.x;
  int loc[32]; int s=0;
  #pragma unroll
  for(int j=0;j<32;j++){ loc[j]=s; s+=cnt[t*32+j]; }
  ps[t]=s; __syncthreads();
  for(int off=1;off<1024;off<<=1){
    int v=(t>=off)?ps[t-off]:0;
    __syncthreads(); ps[t]+=v; __syncthreads();
  }
  int base=(t? ps[t-1]:0);
  #pragma unroll
  for(int j=0;j<32;j++) bstart[t*32+j]=base+loc[j];
  if(t==1023) bstart[32768]=ps[1023];
}
__global__ __launch_bounds__(256) void k_fill(const int* f2e, const int* bstart, int* cur, int* bidx){
  int i=blockIdx.x*256+threadIdx.x;
  int key=((i>>13)<<11)+f2e[i];
  int pos=bstart[key]+atomicAdd(&cur[key],1);
  bidx[pos]=i;
}

// ---------------- gx = wemb[qtext] @ w_ih^T + b_ih + b_hh ----------------
__global__ __launch_bounds__(256) void k_gx(const int* qtext, const void* wemb,
    const bf16* wih, const bf16* bih, const bf16* bhh, float* gx, const int* dfl){
  const int isf=*dfl;
  int bt=blockIdx.x;
  __shared__ float xr[WDIM];
  int w=qtext[bt];
  for(int k4=threadIdx.x*4;k4<WDIM;k4+=1024){
    if(isf){ float4 t=*(const float4*)((const float*)wemb+(long)w*WDIM+k4);
             xr[k4]=t.x;xr[k4+1]=t.y;xr[k4+2]=t.z;xr[k4+3]=t.w; }
    else   { float v[4]; ld4bf((const bf16*)wemb+(long)w*WDIM+k4,v);
             xr[k4]=v[0];xr[k4+1]=v[1];xr[k4+2]=v[2];xr[k4+3]=v[3]; }
  }
  __syncthreads();
  #pragma unroll
  for(int s=0;s<4;s++){
    int g=threadIdx.x+256*s;
    float acc=b2f(bih[g])+b2f(bhh[g]);
    const bf16* wr=wih+(long)g*WDIM;
    for(int k4=0;k4<WDIM;k4+=4){
      float v[4]; ld4bf(wr+k4,v);
      acc+=v[0]*xr[k4]+v[1]*xr[k4+1]+v[2]*xr[k4+2]+v[3]*xr[k4+3];
    }
    gx[bt*1024+g]=acc;
  }
}

// ---------------- MEGA: distributed LSTM (blocks 0..7) + independent work hidden under it ----
// blocks 8..308   : rel_lin, 2 relations per block
// blocks 309..324 : prinit
// blocks 325..8516: ga0 gather, 4 rows per block
// LSTM sync per step: relaxed all-thread spin -> acquire fence (L2 inv, correctness belt);
// publish stores are agent-scope (L3-direct) + __syncthreads vmcnt drain -> RELAXED add
// (release writeback removed: stores are already complete at L3 when the add issues).
#define NLB 8
__global__ __launch_bounds__(512) void k_mega(const float* gx, const bf16* wf,
    float* qh, float* qnode, bf16* hbuf, int* lcnt,
    const void* remb, const bf16* rlw, const bf16* rlb, float* rel_lin,
    const int* local_entity, const void* emb, bf16* A0,
    const void* adj, float* pr, const int* dfl){
  const int bid=blockIdx.x, tid=threadIdx.x;
  if(bid<NLB){
    // ---- LSTM: block k owns hidden units [k*32,k*32+32) ----
    __shared__ bf16  hlds[16*264];
    __shared__ float zs[4*16*32];
    __shared__ bf16  hsl[512];
    const int k=bid;
    const int wv=tid>>6, lane=tid&63, q=lane>>4, l16=lane&15;
    const int gt=(wv>>1)*16 + k*2 + (wv&1);
    const int b=tid>>5, u=tid&31, gu=k*32+u;
    bf16x8 wreg[8];
    #pragma unroll
    for(int kt=0;kt<8;kt++)
      wreg[kt]=*(const bf16x8*)(wf + (((long)(gt*8+kt))*64 + lane)*8);
    float c=0.f;
    float gxr[4];
    #pragma unroll
    for(int g=0;g<4;g++) gxr[g]=gx[(b*QQ+0)*1024 + g*256 + gu];
    for(int t=0;t<QQ;t++){
      f32x4 acc=(f32x4){0.f,0.f,0.f,0.f};
      if(t){
        while(__hip_atomic_load(lcnt+(t-1), __ATOMIC_RELAXED, __HIP_MEMORY_SCOPE_AGENT) < NLB)
          __builtin_amdgcn_s_sleep(2);
        __builtin_amdgcn_fence(__ATOMIC_ACQUIRE, "agent");
        __builtin_amdgcn_sched_barrier(0);
        const bf16* hb = hbuf + (t&1)*4096;
        {
          int r=tid>>5, cc=(tid&31)*8;
          unsigned long long v0=__hip_atomic_load((const unsigned long long*)(hb + r*256 + cc),
                         __ATOMIC_RELAXED, __HIP_MEMORY_SCOPE_AGENT);
          unsigned long long v1=__hip_atomic_load((const unsigned long long*)(hb + r*256 + cc + 4),
                         __ATOMIC_RELAXED, __HIP_MEMORY_SCOPE_AGENT);
          *(unsigned long long*)&hlds[r*264 + cc] = v0;
          *(unsigned long long*)&hlds[r*264 + cc + 4] = v1;
        }
        __syncthreads();
        #pragma unroll
        for(int kt=0;kt<8;kt++){
          bf16x8 af=*(const bf16x8*)&hlds[l16*264 + kt*32 + q*8];
          acc=__builtin_amdgcn_mfma_f32_16x16x32_bf16(af,wreg[kt],acc,0,0,0);
        }
      }
      #pragma unroll
      for(int r=0;r<4;r++) zs[(wv>>1)*512 + (q*4+r)*32 + (wv&1)*16 + l16]=acc[r];
      __syncthreads();
      float zi=zs[0*512+b*32+u]+gxr[0];
      float zf=zs[1*512+b*32+u]+gxr[1];
      float zg=zs[2*512+b*32+u]+gxr[2];
      float zo=zs[3*512+b*32+u]+gxr[3];
      { int tn=(t<QQ-1)?t+1:t;
        #pragma unroll
        for(int g=0;g<4;g++) gxr[g]=gx[(b*QQ+tn)*1024 + g*256 + gu];
      }
      c=sigm(zf)*c+sigm(zi)*tanhf(zg);
      float hv=sigm(zo)*tanhf(c);
      hsl[tid]=f2b(hv);
      __syncthreads();
      if(t<QQ-1){
        if(tid<128){
          bf16* hw=hbuf + ((t+1)&1)*4096;
          int bb=tid>>3, p=tid&7;
          unsigned long long v=*(unsigned long long*)&hsl[bb*32+p*4];
          __hip_atomic_store((unsigned long long*)(hw + bb*256 + k*32 + p*4), v,
                             __ATOMIC_RELAXED, __HIP_MEMORY_SCOPE_AGENT);
        }
        __syncthreads();   // vmcnt(0) drain: publish stores complete at L3
        if(tid==0)
          __hip_atomic_fetch_add(lcnt+t, 1, __ATOMIC_RELAXED, __HIP_MEMORY_SCOPE_AGENT);
      }
      __builtin_nontemporal_store(hv, &qh[(long)(b*QQ+t)*256+gu]);
      if(t==QQ-1) qnode[(b<<8)+gu]=hv;
    }
  } else if(bid<309){
    // ---- rel_lin: 2 relations per block ----
    __shared__ float rr[2][2*WDIM];
    const int isf=*dfl;
    const int half=tid>>8, d=tid&255;
    const int r=(bid-8)*2+half;
    if(r<601){
      for(int k4=d*4;k4<2*WDIM;k4+=1024){
        if(isf){ float4 t4=*(const float4*)((const float*)remb+(long)r*2*WDIM+k4);
                 rr[half][k4]=t4.x;rr[half][k4+1]=t4.y;rr[half][k4+2]=t4.z;rr[half][k4+3]=t4.w; }
        else   { float v[4]; ld4bf((const bf16*)remb+(long)r*2*WDIM+k4,v);
                 rr[half][k4]=v[0];rr[half][k4+1]=v[1];rr[half][k4+2]=v[2];rr[half][k4+3]=v[3]; }
      }
    }
    __syncthreads();
    if(r<601){
      float acc=b2f(rlb[d]);
      const bf16* wr=rlw+(long)d*2*WDIM;
      for(int k4=0;k4<2*WDIM;k4+=4){
        float v[4]; ld4bf(wr+k4,v);
        acc+=v[0]*rr[half][k4]+v[1]*rr[half][k4+1]+v[2]*rr[half][k4+2]+v[3]*rr[half][k4+3];
      }
      rel_lin[r*DD+d]=acc;
    }
  } else if(bid<325){
    // ---- prinit ----
    const int isf=*dfl;
    int i4=((bid-309)*512+tid)*4;
    if(isf){ *(float4*)(pr+i4)=*(const float4*)((const float*)adj+i4); }
    else { float v[4]; ld4bf((const bf16*)adj+i4,v);
           float4 t; t.x=v[0];t.y=v[1];t.z=v[2];t.w=v[3]; *(float4*)(pr+i4)=t; }
  } else {
    // ---- ga0 gather: 4 rows per block ----
    const int isf=*dfl;
    int row=(bid-325)*4+(tid>>7); int t=tid&127;
    int ent=local_entity[row];
    bf16* dst=A0+(long)row*320;
    if(t<75){
      float v[4];
      if(isf){ float4 x=*(const float4*)((const float*)emb+(long)ent*WDIM+t*4);
               v[0]=x.x;v[1]=x.y;v[2]=x.z;v[3]=x.w; }
      else ld4bf((const bf16*)emb+(long)ent*WDIM+t*4, v);
      st4bf(dst+t*4, v[0],v[1],v[2],v[3]);
    } else if(t<80){
      st4bf(dst+t*4, 0.f,0.f,0.f,0.f);
    }
  }
}

// ---------------- sim + masked softmax + Wr (relation space) ----------------
__global__ __launch_bounds__(256) void k_simwr(const float* qh, const float* rel_lin,
    const int* qtext, float* Wr){
  int b = blockIdx.x, rc = blockIdx.y;
  __shared__ float qhb[QQ*DD];
  __shared__ float qm[QQ];
  for(int i=threadIdx.x;i<QQ*DD;i+=256) qhb[i]=qh[b*QQ*DD+i];
  if(threadIdx.x<QQ) qm[threadIdx.x] = (qtext[b*QQ+threadIdx.x]!=NWORD)?0.f:VERY_NEG_F;
  __syncthreads();
  int r = rc*256+threadIdx.x;
  if(r>=601) return;
  float s[QQ];
  #pragma unroll
  for(int q=0;q<QQ;q++) s[q]=0.f;
  for(int k=0;k<DD;k++){
    float rl = rel_lin[r*DD+k];
    #pragma unroll
    for(int q=0;q<QQ;q++) s[q] += qhb[q*DD+k]*rl;
  }
  float m=-1e30f;
  #pragma unroll
  for(int q=0;q<QQ;q++){ s[q]*=0.0625f; m=fmaxf(m, s[q]+qm[q]); }
  float sum=0.f, w=0.f;
  #pragma unroll
  for(int q=0;q<QQ;q++){ float p=expf(s[q]+qm[q]-m); sum+=p; w+=p*s[q]; }
  Wr[b*601+r] = w/sum;
}

// ---------------- Wmax / W_tilde / e2f_softmax ----------------
__global__ __launch_bounds__(256) void k_wmax(const float* Wr, const int* rel, float* wmax){
  int b=blockIdx.x; __shared__ float red[256];
  float m=-1e30f;
  for(int f=threadIdx.x;f<FF;f+=256) m=fmaxf(m, Wr[b*601+rel[b*FF+f]]);
  red[threadIdx.x]=m; __syncthreads();
  for(int o=128;o;o>>=1){ if(threadIdx.x<o) red[threadIdx.x]=fmaxf(red[threadIdx.x],red[threadIdx.x+o]); __syncthreads(); }
  if(!threadIdx.x) wmax[b]=red[0];
}
__global__ __launch_bounds__(256) void k_wt(const float* Wr, const int* rel,
    const float* wmax, const int* e2f, float* wt, float* e2fs){
  int i = blockIdx.x*256+threadIdx.x;
  int b = i>>13;
  float v = expf(Wr[b*601+rel[i]] - wmax[b]);
  wt[i]=v;
  atomicAdd(e2fs + (b<<11) + e2f[i], v);
}

// ---------------- MFMA GEMM: C[M,256] = A[M,K] @ W[256,K]^T, no LDS ----------------
struct MG {
  const bf16* A; const bf16* W; const bf16* bias;
  bf16* out; int K;
  const bf16* Aq2; const bf16* Af2;
  const int* cnt; const bf16* addb;
  const bf16* W2; const bf16* bias2; bf16* out2;
};
template<int CONCAT,int EPI,int TK,int DUAL>
__global__ __launch_bounds__(256) void k_mgemm(MG p){
  const int m0 = blockIdx.x*64;
  const int wave = threadIdx.x>>6, lane = threadIdx.x&63;
  const int q = lane>>4, l16 = lane&15;
  const int n0 = wave*64;
  const int bidx_ = m0>>11;
  const bf16* Wp = p.W; const bf16* biasp = p.bias; bf16* outp = p.out;
  if(DUAL && blockIdx.y){ Wp=p.W2; biasp=p.bias2; outp=p.out2; }
  f32x4 acc[4][4];
  #pragma unroll
  for(int i=0;i<4;i++)
    #pragma unroll
    for(int j=0;j<4;j++) acc[i][j]=(f32x4){0.f,0.f,0.f,0.f};
  #pragma unroll
  for(int k0=0;k0<TK;k0+=32){
    int kk=k0+q*8;
    bf16x8 af[4], bw[4];
    #pragma unroll
    for(int mi=0;mi<4;mi++){
      int row=m0+mi*16+l16;
      const bf16* ap;
      if(CONCAT){
        if(kk<256)      ap=p.A  +(long)row*256+kk;
        else if(kk<512) ap=p.Aq2+(bidx_<<8)+(kk-256);
        else            ap=p.Af2+(long)row*256+(kk-512);
      } else ap=p.A+(long)row*TK+kk;
      af[mi]=*(const bf16x8*)ap;
    }
    #pragma unroll
    for(int ni=0;ni<4;ni++)
      bw[ni]=*(const bf16x8*)(Wp+(long)(n0+ni*16+l16)*TK+kk);
    #pragma unroll
    for(int mi=0;mi<4;mi++)
      #pragma unroll
      for(int ni=0;ni<4;ni++)
        acc[mi][ni]=__builtin_amdgcn_mfma_f32_16x16x32_bf16(af[mi],bw[ni],acc[mi][ni],0,0,0);
  }
  #pragma unroll
  for(int ni=0;ni<4;ni++){
    int col=n0+ni*16+l16;
    float bv=b2f(biasp[col]);
    #pragma unroll
    for(int mi=0;mi<4;mi++){
      #pragma unroll
      for(int r=0;r<4;r++){
        int row=m0+mi*16+q*4+r;
        float v=acc[mi][ni][r];
        if(EPI==0) v+=bv;
        else if(EPI==1) v=fmaxf(v+bv,0.f);
        else {
          v += (float)p.cnt[row]*bv + b2f(p.addb[(long)row*256+col]);
          v=fmaxf(v,0.f);
        }
        outp[(long)row*256+col]=f2b(v);
      }
    }
  }
}

// ---------------- per-layer small mats ----------------
__global__ __launch_bounds__(256) void k_small(const float* rel_lin, const bf16* selfw,
    const bf16* selfb, const float* qnode, const bf16* q2ew, const bf16* q2eb,
    float* relself, float* q2ev, bf16* q2evb){
  __shared__ float xr[DD];
  int d=threadIdx.x;
  if(blockIdx.x<601){
    int r=blockIdx.x;
    xr[d]=rel_lin[r*DD+d]; __syncthreads();
    float acc=b2f(selfb[d]);
    const bf16* wr=selfw+(long)d*DD;
    for(int k4=0;k4<DD;k4+=4){
      float v[4]; ld4bf(wr+k4,v);
      acc+=v[0]*xr[k4]+v[1]*xr[k4+1]+v[2]*xr[k4+2]+v[3]*xr[k4+3];
    }
    relself[r*DD+d]=acc;
  } else {
    int b=blockIdx.x-601;
    xr[d]=qnode[(b<<8)+d]; __syncthreads();
    float acc=b2f(q2eb[d]);
    const bf16* wr=q2ew+(long)d*DD;
    for(int k4=0;k4<DD;k4+=4){
      float v[4]; ld4bf(wr+k4,v);
      acc+=v[0]*xr[k4]+v[1]*xr[k4+1]+v[2]*xr[k4+2]+v[3]*xr[k4+3];
    }
    q2ev[(b<<8)+d]=acc;
    q2evb[(b<<8)+d]=f2b(acc);
  }
}

// ---------------- norm + pagerank numerator scatter ----------------
__global__ __launch_bounds__(256) void k_norm(const float* wt, const float* pr,
    const float* e2fs, const int* e2f, const int* f2e, float* normv, float* pragg){
  int i=blockIdx.x*256+threadIdx.x;
  int b=i>>13;
  int e=e2f[i];
  float v=wt[i]*pr[(b<<11)+e]/fmaxf(e2fs[(b<<11)+e],1e-10f);
  normv[i]=v;
  atomicAdd(pragg+(b<<11)+f2e[i], v);
}

// ---------------- segmented fact aggregation (atomic-free) ----------------
__global__ __launch_bounds__(256) void k_agg(const int* bstart, const int* bidx,
    const int* rel, const int* e2f, const float* normv, const float* relself,
    const bf16* head, bf16* agg){
  int eidx=blockIdx.x*4+(threadIdx.x>>6);
  int lane=threadIdx.x&63;
  int b=eidx>>11;
  float a0=0.f,a1=0.f,a2=0.f,a3=0.f;
  int s=bstart[eidx], e=bstart[eidx+1];
  for(int i=s;i<e;i++){
    int f=bidx[i];
    int r=rel[f]; int ent=e2f[f]; float nv=normv[f];
    float4 rs=*(const float4*)&relself[r*DD+lane*4];
    float hd[4]; ld4bf(head+(long)(((b<<11)+ent)*DD+lane*4),hd);
    a0+=fmaxf(rs.x+hd[0],0.f)*nv; a1+=fmaxf(rs.y+hd[1],0.f)*nv;
    a2+=fmaxf(rs.z+hd[2],0.f)*nv; a3+=fmaxf(rs.w+hd[3],0.f)*nv;
  }
  st4bf(agg+(long)eidx*DD+lane*4, a0,a1,a2,a3);
}

// ---------------- weighted row-sums (fused pagerank update) ----------------
__global__ __launch_bounds__(256) void k_wnxt(const float* pragg, float* pr, const bf16* le,
    const bf16* f2e, float* wnxt, float* prsum){
  __shared__ float r1[4*256];
  __shared__ float r3[4*256];
  __shared__ float rp[4];
  const int b=blockIdx.x, ch=blockIdx.y;
  const int wv=threadIdx.x>>6, lane=threadIdx.x&63;
  const int pe0=(b<<11)+ch*64+wv*16;
  float pv=0.f;
  if(lane<16){
    pv=0.8f*pragg[pe0+lane]+0.2f*pr[pe0+lane];
    pr[pe0+lane]=pv;
  }
  float a1[4]={0.f,0.f,0.f,0.f}, a3[4]={0.f,0.f,0.f,0.f}, ap=0.f;
  #pragma unroll
  for(int r=0;r<16;r++){
    float p=__shfl(pv, r, 64);
    long base=((long)(pe0+r))<<8;
    float v1[4],v3[4];
    ld4bf(le +base+lane*4, v1);
    ld4bf(f2e+base+lane*4, v3);
    #pragma unroll
    for(int j=0;j<4;j++){ a1[j]+=p*v1[j]; a3[j]+=p*v3[j]; }
    ap+=p;
  }
  #pragma unroll
  for(int j=0;j<4;j++){ r1[wv*256+lane*4+j]=a1[j]; r3[wv*256+lane*4+j]=a3[j]; }
  if(!lane) rp[wv]=ap;
  __syncthreads();
  const int t=threadIdx.x;
  float s1=r1[t]+r1[256+t]+r1[512+t]+r1[768+t];
  float s3=r3[t]+r3[256+t]+r3[512+t]+r3[768+t];
  atomicAdd(&wnxt[b*768+t], s1);
  atomicAdd(&wnxt[b*768+512+t], s3);
  if(!t) atomicAdd(&prsum[b], rp[0]+rp[1]+rp[2]+rp[3]);
}

// note: e2q_w tail cols pre-scaled by 3 at cvt -> xr segment 3 is plain a3
__global__ __launch_bounds__(256) void k_qnode(const float* wnxt, const float* prsum,
    const float* q2ev, const bf16* w, const bf16* bias, float* qnode){
  int b=blockIdx.x, d=threadIdx.x;
  __shared__ float xr[768];
  float ps=prsum[b];
  xr[d]=wnxt[b*768+d];
  xr[256+d]=ps*q2ev[(b<<8)+d];
  xr[512+d]=wnxt[b*768+512+d];
  __syncthreads();
  float acc=0.f;
  const bf16* wr=w+(long)d*768;
  for(int k4=0;k4<768;k4+=4){
    float v[4]; ld4bf(wr+k4,v);
    acc+=v[0]*xr[k4]+v[1]*xr[k4+1]+v[2]*xr[k4+2]+v[3]*xr[k4+3];
  }
  qnode[(b<<8)+d]=acc+ps*b2f(bias[d]);
}

// ---------------- score ----------------
__global__ __launch_bounds__(256) void k_score(const bf16* le, const bf16* sw,
    const bf16* sb, void* out, const int* dfl){
  const int isf=*dfl;
  int o=blockIdx.x*4 + (threadIdx.x>>6);
  int lane=threadIdx.x&63;
  float v[4],wv[4];
  ld4bf(le+(long)o*DD+lane*4,v); ld4bf(sw+lane*4,wv);
  float acc=v[0]*wv[0]+v[1]*wv[1]+v[2]*wv[2]+v[3]*wv[3];
  for(int off=32;off;off>>=1) acc+=__shfl_down(acc,off,64);
  if(!lane){
    float r=acc+b2f(sb[0]);
    if(isf) ((float*)out)[o]=r; else ((bf16*)out)[o]=f2b(r);
  }
}

// ---------------- host ----------------
extern "C" void kernel_launch(void* const* d_in, const int* in_sizes, int n_in,
                              void* d_out, int out_size, void* d_ws, size_t ws_size,
                              hipStream_t stream){
  const int*  local_entity=(const int*)d_in[0];
  const void* q2e_adj     =d_in[1];
  const int*  kb_fact_rel =(const int*)d_in[2];
  const int*  query_text  =(const int*)d_in[3];
  const int*  e2f_ent     =(const int*)d_in[5];
  const int*  f2e_ent     =(const int*)d_in[6];
  const void* word_emb    =d_in[7];
  const void* entity_emb  =d_in[8];
  const void* relation_emb=d_in[9];

  char* ws=(char*)d_ws;
  float* gx      =(float*)(ws+O_GX);
  float* qh      =(float*)(ws+O_QH);
  float* qnode   =(float*)(ws+O_QNODE);
  float* rel_lin =(float*)(ws+O_RELLIN);
  float* Wr      =(float*)(ws+O_WR);
  float* wmax    =(float*)(ws+O_WMAX);
  float* wt      =(float*)(ws+O_WT);
  float* e2fs    =(float*)(ws+O_E2FS);
  float* pr      =(float*)(ws+O_PR);
  float* pragg   =(float*)(ws+O_PRAGG);
  float* q2ev    =(float*)(ws+O_Q2EV);
  bf16*  q2evb   =(bf16*)(ws+O_Q2EVB);
  float* relself =(float*)(ws+O_RELSELF);
  float* normv   =(float*)(ws+O_NORM);
  float* wnxt    =(float*)(ws+O_WNXT);
  float* prsum   =(float*)(ws+O_PRSUM);
  int*   cnt     =(int*)(ws+O_CNT);
  int*   cur     =(int*)(ws+O_CUR);
  int*   bstart  =(int*)(ws+O_BSTART);
  int*   bidx    =(int*)(ws+O_BIDX);
  bf16*  elwpad  =(bf16*)(ws+O_ELWPAD);
  int*   dflag   =(int*)(ws+O_FLAG);
  bf16*  cw      =(bf16*)(ws+O_CVT);
  bf16*  agg     =(bf16*)(ws+O_AGG);
  bf16*  A0      =(bf16*)(ws+O_AGG);      // aliases agg + start of entself (pre-layer use only)
  bf16*  entself =(bf16*)(ws+O_ENTSELF);
  bf16*  leA     =(bf16*)(ws+O_LEA);
  bf16*  leB     =(bf16*)(ws+O_LEB);
  bf16*  headb   =(bf16*)(ws+O_HEAD);
  bf16*  f2eemb  =(bf16*)(ws+O_F2EEMB);
  // LSTM h-exchange: aliases leA (dead until the first mgemm, which runs after the LSTM)
  bf16*  hbuf    =(bf16*)(ws+O_LEA);              // 2 slots x 16x256 bf16 = 16KB
  int*   lcnt    =(int*)(ws+O_LEA+16384);         // 20 step flags

  k_sniff<<<1,256,0,stream>>>((const unsigned short*)entity_emb, dflag);

  CvtJobs J;
  int cntj=0;
  auto add=[&](int in_idx, long coff, int n, int sc){
    J.src[cntj]=d_in[in_idx]; J.dst[cntj]=cw+coff; J.n[cntj]=n; J.sc[cntj]=sc; cntj++;
  };
  add(11,C_ELB,256,0);
  add(12,C_RLW,153600,0);  add(13,C_RLB,256,0);
  add(14,C_WIH,307200,0);
  add(16,C_BIH,1024,0);    add(17,C_BHH,1024,0);
  add(18,C_Q2EW,196608,0); add(19,C_Q2EB,768,0);
  add(20,C_E2QW,589824,1); add(21,C_E2QB,768,0);
  add(22,C_E2EW,589824,1); add(23,C_E2EB,768,0);
  add(24,C_KHW,196608,0);  add(25,C_KHB,768,0);
  add(26,C_KTW,196608,0);  add(27,C_KTB,768,0);
  add(28,C_KSW,196608,0);  add(29,C_KSB,768,0);
  add(30,C_SCW,256,0);     add(31,C_SCB,1,0);
  k_cvt<<<dim3(576,20),256,0,stream>>>(J, dflag);
  k_cvtwhh<<<128,256,0,stream>>>(d_in[15], cw+C_WHH, dflag);
  k_cvtelw<<<256,256,0,stream>>>(d_in[10], elwpad, dflag);

  // CSR bucketing (fact graph is launch-constant); cnt+cur adjacent -> one memset
  hipMemsetAsync(cnt, 0, (size_t)2*BB*EE*4, stream);
  k_cnt <<<BB*FF/256,256,0,stream>>>(f2e_ent, cnt);
  k_scan<<<1,1024,0,stream>>>(cnt, bstart);
  k_fill<<<BB*FF/256,256,0,stream>>>(f2e_ent, bstart, cur, bidx);

  k_gx   <<<BB*QQ,256,0,stream>>>(query_text, word_emb, cw+C_WIH, cw+C_BIH, cw+C_BHH, gx, dflag);
  hipMemsetAsync(lcnt, 0, 128, stream);
  // mega: lstm (8) + rel_lin (301) + prinit (16) + ga0 (8192)
  k_mega<<<8517,512,0,stream>>>(gx, cw+C_WHH, qh, qnode, hbuf, lcnt,
      relation_emb, cw+C_RLW, cw+C_RLB, rel_lin,
      local_entity, entity_emb, A0,
      q2e_adj, pr, dflag);
  k_simwr<<<dim3(BB,3),256,0,stream>>>(qh, rel_lin, query_text, Wr);
  k_wmax <<<BB,256,0,stream>>>(Wr, kb_fact_rel, wmax);
  hipMemsetAsync(e2fs, 0, (size_t)BB*EE*4, stream);
  k_wt   <<<BB*FF/256,256,0,stream>>>(Wr, kb_fact_rel, wmax, e2f_ent, wt, e2fs);

  // le = entity_emb[local_entity] @ elw^T + elb   (K padded to 320)
  {
    MG p{}; p.A=A0; p.W=elwpad; p.bias=cw+C_ELB; p.out=leA; p.K=320;
    k_mgemm<0,0,320,0><<<BB*EE/64,256,0,stream>>>(p);
  }

  bf16* le_cur=leA; bf16* le_nxt=leB;
  for(int i=0;i<3;i++){
    k_small<<<617,256,0,stream>>>(rel_lin, cw+C_KSW+(long)i*65536, cw+C_KSB+(long)i*256,
        qnode, cw+C_Q2EW+(long)i*65536, cw+C_Q2EB+(long)i*256, relself, q2ev, q2evb);
    { // fused head + self GEMMs (same A): y=0 -> head, y=1 -> self
      MG p{}; p.A=le_cur; p.K=256;
      p.W=cw+C_KHW+(long)i*65536;  p.bias=cw+C_KHB+(long)i*256;  p.out=headb;
      p.W2=cw+C_KSW+(long)i*65536; p.bias2=cw+C_KSB+(long)i*256; p.out2=entself;
      k_mgemm<0,0,256,1><<<dim3(BB*EE/64,2),256,0,stream>>>(p);
    }
    hipMemsetAsync(pragg, 0, (size_t)BB*EE*4, stream);
    k_norm<<<BB*FF/256,256,0,stream>>>(wt, pr, e2fs, e2f_ent, f2e_ent, normv, pragg);
    k_agg <<<BB*EE/4,256,0,stream>>>(bstart, bidx, kb_fact_rel, e2f_ent, normv, relself, headb, agg);
    {
      MG p{}; p.A=agg; p.W=cw+C_KTW+(long)i*65536; p.bias=cw+C_KTB+(long)i*256;
      p.out=f2eemb; p.K=256; p.cnt=cnt; p.addb=entself;
      k_mgemm<0,2,256,0><<<BB*EE/64,256,0,stream>>>(p);
    }
    hipMemsetAsync(wnxt, 0, (size_t)(BB*768*4+256), stream);
    k_wnxt <<<dim3(BB,32),256,0,stream>>>(pragg, pr, le_cur, f2eemb, wnxt, prsum);
    k_qnode<<<BB,256,0,stream>>>(wnxt, prsum, q2ev, cw+C_E2QW+(long)i*196608, cw+C_E2QB+(long)i*256, qnode);
    {
      MG p{}; p.A=le_cur; p.W=cw+C_E2EW+(long)i*196608; p.bias=cw+C_E2EB+(long)i*256;
      p.out=le_nxt; p.K=768; p.Aq2=q2evb; p.Af2=f2eemb;
      k_mgemm<1,1,768,0><<<BB*EE/64,256,0,stream>>>(p);
    }
    bf16* t=le_cur; le_cur=le_nxt; le_nxt=t;
  }

  k_score<<<BB*EE/4,256,0,stream>>>(le_cur, cw+C_SCW, cw+C_SCB, d_out, dflag);
}

// Round 6
// 979.154 us; speedup vs baseline: 1.4309x; 1.1041x over previous
//
#include <hip/hip_runtime.h>
#include <hip/hip_bf16.h>

typedef __hip_bfloat16 bf16;
typedef __attribute__((ext_vector_type(8))) short bf16x8;
typedef __attribute__((ext_vector_type(4))) float f32x4;

#define BB 16
#define EE 2048
#define FF 8192
#define QQ 20
#define DD 256
#define WDIM 300
#define NWORD 50000
#define VERY_NEG_F (-1.0e11f)

static __device__ __forceinline__ float b2f(bf16 x){ return __bfloat162float(x); }
static __device__ __forceinline__ bf16 f2b(float x){ return __float2bfloat16(x); }
static __device__ __forceinline__ float sigm(float x){ return 1.f/(1.f+expf(-x)); }
static __device__ __forceinline__ void ld4bf(const bf16* p, float v[4]){
  short4 s = *(const short4*)p;
  v[0]=b2f(*(const bf16*)&s.x); v[1]=b2f(*(const bf16*)&s.y);
  v[2]=b2f(*(const bf16*)&s.z); v[3]=b2f(*(const bf16*)&s.w);
}
static __device__ __forceinline__ void st4bf(bf16* p, float a,float b,float c,float d){
  unsigned short u[4]; bf16 t;
  t=f2b(a);u[0]=*(unsigned short*)&t; t=f2b(b);u[1]=*(unsigned short*)&t;
  t=f2b(c);u[2]=*(unsigned short*)&t; t=f2b(d);u[3]=*(unsigned short*)&t;
  *(short4*)p=*(short4*)u;
}

// ---------------- workspace offsets (bytes) ----------------
#define O_GX       0UL
#define O_QH       1310720UL
#define O_QNODE    1638400UL
#define O_RELLIN   1654784UL
#define O_WR       2270208UL
#define O_WMAX     2308864UL
#define O_WT       2309120UL
#define O_E2FS     2833408UL
#define O_PR       2964480UL
#define O_PRAGG    3095552UL
#define O_Q2EV     3226624UL
#define O_Q2EVB    3243008UL
#define O_RELSELF  3251200UL
#define O_NORM     3866624UL
#define O_WNXT     4390912UL
#define O_PRSUM    4440064UL
#define O_CNT      4440320UL
#define O_CUR      4571392UL
#define O_BSTART   4702464UL
#define O_BIDX     4834048UL
#define O_ELWPAD   5358336UL
#define O_FLAG     5522176UL
#define O_CVT      5522432UL   // 5393152 B
#define O_AGG      10915584UL  // bf16 16.7MB; A0 (21MB) aliases AGG+start of ENTSELF
#define O_ENTSELF  27692800UL
#define O_LEA      44470016UL
#define O_LEB      61247232UL
#define O_HEAD     78024448UL
#define O_F2EEMB   94801664UL  // end ~111.6MB

// canonical element offsets within O_CVT (all mult of 8)
#define C_ELB   0
#define C_RLW   256
#define C_RLB   153856
#define C_WIH   154112
#define C_WHH   461312   // frag-linear w_hh (262144 elems)
#define C_BIH   723456
#define C_BHH   724480
#define C_Q2EW  725504
#define C_Q2EB  922112
#define C_E2QW  922880
#define C_E2QB  1512704
#define C_E2EW  1513472
#define C_E2EB  2103296
#define C_KHW   2104064
#define C_KHB   2300672
#define C_KTW   2301440
#define C_KTB   2498048
#define C_KSW   2498816
#define C_KSB   2695424
#define C_SCW   2696192
#define C_SCB   2696448

// ---------------- dtype sniffer ----------------
__global__ __launch_bounds__(256) void k_sniff(const unsigned short* ee, int* flag){
  __shared__ int red[256];
  int c=0;
  for(int i=threadIdx.x;i<4096;i+=256){
    int ex=(ee[2*i]>>7)&0xFF;
    c += (ex>=192);
  }
  red[threadIdx.x]=c; __syncthreads();
  for(int o=128;o;o>>=1){ if(threadIdx.x<o) red[threadIdx.x]+=red[threadIdx.x+o]; __syncthreads(); }
  if(!threadIdx.x) flag[0] = (red[0]>64) ? 1 : 0;
}

// ---------------- batched weight canonicalization -> bf16 (tail-scale for e2q/e2e) ----------------
struct CvtJobs{ const void* src[20]; bf16* dst[20]; int n[20]; int sc[20]; };
__global__ __launch_bounds__(256) void k_cvt(CvtJobs J, const int* dfl){
  const int isf=*dfl;
  int j=blockIdx.y;
  int n=J.n[j];
  int i4=(blockIdx.x*256+threadIdx.x)*4;
  if(i4>=n) return;
  float m = (J.sc[j] && ((i4%768)>=512)) ? 3.f : 1.f;
  bf16* d=J.dst[j]+i4;
  if(isf){
    const float* s=(const float*)J.src[j]+i4;
    if(i4+4<=n){ float4 t=*(const float4*)s; st4bf(d,t.x*m,t.y*m,t.z*m,t.w*m); }
    else for(int r=0;i4+r<n;r++) d[r]=f2b(s[r]*m);
  } else {
    const bf16* s=(const bf16*)J.src[j]+i4;
    if(i4+4<=n){ float v[4]; ld4bf(s,v); st4bf(d,v[0]*m,v[1]*m,v[2]*m,v[3]*m); }
    else for(int r=0;i4+r<n;r++) d[r]=f2b(b2f(s[r])*m);
  }
}

// w_hh (1024x256) -> MFMA-fragment-linear
__global__ __launch_bounds__(256) void k_cvtwhh(const void* src, bf16* wf, const int* dfl){
  const int isf=*dfl;
  int fid=blockIdx.x*256+threadIdx.x;        // 0..32767
  int lane=fid&63, kt=(fid>>6)&7, gt=fid>>9;
  int l16=lane&15, q=lane>>4;
  long so=(long)(gt*16+l16)*256 + kt*32 + q*8;
  float v[8];
  if(isf){ const float* s=(const float*)src+so;
    #pragma unroll
    for(int j=0;j<8;j++) v[j]=s[j];
  } else { const bf16* s=(const bf16*)src+so; ld4bf(s,v); ld4bf(s+4,v+4); }
  bf16* d=wf+(long)fid*8;
  st4bf(d,v[0],v[1],v[2],v[3]); st4bf(d+4,v[4],v[5],v[6],v[7]);
}

// entity_lin_w (256x300) -> padded bf16 (256x320)
__global__ __launch_bounds__(256) void k_cvtelw(const void* src, bf16* dst, const int* dfl){
  const int isf=*dfl;
  int r=blockIdx.x;
  for(int c=threadIdx.x;c<320;c+=256){
    float v=0.f;
    if(c<300) v = isf ? ((const float*)src)[r*300+c] : b2f(((const bf16*)src)[r*300+c]);
    dst[(long)r*320+c]=f2b(v);
  }
}

// ---------------- CSR bucketing of facts by (b, f2e_ent) ----------------
__global__ __launch_bounds__(256) void k_cnt(const int* f2e, int* cnt){
  int i=blockIdx.x*256+threadIdx.x;
  atomicAdd(&cnt[((i>>13)<<11)+f2e[i]], 1);
}
__global__ __launch_bounds__(1024) void k_scan(const int* cnt, int* bstart){
  __shared__ int ps[1024];
  int t=threadIdx.x;
  int loc[32]; int s=0;
  #pragma unroll
  for(int j=0;j<32;j++){ loc[j]=s; s+=cnt[t*32+j]; }
  ps[t]=s; __syncthreads();
  for(int off=1;off<1024;off<<=1){
    int v=(t>=off)?ps[t-off]:0;
    __syncthreads(); ps[t]+=v; __syncthreads();
  }
  int base=(t? ps[t-1]:0);
  #pragma unroll
  for(int j=0;j<32;j++) bstart[t*32+j]=base+loc[j];
  if(t==1023) bstart[32768]=ps[1023];
}
__global__ __launch_bounds__(256) void k_fill(const int* f2e, const int* bstart, int* cur, int* bidx){
  int i=blockIdx.x*256+threadIdx.x;
  int key=((i>>13)<<11)+f2e[i];
  int pos=bstart[key]+atomicAdd(&cur[key],1);
  bidx[pos]=i;
}

// ---------------- gx = wemb[qtext] @ w_ih^T + b_ih + b_hh  (+lcnt zero) ----------------
__global__ __launch_bounds__(256) void k_gx(const int* qtext, const void* wemb,
    const bf16* wih, const bf16* bih, const bf16* bhh, float* gx, const int* dfl,
    int* lcnt){
  if(blockIdx.x==0 && threadIdx.x<32) lcnt[threadIdx.x]=0;
  const int isf=*dfl;
  int bt=blockIdx.x;
  __shared__ float xr[WDIM];
  int w=qtext[bt];
  for(int k4=threadIdx.x*4;k4<WDIM;k4+=1024){
    if(isf){ float4 t=*(const float4*)((const float*)wemb+(long)w*WDIM+k4);
             xr[k4]=t.x;xr[k4+1]=t.y;xr[k4+2]=t.z;xr[k4+3]=t.w; }
    else   { float v[4]; ld4bf((const bf16*)wemb+(long)w*WDIM+k4,v);
             xr[k4]=v[0];xr[k4+1]=v[1];xr[k4+2]=v[2];xr[k4+3]=v[3]; }
  }
  __syncthreads();
  #pragma unroll
  for(int s=0;s<4;s++){
    int g=threadIdx.x+256*s;
    float acc=b2f(bih[g])+b2f(bhh[g]);
    const bf16* wr=wih+(long)g*WDIM;
    for(int k4=0;k4<WDIM;k4+=4){
      float v[4]; ld4bf(wr+k4,v);
      acc+=v[0]*xr[k4]+v[1]*xr[k4+1]+v[2]*xr[k4+2]+v[3]*xr[k4+3];
    }
    gx[bt*1024+g]=acc;
  }
}

// ---------------- MEGA: distributed LSTM (blocks 0..7) + independent work hidden under it ----
// Sync per step: relaxed all-thread spin only. NO acquire fence: both the poll and the
// h-pulls are agent-scope atomic loads (read the L3 coherence point, bypass L2), and a
// wave issues vector loads in order, so h-loads issue only after the poll observed the
// flag; publishers' stores were vmcnt-drained before their flag add. sched_barrier pins
// the compiler. (Removes 20x8 whole-XCD L2 invalidates per LSTM run.)
#define NLB 8
__global__ __launch_bounds__(512) void k_mega(const float* gx, const bf16* wf,
    float* qh, float* qnode, bf16* hbuf, int* lcnt,
    const void* remb, const bf16* rlw, const bf16* rlb, float* rel_lin,
    const int* local_entity, const void* emb, bf16* A0,
    const void* adj, float* pr, const int* dfl){
  const int bid=blockIdx.x, tid=threadIdx.x;
  if(bid<NLB){
    // ---- LSTM: block k owns hidden units [k*32,k*32+32) ----
    __shared__ bf16  hlds[16*264];
    __shared__ float zs[4*16*32];
    __shared__ bf16  hsl[512];
    const int k=bid;
    const int wv=tid>>6, lane=tid&63, q=lane>>4, l16=lane&15;
    const int gt=(wv>>1)*16 + k*2 + (wv&1);
    const int b=tid>>5, u=tid&31, gu=k*32+u;
    bf16x8 wreg[8];
    #pragma unroll
    for(int kt=0;kt<8;kt++)
      wreg[kt]=*(const bf16x8*)(wf + (((long)(gt*8+kt))*64 + lane)*8);
    float c=0.f;
    float gxr[4];
    #pragma unroll
    for(int g=0;g<4;g++) gxr[g]=gx[(b*QQ+0)*1024 + g*256 + gu];
    for(int t=0;t<QQ;t++){
      f32x4 acc=(f32x4){0.f,0.f,0.f,0.f};
      if(t){
        while(__hip_atomic_load(lcnt+(t-1), __ATOMIC_RELAXED, __HIP_MEMORY_SCOPE_AGENT) < NLB)
          __builtin_amdgcn_s_sleep(2);
        __builtin_amdgcn_sched_barrier(0);
        const bf16* hb = hbuf + (t&1)*4096;
        {
          int r=tid>>5, cc=(tid&31)*8;
          unsigned long long v0=__hip_atomic_load((const unsigned long long*)(hb + r*256 + cc),
                         __ATOMIC_RELAXED, __HIP_MEMORY_SCOPE_AGENT);
          unsigned long long v1=__hip_atomic_load((const unsigned long long*)(hb + r*256 + cc + 4),
                         __ATOMIC_RELAXED, __HIP_MEMORY_SCOPE_AGENT);
          *(unsigned long long*)&hlds[r*264 + cc] = v0;
          *(unsigned long long*)&hlds[r*264 + cc + 4] = v1;
        }
        __syncthreads();
        #pragma unroll
        for(int kt=0;kt<8;kt++){
          bf16x8 af=*(const bf16x8*)&hlds[l16*264 + kt*32 + q*8];
          acc=__builtin_amdgcn_mfma_f32_16x16x32_bf16(af,wreg[kt],acc,0,0,0);
        }
      }
      #pragma unroll
      for(int r=0;r<4;r++) zs[(wv>>1)*512 + (q*4+r)*32 + (wv&1)*16 + l16]=acc[r];
      __syncthreads();
      float zi=zs[0*512+b*32+u]+gxr[0];
      float zf=zs[1*512+b*32+u]+gxr[1];
      float zg=zs[2*512+b*32+u]+gxr[2];
      float zo=zs[3*512+b*32+u]+gxr[3];
      { int tn=(t<QQ-1)?t+1:t;
        #pragma unroll
        for(int g=0;g<4;g++) gxr[g]=gx[(b*QQ+tn)*1024 + g*256 + gu];
      }
      c=sigm(zf)*c+sigm(zi)*tanhf(zg);
      float hv=sigm(zo)*tanhf(c);
      hsl[tid]=f2b(hv);
      __syncthreads();
      if(t<QQ-1){
        if(tid<128){
          bf16* hw=hbuf + ((t+1)&1)*4096;
          int bb=tid>>3, p=tid&7;
          unsigned long long v=*(unsigned long long*)&hsl[bb*32+p*4];
          __hip_atomic_store((unsigned long long*)(hw + bb*256 + k*32 + p*4), v,
                             __ATOMIC_RELAXED, __HIP_MEMORY_SCOPE_AGENT);
        }
        __syncthreads();   // vmcnt(0) drain: publish stores complete at L3
        if(tid==0)
          __hip_atomic_fetch_add(lcnt+t, 1, __ATOMIC_RELAXED, __HIP_MEMORY_SCOPE_AGENT);
      }
      __builtin_nontemporal_store(hv, &qh[(long)(b*QQ+t)*256+gu]);
      if(t==QQ-1) qnode[(b<<8)+gu]=hv;
    }
  } else if(bid<309){
    // ---- rel_lin: 2 relations per block ----
    __shared__ float rr[2][2*WDIM];
    const int isf=*dfl;
    const int half=tid>>8, d=tid&255;
    const int r=(bid-8)*2+half;
    if(r<601){
      for(int k4=d*4;k4<2*WDIM;k4+=1024){
        if(isf){ float4 t4=*(const float4*)((const float*)remb+(long)r*2*WDIM+k4);
                 rr[half][k4]=t4.x;rr[half][k4+1]=t4.y;rr[half][k4+2]=t4.z;rr[half][k4+3]=t4.w; }
        else   { float v[4]; ld4bf((const bf16*)remb+(long)r*2*WDIM+k4,v);
                 rr[half][k4]=v[0];rr[half][k4+1]=v[1];rr[half][k4+2]=v[2];rr[half][k4+3]=v[3]; }
      }
    }
    __syncthreads();
    if(r<601){
      float acc=b2f(rlb[d]);
      const bf16* wr=rlw+(long)d*2*WDIM;
      for(int k4=0;k4<2*WDIM;k4+=4){
        float v[4]; ld4bf(wr+k4,v);
        acc+=v[0]*rr[half][k4]+v[1]*rr[half][k4+1]+v[2]*rr[half][k4+2]+v[3]*rr[half][k4+3];
      }
      rel_lin[r*DD+d]=acc;
    }
  } else if(bid<325){
    // ---- prinit ----
    const int isf=*dfl;
    int i4=((bid-309)*512+tid)*4;
    if(isf){ *(float4*)(pr+i4)=*(const float4*)((const float*)adj+i4); }
    else { float v[4]; ld4bf((const bf16*)adj+i4,v);
           float4 t; t.x=v[0];t.y=v[1];t.z=v[2];t.w=v[3]; *(float4*)(pr+i4)=t; }
  } else {
    // ---- ga0 gather: 4 rows per block ----
    const int isf=*dfl;
    int row=(bid-325)*4+(tid>>7); int t=tid&127;
    int ent=local_entity[row];
    bf16* dst=A0+(long)row*320;
    if(t<75){
      float v[4];
      if(isf){ float4 x=*(const float4*)((const float*)emb+(long)ent*WDIM+t*4);
               v[0]=x.x;v[1]=x.y;v[2]=x.z;v[3]=x.w; }
      else ld4bf((const bf16*)emb+(long)ent*WDIM+t*4, v);
      st4bf(dst+t*4, v[0],v[1],v[2],v[3]);
    } else if(t<80){
      st4bf(dst+t*4, 0.f,0.f,0.f,0.f);
    }
  }
}

// ---------------- sim + masked softmax + Wr ----------------
__global__ __launch_bounds__(256) void k_simwr(const float* qh, const float* rel_lin,
    const int* qtext, float* Wr){
  int b = blockIdx.x, rc = blockIdx.y;
  __shared__ float qhb[QQ*DD];
  __shared__ float qm[QQ];
  for(int i=threadIdx.x;i<QQ*DD;i+=256) qhb[i]=qh[b*QQ*DD+i];
  if(threadIdx.x<QQ) qm[threadIdx.x] = (qtext[b*QQ+threadIdx.x]!=NWORD)?0.f:VERY_NEG_F;
  __syncthreads();
  int r = rc*256+threadIdx.x;
  if(r>=601) return;
  float s[QQ];
  #pragma unroll
  for(int q=0;q<QQ;q++) s[q]=0.f;
  for(int k=0;k<DD;k++){
    float rl = rel_lin[r*DD+k];
    #pragma unroll
    for(int q=0;q<QQ;q++) s[q] += qhb[q*DD+k]*rl;
  }
  float m=-1e30f;
  #pragma unroll
  for(int q=0;q<QQ;q++){ s[q]*=0.0625f; m=fmaxf(m, s[q]+qm[q]); }
  float sum=0.f, w=0.f;
  #pragma unroll
  for(int q=0;q<QQ;q++){ float p=expf(s[q]+qm[q]-m); sum+=p; w+=p*s[q]; }
  Wr[b*601+r] = w/sum;
}

// ---------------- Wmax (+e2fs zero) / W_tilde (+one-time zeros) ----------------
__global__ __launch_bounds__(256) void k_wmax(const float* Wr, const int* rel, float* wmax,
    float* e2fs){
  int b=blockIdx.x; __shared__ float red[256];
  { // zero e2fs (32768 floats over 4096 threads)
    int g=b*256+threadIdx.x;
    float4 z={0.f,0.f,0.f,0.f};
    *(float4*)(e2fs+g*8)=z; *(float4*)(e2fs+g*8+4)=z;
  }
  float m=-1e30f;
  for(int f=threadIdx.x;f<FF;f+=256) m=fmaxf(m, Wr[b*601+rel[b*FF+f]]);
  red[threadIdx.x]=m; __syncthreads();
  for(int o=128;o;o>>=1){ if(threadIdx.x<o) red[threadIdx.x]=fmaxf(red[threadIdx.x],red[threadIdx.x+o]); __syncthreads(); }
  if(!threadIdx.x) wmax[b]=red[0];
}
__global__ __launch_bounds__(256) void k_wt(const float* Wr, const int* rel,
    const float* wmax, const int* e2f, float* wt, float* e2fs,
    float* pragg, float* wnxtb, float* prsum){
  int i = blockIdx.x*256+threadIdx.x;
  // one-time zeros for layer-0 consumers (later layers self-clean via read-zero)
  if(i<32768) pragg[i]=0.f;
  if(i<12288) wnxtb[i]=0.f;
  if(i<16)    prsum[i]=0.f;
  int b = i>>13;
  float v = expf(Wr[b*601+rel[i]] - wmax[b]);
  wt[i]=v;
  atomicAdd(e2fs + (b<<11) + e2f[i], v);
}

// ---------------- MFMA GEMM core: C[64,256] = A[64,K] @ W[256,K]^T ----------------
template<int TK,int CONCAT,int EPI>
static __device__ __forceinline__ void mg_body(const bf16* A, const bf16* W,
    const bf16* bias, bf16* out, const bf16* Aq2, const bf16* Af2,
    const int* cnt, const bf16* addb, int m0, int tid){
  const int lane=tid&63, q=lane>>4, l16=lane&15;
  const int n0=(tid>>6)*64;
  const int bidx_=m0>>11;
  f32x4 acc[4][4];
  #pragma unroll
  for(int i=0;i<4;i++)
    #pragma unroll
    for(int j=0;j<4;j++) acc[i][j]=(f32x4){0.f,0.f,0.f,0.f};
  #pragma unroll
  for(int k0=0;k0<TK;k0+=32){
    int kk=k0+q*8;
    bf16x8 af[4], bw[4];
    #pragma unroll
    for(int mi=0;mi<4;mi++){
      int row=m0+mi*16+l16;
      const bf16* ap;
      if(CONCAT){
        if(kk<256)      ap=A  +(long)row*256+kk;
        else if(kk<512) ap=Aq2+(bidx_<<8)+(kk-256);
        else            ap=Af2+(long)row*256+(kk-512);
      } else ap=A+(long)row*TK+kk;
      af[mi]=*(const bf16x8*)ap;
    }
    #pragma unroll
    for(int ni=0;ni<4;ni++)
      bw[ni]=*(const bf16x8*)(W+(long)(n0+ni*16+l16)*TK+kk);
    #pragma unroll
    for(int mi=0;mi<4;mi++)
      #pragma unroll
      for(int ni=0;ni<4;ni++)
        acc[mi][ni]=__builtin_amdgcn_mfma_f32_16x16x32_bf16(af[mi],bw[ni],acc[mi][ni],0,0,0);
  }
  #pragma unroll
  for(int ni=0;ni<4;ni++){
    int col=n0+ni*16+l16;
    float bv=b2f(bias[col]);
    #pragma unroll
    for(int mi=0;mi<4;mi++){
      #pragma unroll
      for(int r=0;r<4;r++){
        int row=m0+mi*16+q*4+r;
        float v=acc[mi][ni][r];
        if(EPI==0) v+=bv;
        else if(EPI==1) v=fmaxf(v+bv,0.f);
        else {
          v += (float)cnt[row]*bv + b2f(addb[(long)row*256+col]);
          v=fmaxf(v,0.f);
        }
        out[(long)row*256+col]=f2b(v);
      }
    }
  }
}

struct MG {
  const bf16* A; const bf16* W; const bf16* bias; bf16* out;
  const bf16* Aq2; const bf16* Af2;
  const int* cnt; const bf16* addb;
};
template<int CONCAT,int EPI,int TK>
__global__ __launch_bounds__(256) void k_mgemm(MG p){
  mg_body<TK,CONCAT,EPI>(p.A,p.W,p.bias,p.out,p.Aq2,p.Af2,p.cnt,p.addb,
                         blockIdx.x*64,threadIdx.x);
}

// ---------------- per-layer fused dispatch #1: small mats + head/self GEMMs + norm ----
// blocks 0..616    : k_small (relself / q2ev)
// blocks 617..1640 : head gemm (512) then self gemm (512), both A=le
// blocks 1641..2152: norm + pagerank numerator scatter
struct L1 {
  const float* rel_lin; const bf16* ksw; const bf16* ksb;
  const float* qnode; const bf16* q2ew; const bf16* q2eb;
  float* relself; float* q2ev; bf16* q2evb;
  const bf16* A; const bf16* khw; const bf16* khb; bf16* headb; bf16* entself;
  const float* wt; const float* pr; const float* e2fs;
  const int* e2f; const int* f2e; float* normv; float* pragg;
};
__global__ __launch_bounds__(256) void k_lay1(L1 p){
  const int bid=blockIdx.x, tid=threadIdx.x;
  if(bid<617){
    __shared__ float xr[DD];
    int d=tid;
    if(bid<601){
      xr[d]=p.rel_lin[bid*DD+d]; __syncthreads();
      float acc=b2f(p.ksb[d]);
      const bf16* wr=p.ksw+(long)d*DD;
      for(int k4=0;k4<DD;k4+=4){
        float v[4]; ld4bf(wr+k4,v);
        acc+=v[0]*xr[k4]+v[1]*xr[k4+1]+v[2]*xr[k4+2]+v[3]*xr[k4+3];
      }
      p.relself[bid*DD+d]=acc;
    } else {
      int b=bid-601;
      xr[d]=p.qnode[(b<<8)+d]; __syncthreads();
      float acc=b2f(p.q2eb[d]);
      const bf16* wr=p.q2ew+(long)d*DD;
      for(int k4=0;k4<DD;k4+=4){
        float v[4]; ld4bf(wr+k4,v);
        acc+=v[0]*xr[k4]+v[1]*xr[k4+1]+v[2]*xr[k4+2]+v[3]*xr[k4+3];
      }
      p.q2ev[(b<<8)+d]=acc;
      p.q2evb[(b<<8)+d]=f2b(acc);
    }
  } else if(bid<1641){
    int g=bid-617;
    int m0=(g&511)*64;
    if(g<512) mg_body<256,0,0>(p.A,p.khw,p.khb,p.headb,0,0,0,0,m0,tid);
    else      mg_body<256,0,0>(p.A,p.ksw,p.ksb,p.entself,0,0,0,0,m0,tid);
  } else {
    int i=(bid-1641)*256+tid;
    int b=i>>13;
    int e=p.e2f[i];
    float v=p.wt[i]*p.pr[(b<<11)+e]/fmaxf(p.e2fs[(b<<11)+e],1e-10f);
    p.normv[i]=v;
    atomicAdd(p.pragg+(b<<11)+p.f2e[i], v);
  }
}

// ---------------- segmented fact aggregation (atomic-free) ----------------
__global__ __launch_bounds__(256) void k_agg(const int* bstart, const int* bidx,
    const int* rel, const int* e2f, const float* normv, const float* relself,
    const bf16* head, bf16* agg){
  int eidx=blockIdx.x*4+(threadIdx.x>>6);
  int lane=threadIdx.x&63;
  int b=eidx>>11;
  float a0=0.f,a1=0.f,a2=0.f,a3=0.f;
  int s=bstart[eidx], e=bstart[eidx+1];
  for(int i=s;i<e;i++){
    int f=bidx[i];
    int r=rel[f]; int ent=e2f[f]; float nv=normv[f];
    float4 rs=*(const float4*)&relself[r*DD+lane*4];
    float hd[4]; ld4bf(head+(long)(((b<<11)+ent)*DD+lane*4),hd);
    a0+=fmaxf(rs.x+hd[0],0.f)*nv; a1+=fmaxf(rs.y+hd[1],0.f)*nv;
    a2+=fmaxf(rs.z+hd[2],0.f)*nv; a3+=fmaxf(rs.w+hd[3],0.f)*nv;
  }
  st4bf(agg+(long)eidx*DD+lane*4, a0,a1,a2,a3);
}

// ---------------- weighted row-sums (fused pagerank update; pragg read-zero) ----------
__global__ __launch_bounds__(256) void k_wnxt(const float* praggc, float* pragg, float* pr,
    const bf16* le, const bf16* f2e, float* wnxt, float* prsum){
  __shared__ float r1[4*256];
  __shared__ float r3[4*256];
  __shared__ float rp[4];
  const int b=blockIdx.x, ch=blockIdx.y;
  const int wv=threadIdx.x>>6, lane=threadIdx.x&63;
  const int pe0=(b<<11)+ch*64+wv*16;
  float pv=0.f;
  if(lane<16){
    int pe=pe0+lane;
    pv=0.8f*praggc[pe]+0.2f*pr[pe];
    pr[pe]=pv;
    pragg[pe]=0.f;        // self-clean for next layer's scatter
  }
  float a1[4]={0.f,0.f,0.f,0.f}, a3[4]={0.f,0.f,0.f,0.f}, ap=0.f;
  #pragma unroll
  for(int r=0;r<16;r++){
    float p=__shfl(pv, r, 64);
    long base=((long)(pe0+r))<<8;
    float v1[4],v3[4];
    ld4bf(le +base+lane*4, v1);
    ld4bf(f2e+base+lane*4, v3);
    #pragma unroll
    for(int j=0;j<4;j++){ a1[j]+=p*v1[j]; a3[j]+=p*v3[j]; }
    ap+=p;
  }
  #pragma unroll
  for(int j=0;j<4;j++){ r1[wv*256+lane*4+j]=a1[j]; r3[wv*256+lane*4+j]=a3[j]; }
  if(!lane) rp[wv]=ap;
  __syncthreads();
  const int t=threadIdx.x;
  float s1=r1[t]+r1[256+t]+r1[512+t]+r1[768+t];
  float s3=r3[t]+r3[256+t]+r3[512+t]+r3[768+t];
  atomicAdd(&wnxt[b*768+t], s1);
  atomicAdd(&wnxt[b*768+512+t], s3);
  if(!t) atomicAdd(&prsum[b], rp[0]+rp[1]+rp[2]+rp[3]);
}

// ---------------- e2e GEMM (CONCAT) + qnode fused; wnxt/prsum read-zero --------------
__global__ __launch_bounds__(256) void k_e2eq(MG p, const float* q2ev,
    const bf16* qw, const bf16* qb, float* wnxtb, float* prsum, float* qnode){
  if(blockIdx.x<512){
    mg_body<768,1,1>(p.A,p.W,p.bias,p.out,p.Aq2,p.Af2,0,0,blockIdx.x*64,threadIdx.x);
  } else {
    int b=blockIdx.x-512, d=threadIdx.x;
    __shared__ float xr[768];
    float ps=prsum[b];
    xr[d]=wnxtb[b*768+d];            wnxtb[b*768+d]=0.f;
    xr[256+d]=ps*q2ev[(b<<8)+d];
    xr[512+d]=wnxtb[b*768+512+d];    wnxtb[b*768+512+d]=0.f;
    __syncthreads();                 // all loads drained (vmcnt) before the zero below
    if(d==0) prsum[b]=0.f;
    float acc=0.f;
    const bf16* wr=qw+(long)d*768;
    for(int k4=0;k4<768;k4+=4){
      float v[4]; ld4bf(wr+k4,v);
      acc+=v[0]*xr[k4]+v[1]*xr[k4+1]+v[2]*xr[k4+2]+v[3]*xr[k4+3];
    }
    qnode[(b<<8)+d]=acc+ps*b2f(qb[d]);
  }
}

// ---------------- score ----------------
__global__ __launch_bounds__(256) void k_score(const bf16* le, const bf16* sw,
    const bf16* sb, void* out, const int* dfl){
  const int isf=*dfl;
  int o=blockIdx.x*4 + (threadIdx.x>>6);
  int lane=threadIdx.x&63;
  float v[4],wv[4];
  ld4bf(le+(long)o*DD+lane*4,v); ld4bf(sw+lane*4,wv);
  float acc=v[0]*wv[0]+v[1]*wv[1]+v[2]*wv[2]+v[3]*wv[3];
  for(int off=32;off;off>>=1) acc+=__shfl_down(acc,off,64);
  if(!lane){
    float r=acc+b2f(sb[0]);
    if(isf) ((float*)out)[o]=r; else ((bf16*)out)[o]=f2b(r);
  }
}

// ---------------- host ----------------
extern "C" void kernel_launch(void* const* d_in, const int* in_sizes, int n_in,
                              void* d_out, int out_size, void* d_ws, size_t ws_size,
                              hipStream_t stream){
  const int*  local_entity=(const int*)d_in[0];
  const void* q2e_adj     =d_in[1];
  const int*  kb_fact_rel =(const int*)d_in[2];
  const int*  query_text  =(const int*)d_in[3];
  const int*  e2f_ent     =(const int*)d_in[5];
  const int*  f2e_ent     =(const int*)d_in[6];
  const void* word_emb    =d_in[7];
  const void* entity_emb  =d_in[8];
  const void* relation_emb=d_in[9];

  char* ws=(char*)d_ws;
  float* gx      =(float*)(ws+O_GX);
  float* qh      =(float*)(ws+O_QH);
  float* qnode   =(float*)(ws+O_QNODE);
  float* rel_lin =(float*)(ws+O_RELLIN);
  float* Wr      =(float*)(ws+O_WR);
  float* wmax    =(float*)(ws+O_WMAX);
  float* wt      =(float*)(ws+O_WT);
  float* e2fs    =(float*)(ws+O_E2FS);
  float* pr      =(float*)(ws+O_PR);
  float* pragg   =(float*)(ws+O_PRAGG);
  float* q2ev    =(float*)(ws+O_Q2EV);
  bf16*  q2evb   =(bf16*)(ws+O_Q2EVB);
  float* relself =(float*)(ws+O_RELSELF);
  float* normv   =(float*)(ws+O_NORM);
  float* wnxt    =(float*)(ws+O_WNXT);
  float* prsum   =(float*)(ws+O_PRSUM);
  int*   cnt     =(int*)(ws+O_CNT);
  int*   cur     =(int*)(ws+O_CUR);
  int*   bstart  =(int*)(ws+O_BSTART);
  int*   bidx    =(int*)(ws+O_BIDX);
  bf16*  elwpad  =(bf16*)(ws+O_ELWPAD);
  int*   dflag   =(int*)(ws+O_FLAG);
  bf16*  cw      =(bf16*)(ws+O_CVT);
  bf16*  agg     =(bf16*)(ws+O_AGG);
  bf16*  A0      =(bf16*)(ws+O_AGG);      // aliases agg + start of entself (pre-layer use only)
  bf16*  entself =(bf16*)(ws+O_ENTSELF);
  bf16*  leA     =(bf16*)(ws+O_LEA);
  bf16*  leB     =(bf16*)(ws+O_LEB);
  bf16*  headb   =(bf16*)(ws+O_HEAD);
  bf16*  f2eemb  =(bf16*)(ws+O_F2EEMB);
  // LSTM h-exchange: aliases leA (dead until the first mgemm, which runs after the LSTM)
  bf16*  hbuf    =(bf16*)(ws+O_LEA);              // 2 slots x 16x256 bf16 = 16KB
  int*   lcnt    =(int*)(ws+O_LEA+16384);         // 20 step flags

  k_sniff<<<1,256,0,stream>>>((const unsigned short*)entity_emb, dflag);

  CvtJobs J;
  int cntj=0;
  auto add=[&](int in_idx, long coff, int n, int sc){
    J.src[cntj]=d_in[in_idx]; J.dst[cntj]=cw+coff; J.n[cntj]=n; J.sc[cntj]=sc; cntj++;
  };
  add(11,C_ELB,256,0);
  add(12,C_RLW,153600,0);  add(13,C_RLB,256,0);
  add(14,C_WIH,307200,0);
  add(16,C_BIH,1024,0);    add(17,C_BHH,1024,0);
  add(18,C_Q2EW,196608,0); add(19,C_Q2EB,768,0);
  add(20,C_E2QW,589824,1); add(21,C_E2QB,768,0);
  add(22,C_E2EW,589824,1); add(23,C_E2EB,768,0);
  add(24,C_KHW,196608,0);  add(25,C_KHB,768,0);
  add(26,C_KTW,196608,0);  add(27,C_KTB,768,0);
  add(28,C_KSW,196608,0);  add(29,C_KSB,768,0);
  add(30,C_SCW,256,0);     add(31,C_SCB,1,0);
  k_cvt<<<dim3(576,20),256,0,stream>>>(J, dflag);
  k_cvtwhh<<<128,256,0,stream>>>(d_in[15], cw+C_WHH, dflag);
  k_cvtelw<<<256,256,0,stream>>>(d_in[10], elwpad, dflag);

  // CSR bucketing (fact graph is launch-constant); cnt+cur adjacent -> one memset
  hipMemsetAsync(cnt, 0, (size_t)2*BB*EE*4, stream);
  k_cnt <<<BB*FF/256,256,0,stream>>>(f2e_ent, cnt);
  k_scan<<<1,1024,0,stream>>>(cnt, bstart);
  k_fill<<<BB*FF/256,256,0,stream>>>(f2e_ent, bstart, cur, bidx);

  k_gx   <<<BB*QQ,256,0,stream>>>(query_text, word_emb, cw+C_WIH, cw+C_BIH, cw+C_BHH, gx, dflag, lcnt);
  // mega: lstm (8) + rel_lin (301) + prinit (16) + ga0 (8192)
  k_mega<<<8517,512,0,stream>>>(gx, cw+C_WHH, qh, qnode, hbuf, lcnt,
      relation_emb, cw+C_RLW, cw+C_RLB, rel_lin,
      local_entity, entity_emb, A0,
      q2e_adj, pr, dflag);
  k_simwr<<<dim3(BB,3),256,0,stream>>>(qh, rel_lin, query_text, Wr);
  k_wmax <<<BB,256,0,stream>>>(Wr, kb_fact_rel, wmax, e2fs);
  k_wt   <<<BB*FF/256,256,0,stream>>>(Wr, kb_fact_rel, wmax, e2f_ent, wt, e2fs,
                                      pragg, wnxt, prsum);

  // le = entity_emb[local_entity] @ elw^T + elb   (K padded to 320)
  {
    MG p{}; p.A=A0; p.W=elwpad; p.bias=cw+C_ELB; p.out=leA;
    k_mgemm<0,0,320><<<BB*EE/64,256,0,stream>>>(p);
  }

  bf16* le_cur=leA; bf16* le_nxt=leB;
  for(int i=0;i<3;i++){
    { // fused: small mats + head/self GEMMs + norm scatter
      L1 p{};
      p.rel_lin=rel_lin; p.ksw=cw+C_KSW+(long)i*65536; p.ksb=cw+C_KSB+(long)i*256;
      p.qnode=qnode; p.q2ew=cw+C_Q2EW+(long)i*65536; p.q2eb=cw+C_Q2EB+(long)i*256;
      p.relself=relself; p.q2ev=q2ev; p.q2evb=q2evb;
      p.A=le_cur; p.khw=cw+C_KHW+(long)i*65536; p.khb=cw+C_KHB+(long)i*256;
      p.headb=headb; p.entself=entself;
      p.wt=wt; p.pr=pr; p.e2fs=e2fs;
      p.e2f=e2f_ent; p.f2e=f2e_ent; p.normv=normv; p.pragg=pragg;
      k_lay1<<<2153,256,0,stream>>>(p);
    }
    k_agg <<<BB*EE/4,256,0,stream>>>(bstart, bidx, kb_fact_rel, e2f_ent, normv, relself, headb, agg);
    {
      MG p{}; p.A=agg; p.W=cw+C_KTW+(long)i*65536; p.bias=cw+C_KTB+(long)i*256;
      p.out=f2eemb; p.cnt=cnt; p.addb=entself;
      k_mgemm<0,2,256><<<BB*EE/64,256,0,stream>>>(p);
    }
    k_wnxt <<<dim3(BB,32),256,0,stream>>>(pragg, pragg, pr, le_cur, f2eemb, wnxt, prsum);
    { // fused: e2e GEMM (CONCAT) + qnode
      MG p{}; p.A=le_cur; p.W=cw+C_E2EW+(long)i*196608; p.bias=cw+C_E2EB+(long)i*256;
      p.out=le_nxt; p.Aq2=q2evb; p.Af2=f2eemb;
      k_e2eq<<<512+BB,256,0,stream>>>(p, q2ev,
          cw+C_E2QW+(long)i*196608, cw+C_E2QB+(long)i*256, wnxt, prsum, qnode);
    }
    bf16* t=le_cur; le_cur=le_nxt; le_nxt=t;
  }

  k_score<<<BB*EE/4,256,0,stream>>>(le_cur, cw+C_SCW, cw+C_SCB, d_out, dflag);
}

// Round 9
// 956.252 us; speedup vs baseline: 1.4652x; 1.0239x over previous
//
#include <hip/hip_runtime.h>
#include <hip/hip_bf16.h>

typedef __hip_bfloat16 bf16;
typedef __attribute__((ext_vector_type(8))) short bf16x8;
typedef __attribute__((ext_vector_type(4))) float f32x4;
typedef __attribute__((address_space(1))) const void* gas_t;
typedef __attribute__((address_space(3))) void* las_t;

#define BB 16
#define EE 2048
#define FF 8192
#define QQ 20
#define DD 256
#define WDIM 300
#define NWORD 50000
#define VERY_NEG_F (-1.0e11f)

static __device__ __forceinline__ float b2f(bf16 x){ return __bfloat162float(x); }
static __device__ __forceinline__ bf16 f2b(float x){ return __float2bfloat16(x); }
static __device__ __forceinline__ float sigm(float x){ return 1.f/(1.f+expf(-x)); }
static __device__ __forceinline__ void ld4bf(const bf16* p, float v[4]){
  short4 s = *(const short4*)p;
  v[0]=b2f(*(const bf16*)&s.x); v[1]=b2f(*(const bf16*)&s.y);
  v[2]=b2f(*(const bf16*)&s.z); v[3]=b2f(*(const bf16*)&s.w);
}
static __device__ __forceinline__ void st4bf(bf16* p, float a,float b,float c,float d){
  unsigned short u[4]; bf16 t;
  t=f2b(a);u[0]=*(unsigned short*)&t; t=f2b(b);u[1]=*(unsigned short*)&t;
  t=f2b(c);u[2]=*(unsigned short*)&t; t=f2b(d);u[3]=*(unsigned short*)&t;
  *(short4*)p=*(short4*)u;
}

// ---------------- workspace offsets (bytes) ----------------
#define O_GX       0UL
#define O_QH       1310720UL
#define O_QNODE    1638400UL
#define O_RELLIN   1654784UL
#define O_WR       2270208UL
#define O_WMAX     2308864UL
#define O_WT       2309120UL
#define O_E2FS     2833408UL
#define O_PR       2964480UL
#define O_PRAGG    3095552UL
#define O_Q2EV     3226624UL
#define O_Q2EVB    3243008UL
#define O_RELSELF  3251200UL
#define O_NORM     3866624UL
#define O_WNXT     4390912UL
#define O_PRSUM    4440064UL
#define O_CNT      4440320UL
#define O_CUR      4571392UL
#define O_BSTART   4702464UL
#define O_BIDX     4834048UL
#define O_ELWPAD   5358336UL
#define O_FLAG     5522176UL
#define O_CVT      5522432UL   // 5393152 B
#define O_AGG      10915584UL  // bf16 16.7MB; A0 (21MB) aliases AGG+start of ENTSELF
#define O_ENTSELF  27692800UL
#define O_LEA      44470016UL
#define O_LEB      61247232UL
#define O_HEAD     78024448UL
#define O_F2EEMB   94801664UL  // end ~111.6MB

// canonical element offsets within O_CVT (all mult of 8)
#define C_ELB   0
#define C_RLW   256
#define C_RLB   153856
#define C_WIH   154112
#define C_WHH   461312   // frag-linear w_hh (262144 elems)
#define C_BIH   723456
#define C_BHH   724480
#define C_Q2EW  725504
#define C_Q2EB  922112
#define C_E2QW  922880
#define C_E2QB  1512704
#define C_E2EW  1513472
#define C_E2EB  2103296
#define C_KHW   2104064
#define C_KHB   2300672
#define C_KTW   2301440
#define C_KTB   2498048
#define C_KSW   2498816
#define C_KSB   2695424
#define C_SCW   2696192
#define C_SCB   2696448

// ---------------- dtype sniffer ----------------
__global__ __launch_bounds__(256) void k_sniff(const unsigned short* ee, int* flag){
  __shared__ int red[256];
  int c=0;
  for(int i=threadIdx.x;i<4096;i+=256){
    int ex=(ee[2*i]>>7)&0xFF;
    c += (ex>=192);
  }
  red[threadIdx.x]=c; __syncthreads();
  for(int o=128;o;o>>=1){ if(threadIdx.x<o) red[threadIdx.x]+=red[threadIdx.x+o]; __syncthreads(); }
  if(!threadIdx.x) flag[0] = (red[0]>64) ? 1 : 0;
}

// ---------------- batched weight canonicalization -> bf16 ----------------
struct CvtJobs{ const void* src[20]; bf16* dst[20]; int n[20]; int sc[20]; };
__global__ __launch_bounds__(256) void k_cvt(CvtJobs J, const int* dfl){
  const int isf=*dfl;
  int j=blockIdx.y;
  int n=J.n[j];
  int i4=(blockIdx.x*256+threadIdx.x)*4;
  if(i4>=n) return;
  float m = (J.sc[j] && ((i4%768)>=512)) ? 3.f : 1.f;
  bf16* d=J.dst[j]+i4;
  if(isf){
    const float* s=(const float*)J.src[j]+i4;
    if(i4+4<=n){ float4 t=*(const float4*)s; st4bf(d,t.x*m,t.y*m,t.z*m,t.w*m); }
    else for(int r=0;i4+r<n;r++) d[r]=f2b(s[r]*m);
  } else {
    const bf16* s=(const bf16*)J.src[j]+i4;
    if(i4+4<=n){ float v[4]; ld4bf(s,v); st4bf(d,v[0]*m,v[1]*m,v[2]*m,v[3]*m); }
    else for(int r=0;i4+r<n;r++) d[r]=f2b(b2f(s[r])*m);
  }
}

// w_hh (1024x256) -> MFMA-fragment-linear
__global__ __launch_bounds__(256) void k_cvtwhh(const void* src, bf16* wf, const int* dfl){
  const int isf=*dfl;
  int fid=blockIdx.x*256+threadIdx.x;        // 0..32767
  int lane=fid&63, kt=(fid>>6)&7, gt=fid>>9;
  int l16=lane&15, q=lane>>4;
  long so=(long)(gt*16+l16)*256 + kt*32 + q*8;
  float v[8];
  if(isf){ const float* s=(const float*)src+so;
    #pragma unroll
    for(int j=0;j<8;j++) v[j]=s[j];
  } else { const bf16* s=(const bf16*)src+so; ld4bf(s,v); ld4bf(s+4,v+4); }
  bf16* d=wf+(long)fid*8;
  st4bf(d,v[0],v[1],v[2],v[3]); st4bf(d+4,v[4],v[5],v[6],v[7]);
}

// entity_lin_w (256x300) -> padded bf16 (256x320)
__global__ __launch_bounds__(256) void k_cvtelw(const void* src, bf16* dst, const int* dfl){
  const int isf=*dfl;
  int r=blockIdx.x;
  for(int c=threadIdx.x;c<320;c+=256){
    float v=0.f;
    if(c<300) v = isf ? ((const float*)src)[r*300+c] : b2f(((const bf16*)src)[r*300+c]);
    dst[(long)r*320+c]=f2b(v);
  }
}

// ---------------- CSR bucketing of facts by (b, f2e_ent) ----------------
__global__ __launch_bounds__(256) void k_cnt(const int* f2e, int* cnt){
  int i=blockIdx.x*256+threadIdx.x;
  atomicAdd(&cnt[((i>>13)<<11)+f2e[i]], 1);
}
__global__ __launch_bounds__(1024) void k_scan(const int* cnt, int* bstart){
  __shared__ int ps[1024];
  int t=threadIdx.x;
  int loc[32]; int s=0;
  #pragma unroll
  for(int j=0;j<32;j++){ loc[j]=s; s+=cnt[t*32+j]; }
  ps[t]=s; __syncthreads();
  for(int off=1;off<1024;off<<=1){
    int v=(t>=off)?ps[t-off]:0;
    __syncthreads(); ps[t]+=v; __syncthreads();
  }
  int base=(t? ps[t-1]:0);
  #pragma unroll
  for(int j=0;j<32;j++) bstart[t*32+j]=base+loc[j];
  if(t==1023) bstart[32768]=ps[1023];
}
__global__ __launch_bounds__(256) void k_fill(const int* f2e, const int* bstart, int* cur, int* bidx){
  int i=blockIdx.x*256+threadIdx.x;
  int key=((i>>13)<<11)+f2e[i];
  int pos=bstart[key]+atomicAdd(&cur[key],1);
  bidx[pos]=i;
}

// ---------------- gx = wemb[qtext] @ w_ih^T + b_ih + b_hh  (+lcnt zero) ----------------
__global__ __launch_bounds__(256) void k_gx(const int* qtext, const void* wemb,
    const bf16* wih, const bf16* bih, const bf16* bhh, float* gx, const int* dfl,
    int* lcnt){
  if(blockIdx.x==0 && threadIdx.x<32) lcnt[threadIdx.x]=0;
  const int isf=*dfl;
  int bt=blockIdx.x;
  __shared__ float xr[WDIM];
  int w=qtext[bt];
  for(int k4=threadIdx.x*4;k4<WDIM;k4+=1024){
    if(isf){ float4 t=*(const float4*)((const float*)wemb+(long)w*WDIM+k4);
             xr[k4]=t.x;xr[k4+1]=t.y;xr[k4+2]=t.z;xr[k4+3]=t.w; }
    else   { float v[4]; ld4bf((const bf16*)wemb+(long)w*WDIM+k4,v);
             xr[k4]=v[0];xr[k4+1]=v[1];xr[k4+2]=v[2];xr[k4+3]=v[3]; }
  }
  __syncthreads();
  #pragma unroll
  for(int s=0;s<4;s++){
    int g=threadIdx.x+256*s;
    float acc=b2f(bih[g])+b2f(bhh[g]);
    const bf16* wr=wih+(long)g*WDIM;
    for(int k4=0;k4<WDIM;k4+=4){
      float v[4]; ld4bf(wr+k4,v);
      acc+=v[0]*xr[k4]+v[1]*xr[k4+1]+v[2]*xr[k4+2]+v[3]*xr[k4+3];
    }
    gx[bt*1024+g]=acc;
  }
}

// ---------------- MEGA: distributed LSTM (blocks 0..7) + independent work under it ----
#define NLB 8
__global__ __launch_bounds__(512) void k_mega(const float* gx, const bf16* wf,
    float* qh, float* qnode, bf16* hbuf, int* lcnt,
    const void* remb, const bf16* rlw, const bf16* rlb, float* rel_lin,
    const int* local_entity, const void* emb, bf16* A0,
    const void* adj, float* pr, const int* dfl){
  const int bid=blockIdx.x, tid=threadIdx.x;
  if(bid<NLB){
    __shared__ bf16  hlds[16*264];
    __shared__ float zs[4*16*32];
    __shared__ bf16  hsl[512];
    const int k=bid;
    const int wv=tid>>6, lane=tid&63, q=lane>>4, l16=lane&15;
    const int gt=(wv>>1)*16 + k*2 + (wv&1);
    const int b=tid>>5, u=tid&31, gu=k*32+u;
    bf16x8 wreg[8];
    #pragma unroll
    for(int kt=0;kt<8;kt++)
      wreg[kt]=*(const bf16x8*)(wf + (((long)(gt*8+kt))*64 + lane)*8);
    float c=0.f;
    float gxr[4];
    #pragma unroll
    for(int g=0;g<4;g++) gxr[g]=gx[(b*QQ+0)*1024 + g*256 + gu];
    for(int t=0;t<QQ;t++){
      f32x4 acc=(f32x4){0.f,0.f,0.f,0.f};
      if(t){
        while(__hip_atomic_load(lcnt+(t-1), __ATOMIC_RELAXED, __HIP_MEMORY_SCOPE_AGENT) < NLB)
          __builtin_amdgcn_s_sleep(2);
        __builtin_amdgcn_sched_barrier(0);
        const bf16* hb = hbuf + (t&1)*4096;
        {
          int r=tid>>5, cc=(tid&31)*8;
          unsigned long long v0=__hip_atomic_load((const unsigned long long*)(hb + r*256 + cc),
                         __ATOMIC_RELAXED, __HIP_MEMORY_SCOPE_AGENT);
          unsigned long long v1=__hip_atomic_load((const unsigned long long*)(hb + r*256 + cc + 4),
                         __ATOMIC_RELAXED, __HIP_MEMORY_SCOPE_AGENT);
          *(unsigned long long*)&hlds[r*264 + cc] = v0;
          *(unsigned long long*)&hlds[r*264 + cc + 4] = v1;
        }
        __syncthreads();
        #pragma unroll
        for(int kt=0;kt<8;kt++){
          bf16x8 af=*(const bf16x8*)&hlds[l16*264 + kt*32 + q*8];
          acc=__builtin_amdgcn_mfma_f32_16x16x32_bf16(af,wreg[kt],acc,0,0,0);
        }
      }
      #pragma unroll
      for(int r=0;r<4;r++) zs[(wv>>1)*512 + (q*4+r)*32 + (wv&1)*16 + l16]=acc[r];
      __syncthreads();
      float zi=zs[0*512+b*32+u]+gxr[0];
      float zf=zs[1*512+b*32+u]+gxr[1];
      float zg=zs[2*512+b*32+u]+gxr[2];
      float zo=zs[3*512+b*32+u]+gxr[3];
      { int tn=(t<QQ-1)?t+1:t;
        #pragma unroll
        for(int g=0;g<4;g++) gxr[g]=gx[(b*QQ+tn)*1024 + g*256 + gu];
      }
      c=sigm(zf)*c+sigm(zi)*tanhf(zg);
      float hv=sigm(zo)*tanhf(c);
      hsl[tid]=f2b(hv);
      __syncthreads();
      if(t<QQ-1){
        if(tid<128){
          bf16* hw=hbuf + ((t+1)&1)*4096;
          int bb=tid>>3, p=tid&7;
          unsigned long long v=*(unsigned long long*)&hsl[bb*32+p*4];
          __hip_atomic_store((unsigned long long*)(hw + bb*256 + k*32 + p*4), v,
                             __ATOMIC_RELAXED, __HIP_MEMORY_SCOPE_AGENT);
        }
        __syncthreads();   // vmcnt(0) drain: publish stores complete at L3
        if(tid==0)
          __hip_atomic_fetch_add(lcnt+t, 1, __ATOMIC_RELAXED, __HIP_MEMORY_SCOPE_AGENT);
      }
      __builtin_nontemporal_store(hv, &qh[(long)(b*QQ+t)*256+gu]);
      if(t==QQ-1) qnode[(b<<8)+gu]=hv;
    }
  } else if(bid<309){
    __shared__ float rr[2][2*WDIM];
    const int isf=*dfl;
    const int half=tid>>8, d=tid&255;
    const int r=(bid-8)*2+half;
    if(r<601){
      for(int k4=d*4;k4<2*WDIM;k4+=1024){
        if(isf){ float4 t4=*(const float4*)((const float*)remb+(long)r*2*WDIM+k4);
                 rr[half][k4]=t4.x;rr[half][k4+1]=t4.y;rr[half][k4+2]=t4.z;rr[half][k4+3]=t4.w; }
        else   { float v[4]; ld4bf((const bf16*)remb+(long)r*2*WDIM+k4,v);
                 rr[half][k4]=v[0];rr[half][k4+1]=v[1];rr[half][k4+2]=v[2];rr[half][k4+3]=v[3]; }
      }
    }
    __syncthreads();
    if(r<601){
      float acc=b2f(rlb[d]);
      const bf16* wr=rlw+(long)d*2*WDIM;
      for(int k4=0;k4<2*WDIM;k4+=4){
        float v[4]; ld4bf(wr+k4,v);
        acc+=v[0]*rr[half][k4]+v[1]*rr[half][k4+1]+v[2]*rr[half][k4+2]+v[3]*rr[half][k4+3];
      }
      rel_lin[r*DD+d]=acc;
    }
  } else if(bid<325){
    const int isf=*dfl;
    int i4=((bid-309)*512+tid)*4;
    if(isf){ *(float4*)(pr+i4)=*(const float4*)((const float*)adj+i4); }
    else { float v[4]; ld4bf((const bf16*)adj+i4,v);
           float4 t; t.x=v[0];t.y=v[1];t.z=v[2];t.w=v[3]; *(float4*)(pr+i4)=t; }
  } else {
    const int isf=*dfl;
    int row=(bid-325)*4+(tid>>7); int t=tid&127;
    int ent=local_entity[row];
    bf16* dst=A0+(long)row*320;
    if(t<75){
      float v[4];
      if(isf){ float4 x=*(const float4*)((const float*)emb+(long)ent*WDIM+t*4);
               v[0]=x.x;v[1]=x.y;v[2]=x.z;v[3]=x.w; }
      else ld4bf((const bf16*)emb+(long)ent*WDIM+t*4, v);
      st4bf(dst+t*4, v[0],v[1],v[2],v[3]);
    } else if(t<80){
      st4bf(dst+t*4, 0.f,0.f,0.f,0.f);
    }
  }
}

// ---------------- sim + masked softmax + Wr ----------------
__global__ __launch_bounds__(256) void k_simwr(const float* qh, const float* rel_lin,
    const int* qtext, float* Wr){
  int b = blockIdx.x, rc = blockIdx.y;
  __shared__ float qhb[QQ*DD];
  __shared__ float qm[QQ];
  for(int i=threadIdx.x;i<QQ*DD;i+=256) qhb[i]=qh[b*QQ*DD+i];
  if(threadIdx.x<QQ) qm[threadIdx.x] = (qtext[b*QQ+threadIdx.x]!=NWORD)?0.f:VERY_NEG_F;
  __syncthreads();
  int r = rc*256+threadIdx.x;
  if(r>=601) return;
  float s[QQ];
  #pragma unroll
  for(int q=0;q<QQ;q++) s[q]=0.f;
  for(int k=0;k<DD;k++){
    float rl = rel_lin[r*DD+k];
    #pragma unroll
    for(int q=0;q<QQ;q++) s[q] += qhb[q*DD+k]*rl;
  }
  float m=-1e30f;
  #pragma unroll
  for(int q=0;q<QQ;q++){ s[q]*=0.0625f; m=fmaxf(m, s[q]+qm[q]); }
  float sum=0.f, w=0.f;
  #pragma unroll
  for(int q=0;q<QQ;q++){ float p=expf(s[q]+qm[q]-m); sum+=p; w+=p*s[q]; }
  Wr[b*601+r] = w/sum;
}

// ---------------- Wmax (+e2fs zero) / W_tilde (+one-time zeros) ----------------
__global__ __launch_bounds__(256) void k_wmax(const float* Wr, const int* rel, float* wmax,
    float* e2fs){
  int b=blockIdx.x; __shared__ float red[256];
  { int g=b*256+threadIdx.x;
    float4 z={0.f,0.f,0.f,0.f};
    *(float4*)(e2fs+g*8)=z; *(float4*)(e2fs+g*8+4)=z;
  }
  float m=-1e30f;
  for(int f=threadIdx.x;f<FF;f+=256) m=fmaxf(m, Wr[b*601+rel[b*FF+f]]);
  red[threadIdx.x]=m; __syncthreads();
  for(int o=128;o;o>>=1){ if(threadIdx.x<o) red[threadIdx.x]=fmaxf(red[threadIdx.x],red[threadIdx.x+o]); __syncthreads(); }
  if(!threadIdx.x) wmax[b]=red[0];
}
__global__ __launch_bounds__(256) void k_wt(const float* Wr, const int* rel,
    const float* wmax, const int* e2f, float* wt, float* e2fs,
    float* pragg, float* wnxtb, float* prsum){
  int i = blockIdx.x*256+threadIdx.x;
  if(i<32768) pragg[i]=0.f;
  if(i<12288) wnxtb[i]=0.f;
  if(i<16)    prsum[i]=0.f;
  int b = i>>13;
  float v = expf(Wr[b*601+rel[i]] - wmax[b]);
  wt[i]=v;
  atomicAdd(e2fs + (b<<11) + e2f[i], v);
}

// ---------------- legacy no-LDS MFMA GEMM (A0 path only, K=320) ----------------
struct MG {
  const bf16* A; const bf16* W; const bf16* bias; bf16* out;
  const bf16* Aq2; const bf16* Af2;
  const int* cnt; const bf16* addb;
};
template<int CONCAT,int EPI,int TK>
__global__ __launch_bounds__(256) void k_mgemm(MG p){
  const int m0 = blockIdx.x*64;
  const int lane = threadIdx.x&63;
  const int q = lane>>4, l16 = lane&15;
  const int n0 = (threadIdx.x>>6)*64;
  f32x4 acc[4][4];
  #pragma unroll
  for(int i=0;i<4;i++)
    #pragma unroll
    for(int j=0;j<4;j++) acc[i][j]=(f32x4){0.f,0.f,0.f,0.f};
  #pragma unroll
  for(int k0=0;k0<TK;k0+=32){
    int kk=k0+q*8;
    bf16x8 af[4], bw[4];
    #pragma unroll
    for(int mi=0;mi<4;mi++)
      af[mi]=*(const bf16x8*)(p.A+(long)(m0+mi*16+l16)*TK+kk);
    #pragma unroll
    for(int ni=0;ni<4;ni++)
      bw[ni]=*(const bf16x8*)(p.W+(long)(n0+ni*16+l16)*TK+kk);
    #pragma unroll
    for(int mi=0;mi<4;mi++)
      #pragma unroll
      for(int ni=0;ni<4;ni++)
        acc[mi][ni]=__builtin_amdgcn_mfma_f32_16x16x32_bf16(af[mi],bw[ni],acc[mi][ni],0,0,0);
  }
  #pragma unroll
  for(int ni=0;ni<4;ni++){
    int col=n0+ni*16+l16;
    float bv=b2f(p.bias[col]);
    #pragma unroll
    for(int mi=0;mi<4;mi++){
      #pragma unroll
      for(int r=0;r<4;r++){
        int row=m0+mi*16+q*4+r;
        float v=acc[mi][ni][r]+bv;
        p.out[(long)row*256+col]=f2b(v);
      }
    }
  }
}

// ---------------- LDS-staged GEMM building blocks (128x256 tile, 512 thr) ----------------
// A tile: 128 rows x 256 cols bf16 = 64KB contiguous. Staged via global_load_lds w=16
// with pre-swizzled GLOBAL source + linear LDS dest (m173 pattern); reads apply the same
// involution byte^=((row&7)<<4) -> <=2-way bank conflict (free, m136).
static __device__ __forceinline__ void stage64(const char* g, char* l, int tid){
  const int wv=tid>>6, lane=tid&63;
  #pragma unroll
  for(int it=0;it<8;++it){
    int chunk=it*8192+wv*1024;
    int off=chunk+lane*16;
    int src=off^(((off>>9)&7)<<4);
    __builtin_amdgcn_global_load_lds((gas_t)(g+src),(las_t)(l+chunk),16,0,0);
  }
}
static __device__ __forceinline__ bf16x8 lds_a(const char* l, int r, int kk){
  int b=(r*512+kk*2)^((r&7)<<4);
  return *(const bf16x8*)(l+b);
}
// C[128,256] += ldsA[128,K=256] @ W[256,256]^T ; wave (wr,wc) owns 64x64 quadrant
template<int EPI>
static __device__ __forceinline__ void mg2_k256(const char* ldsA, const bf16* W,
    const bf16* bias, bf16* out, const int* cnt, const bf16* addb, int m0, int tid){
  const int lane=tid&63, q=lane>>4, l16=lane&15;
  const int wv=tid>>6, wr=wv>>2, wc=wv&3, n0=wc*64;
  f32x4 acc[4][4];
  #pragma unroll
  for(int i=0;i<4;i++)
    #pragma unroll
    for(int j=0;j<4;j++) acc[i][j]=(f32x4){0.f,0.f,0.f,0.f};
  #pragma unroll
  for(int k0=0;k0<256;k0+=32){
    int kk=k0+q*8;
    bf16x8 af[4], bw[4];
    #pragma unroll
    for(int mi=0;mi<4;mi++) af[mi]=lds_a(ldsA, wr*64+mi*16+l16, kk);
    #pragma unroll
    for(int ni=0;ni<4;ni++) bw[ni]=*(const bf16x8*)(W+(long)(n0+ni*16+l16)*256+kk);
    #pragma unroll
    for(int mi=0;mi<4;mi++)
      #pragma unroll
      for(int ni=0;ni<4;ni++)
        acc[mi][ni]=__builtin_amdgcn_mfma_f32_16x16x32_bf16(af[mi],bw[ni],acc[mi][ni],0,0,0);
  }
  #pragma unroll
  for(int ni=0;ni<4;ni++){
    int col=n0+ni*16+l16;
    float bv=b2f(bias[col]);
    #pragma unroll
    for(int mi=0;mi<4;mi++){
      #pragma unroll
      for(int r=0;r<4;r++){
        int row=m0+wr*64+mi*16+q*4+r;
        float v=acc[mi][ni][r];
        if(EPI==0) v+=bv;
        else if(EPI==1) v=fmaxf(v+bv,0.f);
        else {
          v += (float)cnt[row]*bv + b2f(addb[(long)row*256+col]);
          v=fmaxf(v,0.f);
        }
        out[(long)row*256+col]=f2b(v);
      }
    }
  }
}

// ---------------- per-layer fused dispatch #1: small + DUAL head/self GEMM + norm ----
// blocks 0..616   : small mats (256 active threads)
// blocks 617..872 : dual GEMM, A staged once, head then self (m0=(bid-617)*128)
// blocks 873..1128: norm + pagerank numerator scatter (512 thr)
struct L1 {
  const float* rel_lin; const bf16* ksw; const bf16* ksb;
  const float* qnode; const bf16* q2ew; const bf16* q2eb;
  float* relself; float* q2ev; bf16* q2evb;
  const bf16* A; const bf16* khw; const bf16* khb; bf16* headb; bf16* entself;
  const float* wt; const float* pr; const float* e2fs;
  const int* e2f; const int* f2e; float* normv; float* pragg;
};
__global__ __launch_bounds__(512) void k_lay1(L1 p){
  __shared__ char smem[65536];
  const int bid=blockIdx.x, tid=threadIdx.x;
  if(bid<617){
    float* xr=(float*)smem;
    if(tid<256){
      if(bid<601) xr[tid]=p.rel_lin[bid*DD+tid];
      else        xr[tid]=p.qnode[((bid-601)<<8)+tid];
    }
    __syncthreads();
    if(tid<256){
      int d=tid;
      if(bid<601){
        float acc=b2f(p.ksb[d]);
        const bf16* wr=p.ksw+(long)d*DD;
        for(int k4=0;k4<DD;k4+=4){
          float v[4]; ld4bf(wr+k4,v);
          acc+=v[0]*xr[k4]+v[1]*xr[k4+1]+v[2]*xr[k4+2]+v[3]*xr[k4+3];
        }
        p.relself[bid*DD+d]=acc;
      } else {
        int b=bid-601;
        float acc=b2f(p.q2eb[d]);
        const bf16* wr=p.q2ew+(long)d*DD;
        for(int k4=0;k4<DD;k4+=4){
          float v[4]; ld4bf(wr+k4,v);
          acc+=v[0]*xr[k4]+v[1]*xr[k4+1]+v[2]*xr[k4+2]+v[3]*xr[k4+3];
        }
        p.q2ev[(b<<8)+d]=acc;
        p.q2evb[(b<<8)+d]=f2b(acc);
      }
    }
  } else if(bid<873){
    int m0=(bid-617)*128;
    stage64((const char*)(p.A+(long)m0*256), smem, tid);
    __syncthreads();
    mg2_k256<0>(smem, p.khw, p.khb, p.headb, 0, 0, m0, tid);
    mg2_k256<0>(smem, p.ksw, p.ksb, p.entself, 0, 0, m0, tid);
  } else {
    int i=(bid-873)*512+tid;
    int b=i>>13;
    int e=p.e2f[i];
    float v=p.wt[i]*p.pr[(b<<11)+e]/fmaxf(p.e2fs[(b<<11)+e],1e-10f);
    p.normv[i]=v;
    atomicAdd(p.pragg+(b<<11)+p.f2e[i], v);
  }
}

// ---------------- KT GEMM (EPI=2), LDS-staged ----------------
__global__ __launch_bounds__(512) void k_ktg(MG p){
  __shared__ char smem[65536];
  int m0=blockIdx.x*128;
  stage64((const char*)(p.A+(long)m0*256), smem, threadIdx.x);
  __syncthreads();
  mg2_k256<2>(smem, p.W, p.bias, p.out, p.cnt, p.addb, m0, threadIdx.x);
}

// ---------------- segmented fact aggregation (atomic-free) ----------------
__global__ __launch_bounds__(256) void k_agg(const int* bstart, const int* bidx,
    const int* rel, const int* e2f, const float* normv, const float* relself,
    const bf16* head, bf16* agg){
  int eidx=blockIdx.x*4+(threadIdx.x>>6);
  int lane=threadIdx.x&63;
  int b=eidx>>11;
  float a0=0.f,a1=0.f,a2=0.f,a3=0.f;
  int s=bstart[eidx], e=bstart[eidx+1];
  for(int i=s;i<e;i++){
    int f=bidx[i];
    int r=rel[f]; int ent=e2f[f]; float nv=normv[f];
    float4 rs=*(const float4*)&relself[r*DD+lane*4];
    float hd[4]; ld4bf(head+(long)(((b<<11)+ent)*DD+lane*4),hd);
    a0+=fmaxf(rs.x+hd[0],0.f)*nv; a1+=fmaxf(rs.y+hd[1],0.f)*nv;
    a2+=fmaxf(rs.z+hd[2],0.f)*nv; a3+=fmaxf(rs.w+hd[3],0.f)*nv;
  }
  st4bf(agg+(long)eidx*DD+lane*4, a0,a1,a2,a3);
}

// ---------------- weighted row-sums (fused pagerank update; pragg read-zero) ----------
__global__ __launch_bounds__(256) void k_wnxt(const float* praggc, float* pragg, float* pr,
    const bf16* le, const bf16* f2e, float* wnxt, float* prsum){
  __shared__ float r1[4*256];
  __shared__ float r3[4*256];
  __shared__ float rp[4];
  const int b=blockIdx.x, ch=blockIdx.y;
  const int wv=threadIdx.x>>6, lane=threadIdx.x&63;
  const int pe0=(b<<11)+ch*64+wv*16;
  float pv=0.f;
  if(lane<16){
    int pe=pe0+lane;
    pv=0.8f*praggc[pe]+0.2f*pr[pe];
    pr[pe]=pv;
    pragg[pe]=0.f;        // self-clean for next layer's scatter
  }
  float a1[4]={0.f,0.f,0.f,0.f}, a3[4]={0.f,0.f,0.f,0.f}, ap=0.f;
  #pragma unroll
  for(int r=0;r<16;r++){
    float p=__shfl(pv, r, 64);
    long base=((long)(pe0+r))<<8;
    float v1[4],v3[4];
    ld4bf(le +base+lane*4, v1);
    ld4bf(f2e+base+lane*4, v3);
    #pragma unroll
    for(int j=0;j<4;j++){ a1[j]+=p*v1[j]; a3[j]+=p*v3[j]; }
    ap+=p;
  }
  #pragma unroll
  for(int j=0;j<4;j++){ r1[wv*256+lane*4+j]=a1[j]; r3[wv*256+lane*4+j]=a3[j]; }
  if(!lane) rp[wv]=ap;
  __syncthreads();
  const int t=threadIdx.x;
  float s1=r1[t]+r1[256+t]+r1[512+t]+r1[768+t];
  float s3=r3[t]+r3[256+t]+r3[512+t]+r3[768+t];
  atomicAdd(&wnxt[b*768+t], s1);
  atomicAdd(&wnxt[b*768+512+t], s3);
  if(!t) atomicAdd(&prsum[b], rp[0]+rp[1]+rp[2]+rp[3]);
}

// ---------------- e2e GEMM (K=768 concat, LDS-staged) + qnode fused -----------------
// blocks 0..255: GEMM (stage le + f2eemb tiles; q2evb mid-segment broadcast from global)
// blocks 256..271: qnode (wnxt/prsum read-zero)
__global__ __launch_bounds__(512) void k_e2eq(MG p, const float* q2ev,
    const bf16* qw, const bf16* qb, float* wnxtb, float* prsum, float* qnode){
  __shared__ char sA[65536];
  __shared__ char sF[65536];
  const int tid=threadIdx.x;
  if(blockIdx.x<256){
    int m0=blockIdx.x*128;
    stage64((const char*)(p.A  +(long)m0*256), sA, tid);
    stage64((const char*)(p.Af2+(long)m0*256), sF, tid);
    __syncthreads();
    const int lane=tid&63, q=lane>>4, l16=lane&15;
    const int wv=tid>>6, wr=wv>>2, wc=wv&3, n0=wc*64;
    const bf16* aq2 = p.Aq2 + ((m0>>11)<<8);
    f32x4 acc[4][4];
    #pragma unroll
    for(int i=0;i<4;i++)
      #pragma unroll
      for(int j=0;j<4;j++) acc[i][j]=(f32x4){0.f,0.f,0.f,0.f};
    // segment 1: le (K 0..255)
    #pragma unroll
    for(int k0=0;k0<256;k0+=32){
      int kk=k0+q*8;
      bf16x8 af[4], bw[4];
      #pragma unroll
      for(int mi=0;mi<4;mi++) af[mi]=lds_a(sA, wr*64+mi*16+l16, kk);
      #pragma unroll
      for(int ni=0;ni<4;ni++) bw[ni]=*(const bf16x8*)(p.W+(long)(n0+ni*16+l16)*768+kk);
      #pragma unroll
      for(int mi=0;mi<4;mi++)
        #pragma unroll
        for(int ni=0;ni<4;ni++)
          acc[mi][ni]=__builtin_amdgcn_mfma_f32_16x16x32_bf16(af[mi],bw[ni],acc[mi][ni],0,0,0);
    }
    // segment 2: q2evb broadcast (K 256..511) — row-independent A fragment
    #pragma unroll
    for(int k0=256;k0<512;k0+=32){
      int kk=k0+q*8;
      bf16x8 aq=*(const bf16x8*)(aq2+(kk-256));
      bf16x8 bw[4];
      #pragma unroll
      for(int ni=0;ni<4;ni++) bw[ni]=*(const bf16x8*)(p.W+(long)(n0+ni*16+l16)*768+kk);
      #pragma unroll
      for(int mi=0;mi<4;mi++)
        #pragma unroll
        for(int ni=0;ni<4;ni++)
          acc[mi][ni]=__builtin_amdgcn_mfma_f32_16x16x32_bf16(aq,bw[ni],acc[mi][ni],0,0,0);
    }
    // segment 3: f2eemb (K 512..767)
    #pragma unroll
    for(int k0=512;k0<768;k0+=32){
      int kk=k0+q*8;
      bf16x8 af[4], bw[4];
      #pragma unroll
      for(int mi=0;mi<4;mi++) af[mi]=lds_a(sF, wr*64+mi*16+l16, kk-512);
      #pragma unroll
      for(int ni=0;ni<4;ni++) bw[ni]=*(const bf16x8*)(p.W+(long)(n0+ni*16+l16)*768+kk);
      #pragma unroll
      for(int mi=0;mi<4;mi++)
        #pragma unroll
        for(int ni=0;ni<4;ni++)
          acc[mi][ni]=__builtin_amdgcn_mfma_f32_16x16x32_bf16(af[mi],bw[ni],acc[mi][ni],0,0,0);
    }
    #pragma unroll
    for(int ni=0;ni<4;ni++){
      int col=n0+ni*16+l16;
      float bv=b2f(p.bias[col]);
      #pragma unroll
      for(int mi=0;mi<4;mi++){
        #pragma unroll
        for(int r=0;r<4;r++){
          int row=m0+wr*64+mi*16+q*4+r;
          p.out[(long)row*256+col]=f2b(fmaxf(acc[mi][ni][r]+bv,0.f));
        }
      }
    }
  } else {
    int b=blockIdx.x-256;
    float* xr=(float*)sA;
    float ps=prsum[b];
    if(tid<256){
      int d=tid;
      xr[d]=wnxtb[b*768+d];            wnxtb[b*768+d]=0.f;
      xr[256+d]=ps*q2ev[(b<<8)+d];
      xr[512+d]=wnxtb[b*768+512+d];    wnxtb[b*768+512+d]=0.f;
    }
    __syncthreads();
    if(tid<256){
      int d=tid;
      if(d==0) prsum[b]=0.f;
      float acc=0.f;
      const bf16* wr=qw+(long)d*768;
      for(int k4=0;k4<768;k4+=4){
        float v[4]; ld4bf(wr+k4,v);
        acc+=v[0]*xr[k4]+v[1]*xr[k4+1]+v[2]*xr[k4+2]+v[3]*xr[k4+3];
      }
      qnode[(b<<8)+d]=acc+ps*b2f(qb[d]);
    }
  }
}

// ---------------- score ----------------
__global__ __launch_bounds__(256) void k_score(const bf16* le, const bf16* sw,
    const bf16* sb, void* out, const int* dfl){
  const int isf=*dfl;
  int o=blockIdx.x*4 + (threadIdx.x>>6);
  int lane=threadIdx.x&63;
  float v[4],wv[4];
  ld4bf(le+(long)o*DD+lane*4,v); ld4bf(sw+lane*4,wv);
  float acc=v[0]*wv[0]+v[1]*wv[1]+v[2]*wv[2]+v[3]*wv[3];
  for(int off=32;off;off>>=1) acc+=__shfl_down(acc,off,64);
  if(!lane){
    float r=acc+b2f(sb[0]);
    if(isf) ((float*)out)[o]=r; else ((bf16*)out)[o]=f2b(r);
  }
}

// ---------------- host ----------------
extern "C" void kernel_launch(void* const* d_in, const int* in_sizes, int n_in,
                              void* d_out, int out_size, void* d_ws, size_t ws_size,
                              hipStream_t stream){
  const int*  local_entity=(const int*)d_in[0];
  const void* q2e_adj     =d_in[1];
  const int*  kb_fact_rel =(const int*)d_in[2];
  const int*  query_text  =(const int*)d_in[3];
  const int*  e2f_ent     =(const int*)d_in[5];
  const int*  f2e_ent     =(const int*)d_in[6];
  const void* word_emb    =d_in[7];
  const void* entity_emb  =d_in[8];
  const void* relation_emb=d_in[9];

  char* ws=(char*)d_ws;
  float* gx      =(float*)(ws+O_GX);
  float* qh      =(float*)(ws+O_QH);
  float* qnode   =(float*)(ws+O_QNODE);
  float* rel_lin =(float*)(ws+O_RELLIN);
  float* Wr      =(float*)(ws+O_WR);
  float* wmax    =(float*)(ws+O_WMAX);
  float* wt      =(float*)(ws+O_WT);
  float* e2fs    =(float*)(ws+O_E2FS);
  float* pr      =(float*)(ws+O_PR);
  float* pragg   =(float*)(ws+O_PRAGG);
  float* q2ev    =(float*)(ws+O_Q2EV);
  bf16*  q2evb   =(bf16*)(ws+O_Q2EVB);
  float* relself =(float*)(ws+O_RELSELF);
  float* normv   =(float*)(ws+O_NORM);
  float* wnxt    =(float*)(ws+O_WNXT);
  float* prsum   =(float*)(ws+O_PRSUM);
  int*   cnt     =(int*)(ws+O_CNT);
  int*   cur     =(int*)(ws+O_CUR);
  int*   bstart  =(int*)(ws+O_BSTART);
  int*   bidx    =(int*)(ws+O_BIDX);
  bf16*  elwpad  =(bf16*)(ws+O_ELWPAD);
  int*   dflag   =(int*)(ws+O_FLAG);
  bf16*  cw      =(bf16*)(ws+O_CVT);
  bf16*  agg     =(bf16*)(ws+O_AGG);
  bf16*  A0      =(bf16*)(ws+O_AGG);      // aliases agg (pre-layer use only)
  bf16*  entself =(bf16*)(ws+O_ENTSELF);
  bf16*  leA     =(bf16*)(ws+O_LEA);
  bf16*  leB     =(bf16*)(ws+O_LEB);
  bf16*  headb   =(bf16*)(ws+O_HEAD);
  bf16*  f2eemb  =(bf16*)(ws+O_F2EEMB);
  bf16*  hbuf    =(bf16*)(ws+O_LEA);              // 2 slots x 16x256 bf16 = 16KB
  int*   lcnt    =(int*)(ws+O_LEA+16384);         // 20 step flags

  k_sniff<<<1,256,0,stream>>>((const unsigned short*)entity_emb, dflag);

  CvtJobs J;
  int cntj=0;
  auto add=[&](int in_idx, long coff, int n, int sc){
    J.src[cntj]=d_in[in_idx]; J.dst[cntj]=cw+coff; J.n[cntj]=n; J.sc[cntj]=sc; cntj++;
  };
  add(11,C_ELB,256,0);
  add(12,C_RLW,153600,0);  add(13,C_RLB,256,0);
  add(14,C_WIH,307200,0);
  add(16,C_BIH,1024,0);    add(17,C_BHH,1024,0);
  add(18,C_Q2EW,196608,0); add(19,C_Q2EB,768,0);
  add(20,C_E2QW,589824,1); add(21,C_E2QB,768,0);
  add(22,C_E2EW,589824,1); add(23,C_E2EB,768,0);
  add(24,C_KHW,196608,0);  add(25,C_KHB,768,0);
  add(26,C_KTW,196608,0);  add(27,C_KTB,768,0);
  add(28,C_KSW,196608,0);  add(29,C_KSB,768,0);
  add(30,C_SCW,256,0);     add(31,C_SCB,1,0);
  k_cvt<<<dim3(576,20),256,0,stream>>>(J, dflag);
  k_cvtwhh<<<128,256,0,stream>>>(d_in[15], cw+C_WHH, dflag);
  k_cvtelw<<<256,256,0,stream>>>(d_in[10], elwpad, dflag);

  // CSR bucketing (fact graph is launch-constant); cnt+cur adjacent -> one memset
  hipMemsetAsync(cnt, 0, (size_t)2*BB*EE*4, stream);
  k_cnt <<<BB*FF/256,256,0,stream>>>(f2e_ent, cnt);
  k_scan<<<1,1024,0,stream>>>(cnt, bstart);
  k_fill<<<BB*FF/256,256,0,stream>>>(f2e_ent, bstart, cur, bidx);

  k_gx   <<<BB*QQ,256,0,stream>>>(query_text, word_emb, cw+C_WIH, cw+C_BIH, cw+C_BHH, gx, dflag, lcnt);
  // mega: lstm (8) + rel_lin (301) + prinit (16) + ga0 (8192)
  k_mega<<<8517,512,0,stream>>>(gx, cw+C_WHH, qh, qnode, hbuf, lcnt,
      relation_emb, cw+C_RLW, cw+C_RLB, rel_lin,
      local_entity, entity_emb, A0,
      q2e_adj, pr, dflag);
  k_simwr<<<dim3(BB,3),256,0,stream>>>(qh, rel_lin, query_text, Wr);
  k_wmax <<<BB,256,0,stream>>>(Wr, kb_fact_rel, wmax, e2fs);
  k_wt   <<<BB*FF/256,256,0,stream>>>(Wr, kb_fact_rel, wmax, e2f_ent, wt, e2fs,
                                      pragg, wnxt, prsum);

  // le = entity_emb[local_entity] @ elw^T + elb   (K padded to 320; legacy path)
  {
    MG p{}; p.A=A0; p.W=elwpad; p.bias=cw+C_ELB; p.out=leA;
    k_mgemm<0,0,320><<<BB*EE/64,256,0,stream>>>(p);
  }

  bf16* le_cur=leA; bf16* le_nxt=leB;
  for(int i=0;i<3;i++){
    { // fused: small mats + dual head/self LDS-GEMM + norm scatter
      L1 p{};
      p.rel_lin=rel_lin; p.ksw=cw+C_KSW+(long)i*65536; p.ksb=cw+C_KSB+(long)i*256;
      p.qnode=qnode; p.q2ew=cw+C_Q2EW+(long)i*65536; p.q2eb=cw+C_Q2EB+(long)i*256;
      p.relself=relself; p.q2ev=q2ev; p.q2evb=q2evb;
      p.A=le_cur; p.khw=cw+C_KHW+(long)i*65536; p.khb=cw+C_KHB+(long)i*256;
      p.headb=headb; p.entself=entself;
      p.wt=wt; p.pr=pr; p.e2fs=e2fs;
      p.e2f=e2f_ent; p.f2e=f2e_ent; p.normv=normv; p.pragg=pragg;
      k_lay1<<<1129,512,0,stream>>>(p);
    }
    k_agg <<<BB*EE/4,256,0,stream>>>(bstart, bidx, kb_fact_rel, e2f_ent, normv, relself, headb, agg);
    {
      MG p{}; p.A=agg; p.W=cw+C_KTW+(long)i*65536; p.bias=cw+C_KTB+(long)i*256;
      p.out=f2eemb; p.cnt=cnt; p.addb=entself;
      k_ktg<<<256,512,0,stream>>>(p);
    }
    k_wnxt <<<dim3(BB,32),256,0,stream>>>(pragg, pragg, pr, le_cur, f2eemb, wnxt, prsum);
    { // fused: e2e LDS-GEMM (concat) + qnode
      MG p{}; p.A=le_cur; p.W=cw+C_E2EW+(long)i*196608; p.bias=cw+C_E2EB+(long)i*256;
      p.out=le_nxt; p.Aq2=q2evb; p.Af2=f2eemb;
      k_e2eq<<<272,512,0,stream>>>(p, q2ev,
          cw+C_E2QW+(long)i*196608, cw+C_E2QB+(long)i*256, wnxt, prsum, qnode);
    }
    bf16* t=le_cur; le_cur=le_nxt; le_nxt=t;
  }

  k_score<<<BB*EE/4,256,0,stream>>>(le_cur, cw+C_SCW, cw+C_SCB, d_out, dflag);
}

// Round 12
// 949.055 us; speedup vs baseline: 1.4763x; 1.0076x over previous
//
#include <hip/hip_runtime.h>
#include <hip/hip_bf16.h>

typedef __hip_bfloat16 bf16;
typedef __attribute__((ext_vector_type(8))) short bf16x8;
typedef __attribute__((ext_vector_type(4))) float f32x4;
typedef __attribute__((address_space(1))) const void* gas_t;
typedef __attribute__((address_space(3))) void* las_t;

#define BB 16
#define EE 2048
#define FF 8192
#define QQ 20
#define DD 256
#define WDIM 300
#define NWORD 50000
#define VERY_NEG_F (-1.0e11f)

static __device__ __forceinline__ float b2f(bf16 x){ return __bfloat162float(x); }
static __device__ __forceinline__ bf16 f2b(float x){ return __float2bfloat16(x); }
static __device__ __forceinline__ float sigm(float x){ return 1.f/(1.f+expf(-x)); }
static __device__ __forceinline__ void ld4bf(const bf16* p, float v[4]){
  short4 s = *(const short4*)p;
  v[0]=b2f(*(const bf16*)&s.x); v[1]=b2f(*(const bf16*)&s.y);
  v[2]=b2f(*(const bf16*)&s.z); v[3]=b2f(*(const bf16*)&s.w);
}
static __device__ __forceinline__ void st4bf(bf16* p, float a,float b,float c,float d){
  unsigned short u[4]; bf16 t;
  t=f2b(a);u[0]=*(unsigned short*)&t; t=f2b(b);u[1]=*(unsigned short*)&t;
  t=f2b(c);u[2]=*(unsigned short*)&t; t=f2b(d);u[3]=*(unsigned short*)&t;
  *(short4*)p=*(short4*)u;
}

// ---------------- workspace offsets (bytes) ----------------
#define O_GX       0UL
#define O_QH       1310720UL
#define O_QNODE    1638400UL
#define O_RELLIN   1654784UL
#define O_WR       2270208UL
#define O_WMAX     2308864UL
#define O_WT       2309120UL
#define O_E2FS     2833408UL
#define O_PR       2964480UL
#define O_PRAGG    3095552UL
#define O_Q2EV     3226624UL
#define O_Q2EVB    3243008UL
#define O_RELSELF  3251200UL
#define O_NORM     3866624UL
#define O_WNXT     4390912UL
#define O_PRSUM    4440064UL
#define O_CNT      4440320UL
#define O_CUR      4571392UL
#define O_BSTART   4702464UL
#define O_BIDX     4834048UL
#define O_ELWPAD   5358336UL
#define O_FLAG     5522176UL
#define O_CVT      5522432UL   // 5393152 B
#define O_AGG      10915584UL  // bf16 16.7MB; A0 (21MB) aliases AGG+start of ENTSELF
#define O_ENTSELF  27692800UL
#define O_LEA      44470016UL
#define O_LEB      61247232UL
#define O_HEAD     78024448UL
#define O_F2EEMB   94801664UL  // end ~111.6MB

// canonical element offsets within O_CVT (all mult of 8)
#define C_ELB   0
#define C_RLW   256
#define C_RLB   153856
#define C_WIH   154112
#define C_WHH   461312   // frag-linear w_hh (262144 elems)
#define C_BIH   723456
#define C_BHH   724480
#define C_Q2EW  725504
#define C_Q2EB  922112
#define C_E2QW  922880
#define C_E2QB  1512704
#define C_E2EW  1513472
#define C_E2EB  2103296
#define C_KHW   2104064
#define C_KHB   2300672
#define C_KTW   2301440
#define C_KTB   2498048
#define C_KSW   2498816
#define C_KSB   2695424
#define C_SCW   2696192
#define C_SCB   2696448

// ---------------- dtype sniffer ----------------
__global__ __launch_bounds__(256) void k_sniff(const unsigned short* ee, int* flag){
  __shared__ int red[256];
  int c=0;
  for(int i=threadIdx.x;i<4096;i+=256){
    int ex=(ee[2*i]>>7)&0xFF;
    c += (ex>=192);
  }
  red[threadIdx.x]=c; __syncthreads();
  for(int o=128;o;o>>=1){ if(threadIdx.x<o) red[threadIdx.x]+=red[threadIdx.x+o]; __syncthreads(); }
  if(!threadIdx.x) flag[0] = (red[0]>64) ? 1 : 0;
}

// ---------------- batched weight canonicalization -> bf16 ----------------
struct CvtJobs{ const void* src[20]; bf16* dst[20]; int n[20]; int sc[20]; };
__global__ __launch_bounds__(256) void k_cvt(CvtJobs J, const int* dfl){
  const int isf=*dfl;
  int j=blockIdx.y;
  int n=J.n[j];
  int i4=(blockIdx.x*256+threadIdx.x)*4;
  if(i4>=n) return;
  float m = (J.sc[j] && ((i4%768)>=512)) ? 3.f : 1.f;
  bf16* d=J.dst[j]+i4;
  if(isf){
    const float* s=(const float*)J.src[j]+i4;
    if(i4+4<=n){ float4 t=*(const float4*)s; st4bf(d,t.x*m,t.y*m,t.z*m,t.w*m); }
    else for(int r=0;i4+r<n;r++) d[r]=f2b(s[r]*m);
  } else {
    const bf16* s=(const bf16*)J.src[j]+i4;
    if(i4+4<=n){ float v[4]; ld4bf(s,v); st4bf(d,v[0]*m,v[1]*m,v[2]*m,v[3]*m); }
    else for(int r=0;i4+r<n;r++) d[r]=f2b(b2f(s[r])*m);
  }
}

// w_hh (1024x256) -> MFMA-fragment-linear  (+ zero cnt/cur: 262144 B = 16384 int4)
__global__ __launch_bounds__(256) void k_cvtwhh(const void* src, bf16* wf, const int* dfl,
    int* cntz){
  const int isf=*dfl;
  int fid=blockIdx.x*256+threadIdx.x;        // 0..32767
  if(fid<16384){ int4 z={0,0,0,0}; ((int4*)cntz)[fid]=z; }
  int lane=fid&63, kt=(fid>>6)&7, gt=fid>>9;
  int l16=lane&15, q=lane>>4;
  long so=(long)(gt*16+l16)*256 + kt*32 + q*8;
  float v[8];
  if(isf){ const float* s=(const float*)src+so;
    #pragma unroll
    for(int j=0;j<8;j++) v[j]=s[j];
  } else { const bf16* s=(const bf16*)src+so; ld4bf(s,v); ld4bf(s+4,v+4); }
  bf16* d=wf+(long)fid*8;
  st4bf(d,v[0],v[1],v[2],v[3]); st4bf(d+4,v[4],v[5],v[6],v[7]);
}

// entity_lin_w (256x300) -> padded bf16 (256x320)
__global__ __launch_bounds__(256) void k_cvtelw(const void* src, bf16* dst, const int* dfl){
  const int isf=*dfl;
  int r=blockIdx.x;
  for(int c=threadIdx.x;c<320;c+=256){
    float v=0.f;
    if(c<300) v = isf ? ((const float*)src)[r*300+c] : b2f(((const bf16*)src)[r*300+c]);
    dst[(long)r*320+c]=f2b(v);
  }
}

// ---------------- CSR scan (1 block; cnt produced by k_gx, fill done in k_mega) -----
__global__ __launch_bounds__(1024) void k_scan(const int* cnt, int* bstart){
  __shared__ int ps[1024];
  int t=threadIdx.x;
  int loc[32]; int s=0;
  #pragma unroll
  for(int j=0;j<32;j++){ loc[j]=s; s+=cnt[t*32+j]; }
  ps[t]=s; __syncthreads();
  for(int off=1;off<1024;off<<=1){
    int v=(t>=off)?ps[t-off]:0;
    __syncthreads(); ps[t]+=v; __syncthreads();
  }
  int base=(t? ps[t-1]:0);
  #pragma unroll
  for(int j=0;j<32;j++) bstart[t*32+j]=base+loc[j];
  if(t==1023) bstart[32768]=ps[1023];
}

// ---------------- gx (blocks 0..319) + CSR count (blocks 320..831) + lcnt zero ------
__global__ __launch_bounds__(256) void k_gx(const int* qtext, const void* wemb,
    const bf16* wih, const bf16* bih, const bf16* bhh, float* gx, const int* dfl,
    int* lcnt, const int* f2e, int* cnt){
  if(blockIdx.x>=320){
    int i=(blockIdx.x-320)*256+threadIdx.x;
    atomicAdd(&cnt[((i>>13)<<11)+f2e[i]], 1);
    return;
  }
  if(blockIdx.x==0 && threadIdx.x<32) lcnt[threadIdx.x]=0;
  const int isf=*dfl;
  int bt=blockIdx.x;
  __shared__ float xr[WDIM];
  int w=qtext[bt];
  for(int k4=threadIdx.x*4;k4<WDIM;k4+=1024){
    if(isf){ float4 t=*(const float4*)((const float*)wemb+(long)w*WDIM+k4);
             xr[k4]=t.x;xr[k4+1]=t.y;xr[k4+2]=t.z;xr[k4+3]=t.w; }
    else   { float v[4]; ld4bf((const bf16*)wemb+(long)w*WDIM+k4,v);
             xr[k4]=v[0];xr[k4+1]=v[1];xr[k4+2]=v[2];xr[k4+3]=v[3]; }
  }
  __syncthreads();
  #pragma unroll
  for(int s=0;s<4;s++){
    int g=threadIdx.x+256*s;
    float acc=b2f(bih[g])+b2f(bhh[g]);
    const bf16* wr=wih+(long)g*WDIM;
    for(int k4=0;k4<WDIM;k4+=4){
      float v[4]; ld4bf(wr+k4,v);
      acc+=v[0]*xr[k4]+v[1]*xr[k4+1]+v[2]*xr[k4+2]+v[3]*xr[k4+3];
    }
    gx[bt*1024+g]=acc;
  }
}

// ---------------- MEGA: LSTM (0..7) + rel_lin (8..308) + prinit (309..324) +
//                  ga0 (325..8516) + CSR fill (8517..8772) --------------------------
#define NLB 8
__global__ __launch_bounds__(512) void k_mega(const float* gx, const bf16* wf,
    float* qh, float* qnode, bf16* hbuf, int* lcnt,
    const void* remb, const bf16* rlw, const bf16* rlb, float* rel_lin,
    const int* local_entity, const void* emb, bf16* A0,
    const void* adj, float* pr, const int* dfl,
    const int* f2e, const int* bstart, int* cur, int* bidx){
  const int bid=blockIdx.x, tid=threadIdx.x;
  if(bid<NLB){
    __shared__ bf16  hlds[16*264];
    __shared__ float zs[4*16*32];
    __shared__ bf16  hsl[512];
    const int k=bid;
    const int wv=tid>>6, lane=tid&63, q=lane>>4, l16=lane&15;
    const int gt=(wv>>1)*16 + k*2 + (wv&1);
    const int b=tid>>5, u=tid&31, gu=k*32+u;
    bf16x8 wreg[8];
    #pragma unroll
    for(int kt=0;kt<8;kt++)
      wreg[kt]=*(const bf16x8*)(wf + (((long)(gt*8+kt))*64 + lane)*8);
    float c=0.f;
    float gxr[4];
    #pragma unroll
    for(int g=0;g<4;g++) gxr[g]=gx[(b*QQ+0)*1024 + g*256 + gu];
    for(int t=0;t<QQ;t++){
      f32x4 acc=(f32x4){0.f,0.f,0.f,0.f};
      if(t){
        while(__hip_atomic_load(lcnt+(t-1), __ATOMIC_RELAXED, __HIP_MEMORY_SCOPE_AGENT) < NLB)
          __builtin_amdgcn_s_sleep(2);
        __builtin_amdgcn_sched_barrier(0);
        const bf16* hb = hbuf + (t&1)*4096;
        {
          int r=tid>>5, cc=(tid&31)*8;
          unsigned long long v0=__hip_atomic_load((const unsigned long long*)(hb + r*256 + cc),
                         __ATOMIC_RELAXED, __HIP_MEMORY_SCOPE_AGENT);
          unsigned long long v1=__hip_atomic_load((const unsigned long long*)(hb + r*256 + cc + 4),
                         __ATOMIC_RELAXED, __HIP_MEMORY_SCOPE_AGENT);
          *(unsigned long long*)&hlds[r*264 + cc] = v0;
          *(unsigned long long*)&hlds[r*264 + cc + 4] = v1;
        }
        __syncthreads();
        #pragma unroll
        for(int kt=0;kt<8;kt++){
          bf16x8 af=*(const bf16x8*)&hlds[l16*264 + kt*32 + q*8];
          acc=__builtin_amdgcn_mfma_f32_16x16x32_bf16(af,wreg[kt],acc,0,0,0);
        }
      }
      #pragma unroll
      for(int r=0;r<4;r++) zs[(wv>>1)*512 + (q*4+r)*32 + (wv&1)*16 + l16]=acc[r];
      __syncthreads();
      float zi=zs[0*512+b*32+u]+gxr[0];
      float zf=zs[1*512+b*32+u]+gxr[1];
      float zg=zs[2*512+b*32+u]+gxr[2];
      float zo=zs[3*512+b*32+u]+gxr[3];
      { int tn=(t<QQ-1)?t+1:t;
        #pragma unroll
        for(int g=0;g<4;g++) gxr[g]=gx[(b*QQ+tn)*1024 + g*256 + gu];
      }
      c=sigm(zf)*c+sigm(zi)*tanhf(zg);
      float hv=sigm(zo)*tanhf(c);
      hsl[tid]=f2b(hv);
      __syncthreads();
      if(t<QQ-1){
        if(tid<128){
          bf16* hw=hbuf + ((t+1)&1)*4096;
          int bb=tid>>3, p=tid&7;
          unsigned long long v=*(unsigned long long*)&hsl[bb*32+p*4];
          __hip_atomic_store((unsigned long long*)(hw + bb*256 + k*32 + p*4), v,
                             __ATOMIC_RELAXED, __HIP_MEMORY_SCOPE_AGENT);
        }
        __syncthreads();   // vmcnt(0) drain: publish stores complete at L3
        if(tid==0)
          __hip_atomic_fetch_add(lcnt+t, 1, __ATOMIC_RELAXED, __HIP_MEMORY_SCOPE_AGENT);
      }
      __builtin_nontemporal_store(hv, &qh[(long)(b*QQ+t)*256+gu]);
      if(t==QQ-1) qnode[(b<<8)+gu]=hv;
    }
  } else if(bid<309){
    __shared__ float rr[2][2*WDIM];
    const int isf=*dfl;
    const int half=tid>>8, d=tid&255;
    const int r=(bid-8)*2+half;
    if(r<601){
      for(int k4=d*4;k4<2*WDIM;k4+=1024){
        if(isf){ float4 t4=*(const float4*)((const float*)remb+(long)r*2*WDIM+k4);
                 rr[half][k4]=t4.x;rr[half][k4+1]=t4.y;rr[half][k4+2]=t4.z;rr[half][k4+3]=t4.w; }
        else   { float v[4]; ld4bf((const bf16*)remb+(long)r*2*WDIM+k4,v);
                 rr[half][k4]=v[0];rr[half][k4+1]=v[1];rr[half][k4+2]=v[2];rr[half][k4+3]=v[3]; }
      }
    }
    __syncthreads();
    if(r<601){
      float acc=b2f(rlb[d]);
      const bf16* wr=rlw+(long)d*2*WDIM;
      for(int k4=0;k4<2*WDIM;k4+=4){
        float v[4]; ld4bf(wr+k4,v);
        acc+=v[0]*rr[half][k4]+v[1]*rr[half][k4+1]+v[2]*rr[half][k4+2]+v[3]*rr[half][k4+3];
      }
      rel_lin[r*DD+d]=acc;
    }
  } else if(bid<325){
    const int isf=*dfl;
    int i4=((bid-309)*512+tid)*4;
    if(isf){ *(float4*)(pr+i4)=*(const float4*)((const float*)adj+i4); }
    else { float v[4]; ld4bf((const bf16*)adj+i4,v);
           float4 t; t.x=v[0];t.y=v[1];t.z=v[2];t.w=v[3]; *(float4*)(pr+i4)=t; }
  } else if(bid<8517){
    const int isf=*dfl;
    int row=(bid-325)*4+(tid>>7); int t=tid&127;
    int ent=local_entity[row];
    bf16* dst=A0+(long)row*320;
    if(t<75){
      float v[4];
      if(isf){ float4 x=*(const float4*)((const float*)emb+(long)ent*WDIM+t*4);
               v[0]=x.x;v[1]=x.y;v[2]=x.z;v[3]=x.w; }
      else ld4bf((const bf16*)emb+(long)ent*WDIM+t*4, v);
      st4bf(dst+t*4, v[0],v[1],v[2],v[3]);
    } else if(t<80){
      st4bf(dst+t*4, 0.f,0.f,0.f,0.f);
    }
  } else {
    // ---- CSR fill (bstart from k_scan, prior dispatch; cur zeroed in k_cvtwhh) ----
    int i=(bid-8517)*512+tid;
    int key=((i>>13)<<11)+f2e[i];
    int pos=bstart[key]+atomicAdd(&cur[key],1);
    bidx[pos]=i;
  }
}

// ---------------- sim + masked softmax + Wr ----------------
__global__ __launch_bounds__(256) void k_simwr(const float* qh, const float* rel_lin,
    const int* qtext, float* Wr){
  int b = blockIdx.x, rc = blockIdx.y;
  __shared__ float qhb[QQ*DD];
  __shared__ float qm[QQ];
  for(int i=threadIdx.x;i<QQ*DD;i+=256) qhb[i]=qh[b*QQ*DD+i];
  if(threadIdx.x<QQ) qm[threadIdx.x] = (qtext[b*QQ+threadIdx.x]!=NWORD)?0.f:VERY_NEG_F;
  __syncthreads();
  int r = rc*256+threadIdx.x;
  if(r>=601) return;
  float s[QQ];
  #pragma unroll
  for(int q=0;q<QQ;q++) s[q]=0.f;
  for(int k=0;k<DD;k++){
    float rl = rel_lin[r*DD+k];
    #pragma unroll
    for(int q=0;q<QQ;q++) s[q] += qhb[q*DD+k]*rl;
  }
  float m=-1e30f;
  #pragma unroll
  for(int q=0;q<QQ;q++){ s[q]*=0.0625f; m=fmaxf(m, s[q]+qm[q]); }
  float sum=0.f, w=0.f;
  #pragma unroll
  for(int q=0;q<QQ;q++){ float p=expf(s[q]+qm[q]-m); sum+=p; w+=p*s[q]; }
  Wr[b*601+r] = w/sum;
}

// ---------------- Wmax (+e2fs zero) / W_tilde (+one-time zeros) ----------------
__global__ __launch_bounds__(256) void k_wmax(const float* Wr, const int* rel, float* wmax,
    float* e2fs){
  int b=blockIdx.x; __shared__ float red[256];
  { int g=b*256+threadIdx.x;
    float4 z={0.f,0.f,0.f,0.f};
    *(float4*)(e2fs+g*8)=z; *(float4*)(e2fs+g*8+4)=z;
  }
  float m=-1e30f;
  for(int f=threadIdx.x;f<FF;f+=256) m=fmaxf(m, Wr[b*601+rel[b*FF+f]]);
  red[threadIdx.x]=m; __syncthreads();
  for(int o=128;o;o>>=1){ if(threadIdx.x<o) red[threadIdx.x]=fmaxf(red[threadIdx.x],red[threadIdx.x+o]); __syncthreads(); }
  if(!threadIdx.x) wmax[b]=red[0];
}
__global__ __launch_bounds__(256) void k_wt(const float* Wr, const int* rel,
    const float* wmax, const int* e2f, float* wt, float* e2fs,
    float* pragg, float* wnxtb, float* prsum){
  int i = blockIdx.x*256+threadIdx.x;
  if(i<32768) pragg[i]=0.f;
  if(i<12288) wnxtb[i]=0.f;
  if(i<16)    prsum[i]=0.f;
  int b = i>>13;
  float v = expf(Wr[b*601+rel[i]] - wmax[b]);
  wt[i]=v;
  atomicAdd(e2fs + (b<<11) + e2f[i], v);
}

// ---------------- LDS-staged GEMM building blocks ----------------
// 256-col tiles: row stride 512B; swizzle involution byte^=((row&7)<<4).
static __device__ __forceinline__ void stage64(const char* g, char* l, int tid){
  const int wv=tid>>6, lane=tid&63;
  #pragma unroll
  for(int it=0;it<8;++it){
    int chunk=it*8192+wv*1024;
    int off=chunk+lane*16;
    int src=off^(((off>>9)&7)<<4);
    __builtin_amdgcn_global_load_lds((gas_t)(g+src),(las_t)(l+chunk),16,0,0);
  }
}
static __device__ __forceinline__ bf16x8 lds_a(const char* l, int r, int kk){
  int b=(r*512+kk*2)^((r&7)<<4);
  return *(const bf16x8*)(l+b);
}
// 320-col tiles (A0 path): row stride 640B. 640=5*128 -> bits 4..6 of the byte
// address are intra-row only, so the same XOR is a row-local involution.
static __device__ __forceinline__ void stage80(const char* g, char* l, int tid){
  const int wv=tid>>6, lane=tid&63;
  #pragma unroll
  for(int it=0;it<10;++it){
    int chunk=it*8192+wv*1024;
    int off=chunk+lane*16;
    int row=off/640;
    int src=off^((row&7)<<4);
    __builtin_amdgcn_global_load_lds((gas_t)(g+src),(las_t)(l+chunk),16,0,0);
  }
}
static __device__ __forceinline__ bf16x8 lds_a320(const char* l, int r, int kk){
  int b=(r*640+kk*2)^((r&7)<<4);
  return *(const bf16x8*)(l+b);
}

// C[128,256] += ldsA[128,256] @ W[256,256]^T ; wave (wr,wc) owns 64x64 quadrant
template<int EPI>
static __device__ __forceinline__ void mg2_k256(const char* ldsA, const bf16* W,
    const bf16* bias, bf16* out, const int* cnt, const bf16* addb, int m0, int tid){
  const int lane=tid&63, q=lane>>4, l16=lane&15;
  const int wv=tid>>6, wr=wv>>2, wc=wv&3, n0=wc*64;
  f32x4 acc[4][4];
  #pragma unroll
  for(int i=0;i<4;i++)
    #pragma unroll
    for(int j=0;j<4;j++) acc[i][j]=(f32x4){0.f,0.f,0.f,0.f};
  #pragma unroll
  for(int k0=0;k0<256;k0+=32){
    int kk=k0+q*8;
    bf16x8 af[4], bw[4];
    #pragma unroll
    for(int mi=0;mi<4;mi++) af[mi]=lds_a(ldsA, wr*64+mi*16+l16, kk);
    #pragma unroll
    for(int ni=0;ni<4;ni++) bw[ni]=*(const bf16x8*)(W+(long)(n0+ni*16+l16)*256+kk);
    #pragma unroll
    for(int mi=0;mi<4;mi++)
      #pragma unroll
      for(int ni=0;ni<4;ni++)
        acc[mi][ni]=__builtin_amdgcn_mfma_f32_16x16x32_bf16(af[mi],bw[ni],acc[mi][ni],0,0,0);
  }
  #pragma unroll
  for(int ni=0;ni<4;ni++){
    int col=n0+ni*16+l16;
    float bv=b2f(bias[col]);
    #pragma unroll
    for(int mi=0;mi<4;mi++){
      #pragma unroll
      for(int r=0;r<4;r++){
        int row=m0+wr*64+mi*16+q*4+r;
        float v=acc[mi][ni][r];
        if(EPI==0) v+=bv;
        else if(EPI==1) v=fmaxf(v+bv,0.f);
        else {
          v += (float)cnt[row]*bv + b2f(addb[(long)row*256+col]);
          v=fmaxf(v,0.f);
        }
        out[(long)row*256+col]=f2b(v);
      }
    }
  }
}

// ---------------- A0 GEMM: le = A0[32768,320] @ elw[256,320]^T + b  (LDS-staged) ----
__global__ __launch_bounds__(512) void k_a0g(const bf16* A, const bf16* W,
    const bf16* bias, bf16* out){
  __shared__ char smem[81920];
  const int tid=threadIdx.x;
  int m0=blockIdx.x*128;
  stage80((const char*)(A+(long)m0*320), smem, tid);
  __syncthreads();
  const int lane=tid&63, q=lane>>4, l16=lane&15;
  const int wv=tid>>6, wr=wv>>2, wc=wv&3, n0=wc*64;
  f32x4 acc[4][4];
  #pragma unroll
  for(int i=0;i<4;i++)
    #pragma unroll
    for(int j=0;j<4;j++) acc[i][j]=(f32x4){0.f,0.f,0.f,0.f};
  #pragma unroll
  for(int k0=0;k0<320;k0+=32){
    int kk=k0+q*8;
    bf16x8 af[4], bw[4];
    #pragma unroll
    for(int mi=0;mi<4;mi++) af[mi]=lds_a320(smem, wr*64+mi*16+l16, kk);
    #pragma unroll
    for(int ni=0;ni<4;ni++) bw[ni]=*(const bf16x8*)(W+(long)(n0+ni*16+l16)*320+kk);
    #pragma unroll
    for(int mi=0;mi<4;mi++)
      #pragma unroll
      for(int ni=0;ni<4;ni++)
        acc[mi][ni]=__builtin_amdgcn_mfma_f32_16x16x32_bf16(af[mi],bw[ni],acc[mi][ni],0,0,0);
  }
  #pragma unroll
  for(int ni=0;ni<4;ni++){
    int col=n0+ni*16+l16;
    float bv=b2f(bias[col]);
    #pragma unroll
    for(int mi=0;mi<4;mi++){
      #pragma unroll
      for(int r=0;r<4;r++){
        int row=m0+wr*64+mi*16+q*4+r;
        out[(long)row*256+col]=f2b(acc[mi][ni][r]+bv);
      }
    }
  }
}

// ---------------- per-layer fused dispatch #1: small + DUAL head/self GEMM + norm ----
struct L1 {
  const float* rel_lin; const bf16* ksw; const bf16* ksb;
  const float* qnode; const bf16* q2ew; const bf16* q2eb;
  float* relself; float* q2ev; bf16* q2evb;
  const bf16* A; const bf16* khw; const bf16* khb; bf16* headb; bf16* entself;
  const float* wt; const float* pr; const float* e2fs;
  const int* e2f; const int* f2e; float* normv; float* pragg;
};
__global__ __launch_bounds__(512) void k_lay1(L1 p){
  __shared__ char smem[65536];
  const int bid=blockIdx.x, tid=threadIdx.x;
  if(bid<617){
    float* xr=(float*)smem;
    if(tid<256){
      if(bid<601) xr[tid]=p.rel_lin[bid*DD+tid];
      else        xr[tid]=p.qnode[((bid-601)<<8)+tid];
    }
    __syncthreads();
    if(tid<256){
      int d=tid;
      if(bid<601){
        float acc=b2f(p.ksb[d]);
        const bf16* wr=p.ksw+(long)d*DD;
        for(int k4=0;k4<DD;k4+=4){
          float v[4]; ld4bf(wr+k4,v);
          acc+=v[0]*xr[k4]+v[1]*xr[k4+1]+v[2]*xr[k4+2]+v[3]*xr[k4+3];
        }
        p.relself[bid*DD+d]=acc;
      } else {
        int b=bid-601;
        float acc=b2f(p.q2eb[d]);
        const bf16* wr=p.q2ew+(long)d*DD;
        for(int k4=0;k4<DD;k4+=4){
          float v[4]; ld4bf(wr+k4,v);
          acc+=v[0]*xr[k4]+v[1]*xr[k4+1]+v[2]*xr[k4+2]+v[3]*xr[k4+3];
        }
        p.q2ev[(b<<8)+d]=acc;
        p.q2evb[(b<<8)+d]=f2b(acc);
      }
    }
  } else if(bid<873){
    int m0=(bid-617)*128;
    stage64((const char*)(p.A+(long)m0*256), smem, tid);
    __syncthreads();
    mg2_k256<0>(smem, p.khw, p.khb, p.headb, 0, 0, m0, tid);
    mg2_k256<0>(smem, p.ksw, p.ksb, p.entself, 0, 0, m0, tid);
  } else {
    int i=(bid-873)*512+tid;
    int b=i>>13;
    int e=p.e2f[i];
    float v=p.wt[i]*p.pr[(b<<11)+e]/fmaxf(p.e2fs[(b<<11)+e],1e-10f);
    p.normv[i]=v;
    atomicAdd(p.pragg+(b<<11)+p.f2e[i], v);
  }
}

struct MG {
  const bf16* A; const bf16* W; const bf16* bias; bf16* out;
  const bf16* Aq2; const bf16* Af2;
  const int* cnt; const bf16* addb;
};
// ---------------- KT GEMM (EPI=2), LDS-staged ----------------
__global__ __launch_bounds__(512) void k_ktg(MG p){
  __shared__ char smem[65536];
  int m0=blockIdx.x*128;
  stage64((const char*)(p.A+(long)m0*256), smem, threadIdx.x);
  __syncthreads();
  mg2_k256<2>(smem, p.W, p.bias, p.out, p.cnt, p.addb, m0, threadIdx.x);
}

// ---------------- segmented fact aggregation (atomic-free) ----------------
__global__ __launch_bounds__(256) void k_agg(const int* bstart, const int* bidx,
    const int* rel, const int* e2f, const float* normv, const float* relself,
    const bf16* head, bf16* agg){
  int eidx=blockIdx.x*4+(threadIdx.x>>6);
  int lane=threadIdx.x&63;
  int b=eidx>>11;
  float a0=0.f,a1=0.f,a2=0.f,a3=0.f;
  int s=bstart[eidx], e=bstart[eidx+1];
  for(int i=s;i<e;i++){
    int f=bidx[i];
    int r=rel[f]; int ent=e2f[f]; float nv=normv[f];
    float4 rs=*(const float4*)&relself[r*DD+lane*4];
    float hd[4]; ld4bf(head+(long)(((b<<11)+ent)*DD+lane*4),hd);
    a0+=fmaxf(rs.x+hd[0],0.f)*nv; a1+=fmaxf(rs.y+hd[1],0.f)*nv;
    a2+=fmaxf(rs.z+hd[2],0.f)*nv; a3+=fmaxf(rs.w+hd[3],0.f)*nv;
  }
  st4bf(agg+(long)eidx*DD+lane*4, a0,a1,a2,a3);
}

// ---------------- weighted row-sums (fused pagerank update; pragg read-zero) ----------
__global__ __launch_bounds__(256) void k_wnxt(const float* praggc, float* pragg, float* pr,
    const bf16* le, const bf16* f2e, float* wnxt, float* prsum){
  __shared__ float r1[4*256];
  __shared__ float r3[4*256];
  __shared__ float rp[4];
  const int b=blockIdx.x, ch=blockIdx.y;
  const int wv=threadIdx.x>>6, lane=threadIdx.x&63;
  const int pe0=(b<<11)+ch*64+wv*16;
  float pv=0.f;
  if(lane<16){
    int pe=pe0+lane;
    pv=0.8f*praggc[pe]+0.2f*pr[pe];
    pr[pe]=pv;
    pragg[pe]=0.f;        // self-clean for next layer's scatter
  }
  float a1[4]={0.f,0.f,0.f,0.f}, a3[4]={0.f,0.f,0.f,0.f}, ap=0.f;
  #pragma unroll
  for(int r=0;r<16;r++){
    float p=__shfl(pv, r, 64);
    long base=((long)(pe0+r))<<8;
    float v1[4],v3[4];
    ld4bf(le +base+lane*4, v1);
    ld4bf(f2e+base+lane*4, v3);
    #pragma unroll
    for(int j=0;j<4;j++){ a1[j]+=p*v1[j]; a3[j]+=p*v3[j]; }
    ap+=p;
  }
  #pragma unroll
  for(int j=0;j<4;j++){ r1[wv*256+lane*4+j]=a1[j]; r3[wv*256+lane*4+j]=a3[j]; }
  if(!lane) rp[wv]=ap;
  __syncthreads();
  const int t=threadIdx.x;
  float s1=r1[t]+r1[256+t]+r1[512+t]+r1[768+t];
  float s3=r3[t]+r3[256+t]+r3[512+t]+r3[768+t];
  atomicAdd(&wnxt[b*768+t], s1);
  atomicAdd(&wnxt[b*768+512+t], s3);
  if(!t) atomicAdd(&prsum[b], rp[0]+rp[1]+rp[2]+rp[3]);
}

// ---------------- e2e GEMM (K=768 concat) + qnode fused -----------------------------
// le staged in LDS (HBM-cold); f2eemb read direct from global (L2-hot, just written);
// q2evb broadcast. LDS 64KB -> 2 blocks/CU.
__global__ __launch_bounds__(512) void k_e2eq(MG p, const float* q2ev,
    const bf16* qw, const bf16* qb, float* wnxtb, float* prsum, float* qnode){
  __shared__ char sA[65536];
  const int tid=threadIdx.x;
  if(blockIdx.x<256){
    int m0=blockIdx.x*128;
    stage64((const char*)(p.A+(long)m0*256), sA, tid);
    __syncthreads();
    const int lane=tid&63, q=lane>>4, l16=lane&15;
    const int wv=tid>>6, wr=wv>>2, wc=wv&3, n0=wc*64;
    const bf16* aq2 = p.Aq2 + ((m0>>11)<<8);
    f32x4 acc[4][4];
    #pragma unroll
    for(int i=0;i<4;i++)
      #pragma unroll
      for(int j=0;j<4;j++) acc[i][j]=(f32x4){0.f,0.f,0.f,0.f};
    // segment 1: le (K 0..255) from LDS
    #pragma unroll
    for(int k0=0;k0<256;k0+=32){
      int kk=k0+q*8;
      bf16x8 af[4], bw[4];
      #pragma unroll
      for(int mi=0;mi<4;mi++) af[mi]=lds_a(sA, wr*64+mi*16+l16, kk);
      #pragma unroll
      for(int ni=0;ni<4;ni++) bw[ni]=*(const bf16x8*)(p.W+(long)(n0+ni*16+l16)*768+kk);
      #pragma unroll
      for(int mi=0;mi<4;mi++)
        #pragma unroll
        for(int ni=0;ni<4;ni++)
          acc[mi][ni]=__builtin_amdgcn_mfma_f32_16x16x32_bf16(af[mi],bw[ni],acc[mi][ni],0,0,0);
    }
    // segment 2: q2evb broadcast (K 256..511)
    #pragma unroll
    for(int k0=256;k0<512;k0+=32){
      int kk=k0+q*8;
      bf16x8 aq=*(const bf16x8*)(aq2+(kk-256));
      bf16x8 bw[4];
      #pragma unroll
      for(int ni=0;ni<4;ni++) bw[ni]=*(const bf16x8*)(p.W+(long)(n0+ni*16+l16)*768+kk);
      #pragma unroll
      for(int mi=0;mi<4;mi++)
        #pragma unroll
        for(int ni=0;ni<4;ni++)
          acc[mi][ni]=__builtin_amdgcn_mfma_f32_16x16x32_bf16(aq,bw[ni],acc[mi][ni],0,0,0);
    }
    // segment 3: f2eemb (K 512..767) direct from global (L2-hot)
    #pragma unroll
    for(int k0=512;k0<768;k0+=32){
      int kk=k0+q*8;
      bf16x8 af[4], bw[4];
      #pragma unroll
      for(int mi=0;mi<4;mi++)
        af[mi]=*(const bf16x8*)(p.Af2+(long)(m0+wr*64+mi*16+l16)*256+(kk-512));
      #pragma unroll
      for(int ni=0;ni<4;ni++) bw[ni]=*(const bf16x8*)(p.W+(long)(n0+ni*16+l16)*768+kk);
      #pragma unroll
      for(int mi=0;mi<4;mi++)
        #pragma unroll
        for(int ni=0;ni<4;ni++)
          acc[mi][ni]=__builtin_amdgcn_mfma_f32_16x16x32_bf16(af[mi],bw[ni],acc[mi][ni],0,0,0);
    }
    #pragma unroll
    for(int ni=0;ni<4;ni++){
      int col=n0+ni*16+l16;
      float bv=b2f(p.bias[col]);
      #pragma unroll
      for(int mi=0;mi<4;mi++){
        #pragma unroll
        for(int r=0;r<4;r++){
          int row=m0+wr*64+mi*16+q*4+r;
          p.out[(long)row*256+col]=f2b(fmaxf(acc[mi][ni][r]+bv,0.f));
        }
      }
    }
  } else {
    int b=blockIdx.x-256;
    float* xr=(float*)sA;
    float ps=prsum[b];
    if(tid<256){
      int d=tid;
      xr[d]=wnxtb[b*768+d];            wnxtb[b*768+d]=0.f;
      xr[256+d]=ps*q2ev[(b<<8)+d];
      xr[512+d]=wnxtb[b*768+512+d];    wnxtb[b*768+512+d]=0.f;
    }
    __syncthreads();
    if(tid<256){
      int d=tid;
      if(d==0) prsum[b]=0.f;
      float acc=0.f;
      const bf16* wr=qw+(long)d*768;
      for(int k4=0;k4<768;k4+=4){
        float v[4]; ld4bf(wr+k4,v);
        acc+=v[0]*xr[k4]+v[1]*xr[k4+1]+v[2]*xr[k4+2]+v[3]*xr[k4+3];
      }
      qnode[(b<<8)+d]=acc+ps*b2f(qb[d]);
    }
  }
}

// ---------------- score ----------------
__global__ __launch_bounds__(256) void k_score(const bf16* le, const bf16* sw,
    const bf16* sb, void* out, const int* dfl){
  const int isf=*dfl;
  int o=blockIdx.x*4 + (threadIdx.x>>6);
  int lane=threadIdx.x&63;
  float v[4],wv[4];
  ld4bf(le+(long)o*DD+lane*4,v); ld4bf(sw+lane*4,wv);
  float acc=v[0]*wv[0]+v[1]*wv[1]+v[2]*wv[2]+v[3]*wv[3];
  for(int off=32;off;off>>=1) acc+=__shfl_down(acc,off,64);
  if(!lane){
    float r=acc+b2f(sb[0]);
    if(isf) ((float*)out)[o]=r; else ((bf16*)out)[o]=f2b(r);
  }
}

// ---------------- host ----------------
extern "C" void kernel_launch(void* const* d_in, const int* in_sizes, int n_in,
                              void* d_out, int out_size, void* d_ws, size_t ws_size,
                              hipStream_t stream){
  const int*  local_entity=(const int*)d_in[0];
  const void* q2e_adj     =d_in[1];
  const int*  kb_fact_rel =(const int*)d_in[2];
  const int*  query_text  =(const int*)d_in[3];
  const int*  e2f_ent     =(const int*)d_in[5];
  const int*  f2e_ent     =(const int*)d_in[6];
  const void* word_emb    =d_in[7];
  const void* entity_emb  =d_in[8];
  const void* relation_emb=d_in[9];

  char* ws=(char*)d_ws;
  float* gx      =(float*)(ws+O_GX);
  float* qh      =(float*)(ws+O_QH);
  float* qnode   =(float*)(ws+O_QNODE);
  float* rel_lin =(float*)(ws+O_RELLIN);
  float* Wr      =(float*)(ws+O_WR);
  float* wmax    =(float*)(ws+O_WMAX);
  float* wt      =(float*)(ws+O_WT);
  float* e2fs    =(float*)(ws+O_E2FS);
  float* pr      =(float*)(ws+O_PR);
  float* pragg   =(float*)(ws+O_PRAGG);
  float* q2ev    =(float*)(ws+O_Q2EV);
  bf16*  q2evb   =(bf16*)(ws+O_Q2EVB);
  float* relself =(float*)(ws+O_RELSELF);
  float* normv   =(float*)(ws+O_NORM);
  float* wnxt    =(float*)(ws+O_WNXT);
  float* prsum   =(float*)(ws+O_PRSUM);
  int*   cnt     =(int*)(ws+O_CNT);
  int*   cur     =(int*)(ws+O_CUR);
  int*   bstart  =(int*)(ws+O_BSTART);
  int*   bidx    =(int*)(ws+O_BIDX);
  bf16*  elwpad  =(bf16*)(ws+O_ELWPAD);
  int*   dflag   =(int*)(ws+O_FLAG);
  bf16*  cw      =(bf16*)(ws+O_CVT);
  bf16*  agg     =(bf16*)(ws+O_AGG);
  bf16*  A0      =(bf16*)(ws+O_AGG);      // aliases agg (pre-layer use only)
  bf16*  entself =(bf16*)(ws+O_ENTSELF);
  bf16*  leA     =(bf16*)(ws+O_LEA);
  bf16*  leB     =(bf16*)(ws+O_LEB);
  bf16*  headb   =(bf16*)(ws+O_HEAD);
  bf16*  f2eemb  =(bf16*)(ws+O_F2EEMB);
  bf16*  hbuf    =(bf16*)(ws+O_LEA);              // 2 slots x 16x256 bf16 = 16KB
  int*   lcnt    =(int*)(ws+O_LEA+16384);         // 20 step flags

  k_sniff<<<1,256,0,stream>>>((const unsigned short*)entity_emb, dflag);

  CvtJobs J;
  int cntj=0;
  auto add=[&](int in_idx, long coff, int n, int sc){
    J.src[cntj]=d_in[in_idx]; J.dst[cntj]=cw+coff; J.n[cntj]=n; J.sc[cntj]=sc; cntj++;
  };
  add(11,C_ELB,256,0);
  add(12,C_RLW,153600,0);  add(13,C_RLB,256,0);
  add(14,C_WIH,307200,0);
  add(16,C_BIH,1024,0);    add(17,C_BHH,1024,0);
  add(18,C_Q2EW,196608,0); add(19,C_Q2EB,768,0);
  add(20,C_E2QW,589824,1); add(21,C_E2QB,768,0);
  add(22,C_E2EW,589824,1); add(23,C_E2EB,768,0);
  add(24,C_KHW,196608,0);  add(25,C_KHB,768,0);
  add(26,C_KTW,196608,0);  add(27,C_KTB,768,0);
  add(28,C_KSW,196608,0);  add(29,C_KSB,768,0);
  add(30,C_SCW,256,0);     add(31,C_SCB,1,0);
  k_cvt<<<dim3(576,20),256,0,stream>>>(J, dflag);
  k_cvtwhh<<<128,256,0,stream>>>(d_in[15], cw+C_WHH, dflag, cnt);   // also zeroes cnt+cur
  k_cvtelw<<<256,256,0,stream>>>(d_in[10], elwpad, dflag);

  // gx (320) + CSR count (512); lcnt zeroed by block 0
  k_gx  <<<832,256,0,stream>>>(query_text, word_emb, cw+C_WIH, cw+C_BIH, cw+C_BHH,
                               gx, dflag, lcnt, f2e_ent, cnt);
  k_scan<<<1,1024,0,stream>>>(cnt, bstart);
  // mega: lstm (8) + rel_lin (301) + prinit (16) + ga0 (8192) + CSR fill (256)
  k_mega<<<8773,512,0,stream>>>(gx, cw+C_WHH, qh, qnode, hbuf, lcnt,
      relation_emb, cw+C_RLW, cw+C_RLB, rel_lin,
      local_entity, entity_emb, A0,
      q2e_adj, pr, dflag,
      f2e_ent, bstart, cur, bidx);
  k_simwr<<<dim3(BB,3),256,0,stream>>>(qh, rel_lin, query_text, Wr);
  k_wmax <<<BB,256,0,stream>>>(Wr, kb_fact_rel, wmax, e2fs);
  k_wt   <<<BB*FF/256,256,0,stream>>>(Wr, kb_fact_rel, wmax, e2f_ent, wt, e2fs,
                                      pragg, wnxt, prsum);

  // le = A0 @ elw^T + elb  (LDS-staged, K=320)
  k_a0g<<<BB*EE/128,512,0,stream>>>(A0, elwpad, cw+C_ELB, leA);

  bf16* le_cur=leA; bf16* le_nxt=leB;
  for(int i=0;i<3;i++){
    { // fused: small mats + dual head/self LDS-GEMM + norm scatter
      L1 p{};
      p.rel_lin=rel_lin; p.ksw=cw+C_KSW+(long)i*65536; p.ksb=cw+C_KSB+(long)i*256;
      p.qnode=qnode; p.q2ew=cw+C_Q2EW+(long)i*65536; p.q2eb=cw+C_Q2EB+(long)i*256;
      p.relself=relself; p.q2ev=q2ev; p.q2evb=q2evb;
      p.A=le_cur; p.khw=cw+C_KHW+(long)i*65536; p.khb=cw+C_KHB+(long)i*256;
      p.headb=headb; p.entself=entself;
      p.wt=wt; p.pr=pr; p.e2fs=e2fs;
      p.e2f=e2f_ent; p.f2e=f2e_ent; p.normv=normv; p.pragg=pragg;
      k_lay1<<<1129,512,0,stream>>>(p);
    }
    k_agg <<<BB*EE/4,256,0,stream>>>(bstart, bidx, kb_fact_rel, e2f_ent, normv, relself, headb, agg);
    {
      MG p{}; p.A=agg; p.W=cw+C_KTW+(long)i*65536; p.bias=cw+C_KTB+(long)i*256;
      p.out=f2eemb; p.cnt=cnt; p.addb=entself;
      k_ktg<<<256,512,0,stream>>>(p);
    }
    k_wnxt <<<dim3(BB,32),256,0,stream>>>(pragg, pragg, pr, le_cur, f2eemb, wnxt, prsum);
    { // fused: e2e GEMM (concat, le-LDS + f2eemb-direct) + qnode
      MG p{}; p.A=le_cur; p.W=cw+C_E2EW+(long)i*196608; p.bias=cw+C_E2EB+(long)i*256;
      p.out=le_nxt; p.Aq2=q2evb; p.Af2=f2eemb;
      k_e2eq<<<272,512,0,stream>>>(p, q2ev,
          cw+C_E2QW+(long)i*196608, cw+C_E2QB+(long)i*256, wnxt, prsum, qnode);
    }
    bf16* t=le_cur; le_cur=le_nxt; le_nxt=t;
  }

  k_score<<<BB*EE/4,256,0,stream>>>(le_cur, cw+C_SCW, cw+C_SCB, d_out, dflag);
}